// Round 1
// baseline (788.787 us; speedup 1.0000x reference)
//
#include <hip/hip_runtime.h>
#include <math.h>

#define BB 8
#define NN 2048
#define KK 30
#define NF 128
#define EF 128
#define NPE 16
#define NRBF 16
#define MAXREL 32

#define V_OUT_SZ   (BB*NN*NF)        // 2097152
#define E_OUT_OFF  (V_OUT_SZ)
#define E_OUT_SZ   (BB*NN*KK*EF)     // 62914560
#define EIDX_OUT_OFF (E_OUT_OFF + E_OUT_SZ)

// workspace byte offsets
#define WS_EIDX_OFF 0                       // int[B*N*K]  = 1966080 B
#define WS_DNB_OFF  1966080                 // float[B*N*K]
#define WS_O_OFF    3932160                 // float[B*N*9] = 589824 B
#define WS_V6_OFF   4521984                 // float[B*N*6] = 393216 B

struct F3 { float x, y, z; };
__device__ inline F3 f3sub(F3 a, F3 b){ return {a.x-b.x, a.y-b.y, a.z-b.z}; }
__device__ inline F3 f3cross(F3 a, F3 b){ return {a.y*b.z - a.z*b.y, a.z*b.x - a.x*b.z, a.x*b.y - a.y*b.x}; }
__device__ inline float f3dot(F3 a, F3 b){ return a.x*b.x + a.y*b.y + a.z*b.z; }
__device__ inline F3 f3norm(F3 v){
    float n = sqrtf(f3dot(v, v));
    float r = 1.0f/(n + 1e-8f);
    return {v.x*r, v.y*r, v.z*r};
}
__device__ inline float sgnf(float x){ return (x>0.f)?1.f:((x<0.f)?-1.f:0.f); }

// ---------------------------------------------------------------------------
// Kernel A: per-node geometry -> dihedral features (6) and orientation O (9)
// ---------------------------------------------------------------------------
__global__ void geom_kernel(const float* __restrict__ X,
                            float* __restrict__ wsO, float* __restrict__ wsV6)
{
    int ng = blockIdx.x * blockDim.x + threadIdx.x;
    if (ng >= BB*NN) return;
    int b = ng / NN, n = ng % NN;
    const float* Xb = X + (size_t)b * NN * 12;   // [N][4][3]

    // ---- dihedrals: backbone atoms Xb[m], m = 3*res + atom(0..2) ----
    int k0 = 3*n - 1;
    F3 P[6];
    #pragma unroll
    for (int t = 0; t < 6; ++t) {
        int m = k0 + t;
        if (m < 0) m = 0;
        if (m > 3*NN-1) m = 3*NN-1;
        int r = m / 3, a = m % 3;
        const float* p = Xb + ((size_t)r*4 + a)*3;
        P[t] = {p[0], p[1], p[2]};
    }
    F3 U[5];
    #pragma unroll
    for (int t = 0; t < 5; ++t) U[t] = f3norm(f3sub(P[t+1], P[t]));

    float Dang[3];
    #pragma unroll
    for (int t = 0; t < 3; ++t) {
        int k = k0 + t;
        if (k < 0 || k > 3*NN-4) { Dang[t] = 0.f; continue; }
        F3 u2 = U[t], u1 = U[t+1], u0 = U[t+2];
        F3 n2 = f3norm(f3cross(u2, u1));
        F3 n1 = f3norm(f3cross(u1, u0));
        float cosD = f3dot(n2, n1);
        cosD = fminf(fmaxf(cosD, -1.f + 1e-7f), 1.f - 1e-7f);
        float s = f3dot(u2, n1);
        Dang[t] = sgnf(s) * acosf(cosD);
    }
    float* v6 = wsV6 + (size_t)ng * 6;
    v6[0] = cosf(Dang[0]); v6[1] = cosf(Dang[1]); v6[2] = cosf(Dang[2]);
    v6[3] = sinf(Dang[0]); v6[4] = sinf(Dang[1]); v6[5] = sinf(Dang[2]);

    // ---- orientation matrix O (rows: o1, n2, o1 x n2), valid 1 <= n <= N-3 ----
    float* o = wsO + (size_t)ng * 9;
    if (n >= 1 && n <= NN-3) {
        const float* cb = X + (size_t)b * NN * 12 + 3;  // Ca = atom 1
        F3 c0 = {cb[(size_t)(n-1)*12+0], cb[(size_t)(n-1)*12+1], cb[(size_t)(n-1)*12+2]};
        F3 c1 = {cb[(size_t)(n  )*12+0], cb[(size_t)(n  )*12+1], cb[(size_t)(n  )*12+2]};
        F3 c2 = {cb[(size_t)(n+1)*12+0], cb[(size_t)(n+1)*12+1], cb[(size_t)(n+1)*12+2]};
        F3 c3 = {cb[(size_t)(n+2)*12+0], cb[(size_t)(n+2)*12+1], cb[(size_t)(n+2)*12+2]};
        F3 u2 = f3norm(f3sub(c1, c0));
        F3 u1 = f3norm(f3sub(c2, c1));
        F3 n2 = f3norm(f3cross(u2, u1));
        F3 o1 = f3norm(f3sub(u2, u1));
        F3 r2 = f3cross(o1, n2);
        o[0]=o1.x; o[1]=o1.y; o[2]=o1.z;
        o[3]=n2.x; o[4]=n2.y; o[5]=n2.z;
        o[6]=r2.x; o[7]=r2.y; o[8]=r2.z;
    } else {
        #pragma unroll
        for (int m = 0; m < 9; ++m) o[m] = 0.f;
    }
}

// ---------------------------------------------------------------------------
// Kernel B: top-K nearest neighbors per row. 1 wave (64 threads) per row.
// Exact jax.lax.top_k tie-break via packed (dist_bits<<32 | j) u64 keys.
// ---------------------------------------------------------------------------
__global__ __launch_bounds__(64) void topk_kernel(
    const float* __restrict__ X, const float* __restrict__ mask,
    int* __restrict__ wsEidx, float* __restrict__ wsDnb,
    float* __restrict__ outEidxF)
{
    int row = blockIdx.x;          // b*N + i
    int b = row / NN, i = row % NN;
    int lane = threadIdx.x;
    __shared__ float dist[NN];     // column [slot*64 + lane] is lane-private

    const float* cb = X + (size_t)b * NN * 12 + 3;   // Ca base
    float cix = cb[(size_t)i*12+0], ciy = cb[(size_t)i*12+1], ciz = cb[(size_t)i*12+2];
    float mi = mask[(size_t)b*NN + i];

    float best = __builtin_inff();
    int bestIdx = 0;
    #pragma unroll 4
    for (int s = 0; s < NN/64; ++s) {
        int j = s*64 + lane;
        float dx = cix - cb[(size_t)j*12+0];
        float dy = ciy - cb[(size_t)j*12+1];
        float dz = ciz - cb[(size_t)j*12+2];
        float d = sqrtf(dx*dx + dy*dy + dz*dz + 1e-6f);
        d += (1.0f - mi * mask[(size_t)b*NN + j]) * 10000.0f;
        dist[s*64 + lane] = d;
        if (d < best) { best = d; bestIdx = j; }
    }

    size_t rb = (size_t)row * KK;
    for (int k = 0; k < KK; ++k) {
        unsigned long long key =
            ((unsigned long long)__float_as_uint(best) << 32) | (unsigned)bestIdx;
        #pragma unroll
        for (int off = 32; off; off >>= 1) {
            unsigned long long o = __shfl_xor(key, off, 64);
            if (o < key) key = o;
        }
        int jwin = (int)(key & 0xffffffffu);
        float dwin = __uint_as_float((unsigned)(key >> 32));
        if (lane == 0) {
            wsEidx[rb + k] = jwin;
            wsDnb[rb + k]  = dwin;
            outEidxF[rb + k] = (float)jwin;
        }
        if (bestIdx == jwin) {   // exactly one lane matches (jwin % 64 == lane)
            dist[jwin & (NN-1) ? 0 : 0, (jwin >> 6)*64 + lane] = __builtin_inff();
            best = __builtin_inff(); bestIdx = lane;
            for (int s = 0; s < NN/64; ++s) {
                float d = dist[s*64 + lane];
                if (d < best) { best = d; bestIdx = s*64 + lane; }
            }
        }
    }
}

// ---------------------------------------------------------------------------
// Kernel C: node path — hV = (V6 @ W1 + b1) @ W2 + b2 ; LayerNorm -> V_out
// 128 threads per node, W2 column in registers, 8 nodes per block.
// ---------------------------------------------------------------------------
__global__ __launch_bounds__(128) void node_kernel(
    const float* __restrict__ wsV6,
    const float* __restrict__ nlw, const float* __restrict__ nlb,
    const float* __restrict__ new_, const float* __restrict__ neb,
    const float* __restrict__ nng, const float* __restrict__ nnb,
    float* __restrict__ outV)
{
    int f = threadIdx.x;
    __shared__ float h1[128];
    __shared__ float red[2][2];

    float w2[128];
    #pragma unroll
    for (int c = 0; c < 128; ++c) w2[c] = new_[c*128 + f];
    float w1[6];
    #pragma unroll
    for (int c = 0; c < 6; ++c) w1[c] = nlw[c*128 + f];
    float b1v = nlb[f], b2v = neb[f], gv = nng[f], bv = nnb[f];

    for (int gi = 0; gi < 8; ++gi) {
        int row = blockIdx.x*8 + gi;
        float acc = b1v;
        #pragma unroll
        for (int c = 0; c < 6; ++c) acc = fmaf(wsV6[(size_t)row*6 + c], w1[c], acc);
        h1[f] = acc;
        __syncthreads();

        float a2 = b2v;
        #pragma unroll
        for (int c4 = 0; c4 < 32; ++c4) {
            float4 v = *(const float4*)&h1[c4*4];
            a2 = fmaf(v.x, w2[c4*4+0], a2);
            a2 = fmaf(v.y, w2[c4*4+1], a2);
            a2 = fmaf(v.z, w2[c4*4+2], a2);
            a2 = fmaf(v.w, w2[c4*4+3], a2);
        }
        float s = a2, ss = a2*a2;
        #pragma unroll
        for (int off = 32; off; off >>= 1) {
            s  += __shfl_xor(s,  off, 64);
            ss += __shfl_xor(ss, off, 64);
        }
        int wig = f >> 6;
        if ((f & 63) == 0) { red[wig][0] = s; red[wig][1] = ss; }
        __syncthreads();
        float S = red[0][0] + red[1][0], SS = red[0][1] + red[1][1];
        float mu = S * (1.f/128.f);
        float var = SS * (1.f/128.f) - mu*mu;
        float inv = rsqrtf(var + 1e-5f);
        outV[(size_t)row*128 + f] = (a2 - mu)*inv*gv + bv;
        __syncthreads();
    }
}

// ---------------------------------------------------------------------------
// Kernel D: edge path — build 39-dim edge features, 2-layer MLP, LayerNorm.
// 256 threads per node (f = tid&127, es = tid>>7 covers 2 edges at a time).
// W1/W2 columns in registers; LDS holds features + h1 (broadcast reads only).
// ---------------------------------------------------------------------------
__global__ __launch_bounds__(256, 2) void edge_kernel(
    const float* __restrict__ X,
    const int* __restrict__ ridx, const int* __restrict__ chain,
    const int* __restrict__ wsEidx, const float* __restrict__ wsDnb,
    const float* __restrict__ wsO,
    const float* __restrict__ pe_w, const float* __restrict__ pe_b,
    const float* __restrict__ elw, const float* __restrict__ elb,
    const float* __restrict__ eew, const float* __restrict__ eeb,
    const float* __restrict__ neg_, const float* __restrict__ neb_,
    float* __restrict__ outE)
{
    int tid = threadIdx.x;
    int f = tid & 127, es = tid >> 7;

    __shared__ float Ef[KK][40];
    __shared__ float h1[KK][128];
    __shared__ float red[2][2][2];

    float w1[40];
    #pragma unroll
    for (int c = 0; c < 39; ++c) w1[c] = elw[c*128 + f];
    w1[39] = 0.f;
    float w2[128];
    #pragma unroll
    for (int c = 0; c < 128; ++c) w2[c] = eew[c*128 + f];
    float b1v = elb[f], b2v = eeb[f], gv = neg_[f], bv = neb_[f];

    for (int gi = 0; gi < 4; ++gi) {
        int row = blockIdx.x*4 + gi;
        int b = row / NN, i = row % NN;
        size_t rb = (size_t)row * KK;

        // ---------------- feature phase (3 waves busy on disjoint columns) ---
        if (tid < KK) {
            int e = tid;
            int j = wsEidx[rb + e];
            float Oi[9], Oj[9];
            #pragma unroll
            for (int m = 0; m < 9; ++m) {
                Oi[m] = wsO[(size_t)row*9 + m];
                Oj[m] = wsO[((size_t)b*NN + j)*9 + m];
            }
            const float* cip = X + ((size_t)(b*NN + i)*4 + 1)*3;
            const float* cjp = X + ((size_t)(b*NN + j)*4 + 1)*3;
            float dx = cjp[0]-cip[0], dy = cjp[1]-cip[1], dz = cjp[2]-cip[2];
            float t0 = Oi[0]*dx + Oi[1]*dy + Oi[2]*dz;
            float t1 = Oi[3]*dx + Oi[4]*dy + Oi[5]*dz;
            float t2 = Oi[6]*dx + Oi[7]*dy + Oi[8]*dz;
            float nr = sqrtf(t0*t0 + t1*t1 + t2*t2);
            float iv = 1.f/(nr + 1e-8f);
            Ef[e][32] = t0*iv; Ef[e][33] = t1*iv; Ef[e][34] = t2*iv;
            // R = Oi^T * Oj
            float R00 = Oi[0]*Oj[0]+Oi[3]*Oj[3]+Oi[6]*Oj[6];
            float R01 = Oi[0]*Oj[1]+Oi[3]*Oj[4]+Oi[6]*Oj[7];
            float R02 = Oi[0]*Oj[2]+Oi[3]*Oj[5]+Oi[6]*Oj[8];
            float R10 = Oi[1]*Oj[0]+Oi[4]*Oj[3]+Oi[7]*Oj[6];
            float R11 = Oi[1]*Oj[1]+Oi[4]*Oj[4]+Oi[7]*Oj[7];
            float R12 = Oi[1]*Oj[2]+Oi[4]*Oj[5]+Oi[7]*Oj[8];
            float R20 = Oi[2]*Oj[0]+Oi[5]*Oj[3]+Oi[8]*Oj[6];
            float R21 = Oi[2]*Oj[1]+Oi[5]*Oj[4]+Oi[8]*Oj[7];
            float R22 = Oi[2]*Oj[2]+Oi[5]*Oj[5]+Oi[8]*Oj[8];
            float mx = 0.5f*sqrtf(fabsf(1.f + R00 - R11 - R22));
            float my = 0.5f*sqrtf(fabsf(1.f - R00 + R11 - R22));
            float mz = 0.5f*sqrtf(fabsf(1.f - R00 - R11 + R22));
            float qx = sgnf(R21 - R12)*mx;
            float qy = sgnf(R02 - R20)*my;
            float qz = sgnf(R10 - R01)*mz;
            float qw = 0.5f*sqrtf(fmaxf(0.f, 1.f + R00 + R11 + R22));
            float qn = sqrtf(qx*qx + qy*qy + qz*qz + qw*qw);
            float qi = 1.f/(qn + 1e-8f);
            Ef[e][35] = qx*qi; Ef[e][36] = qy*qi; Ef[e][37] = qz*qi; Ef[e][38] = qw*qi;
            Ef[e][39] = 0.f;
        } else if (tid >= 64 && tid < 64 + KK) {       // RBF
            int e = tid - 64;
            float dnb = wsDnb[rb + e];
            #pragma unroll
            for (int m = 0; m < 16; ++m) {
                float mu = 2.f + (20.f/15.f)*(float)m;
                float z = (dnb - mu) * 0.8f;
                Ef[e][16 + m] = expf(-z*z);
            }
        } else if (tid >= 128 && tid < 128 + KK) {     // positional embedding
            int e = tid - 128;
            int j = wsEidx[rb + e];
            int ri = ridx[(size_t)b*NN + i], rj = ridx[(size_t)b*NN + j];
            int ch = (chain[(size_t)b*NN + i] == chain[(size_t)b*NN + j]) ? 1 : 0;
            int dd = min(max(ri - rj + MAXREL, 0), 2*MAXREL);
            dd = ch ? dd : (2*MAXREL + 1);
            #pragma unroll
            for (int m = 0; m < 16; ++m) Ef[e][m] = pe_w[dd*16 + m] + pe_b[m];
        }
        __syncthreads();

        // ---------------- layer 1: h1[e][f] = b1 + E[e][:] . W1[:,f] --------
        for (int p = 0; p < 15; ++p) {
            int e = p*2 + es;
            float acc = b1v;
            #pragma unroll
            for (int c4 = 0; c4 < 10; ++c4) {
                float4 v = *(const float4*)&Ef[e][c4*4];
                acc = fmaf(v.x, w1[c4*4+0], acc);
                acc = fmaf(v.y, w1[c4*4+1], acc);
                acc = fmaf(v.z, w1[c4*4+2], acc);
                acc = fmaf(v.w, w1[c4*4+3], acc);
            }
            h1[e][f] = acc;
        }
        __syncthreads();

        // ---------------- layer 2 + LayerNorm + store ------------------------
        for (int p = 0; p < 15; ++p) {
            int e = p*2 + es;
            float acc = b2v;
            #pragma unroll
            for (int c4 = 0; c4 < 32; ++c4) {
                float4 v = *(const float4*)&h1[e][c4*4];
                acc = fmaf(v.x, w2[c4*4+0], acc);
                acc = fmaf(v.y, w2[c4*4+1], acc);
                acc = fmaf(v.z, w2[c4*4+2], acc);
                acc = fmaf(v.w, w2[c4*4+3], acc);
            }
            float s = acc, ss = acc*acc;
            #pragma unroll
            for (int off = 32; off; off >>= 1) {
                s  += __shfl_xor(s,  off, 64);
                ss += __shfl_xor(ss, off, 64);
            }
            int wig = (tid >> 6) & 1;
            if ((tid & 63) == 0) { red[es][wig][0] = s; red[es][wig][1] = ss; }
            __syncthreads();
            float S  = red[es][0][0] + red[es][1][0];
            float SS = red[es][0][1] + red[es][1][1];
            float mu = S * (1.f/128.f);
            float var = SS * (1.f/128.f) - mu*mu;
            float inv = rsqrtf(var + 1e-5f);
            outE[(rb + e)*128 + f] = (acc - mu)*inv*gv + bv;
            __syncthreads();
        }
    }
}

// ---------------------------------------------------------------------------
extern "C" void kernel_launch(void* const* d_in, const int* in_sizes, int n_in,
                              void* d_out, int out_size, void* d_ws, size_t ws_size,
                              hipStream_t stream)
{
    const float* X     = (const float*)d_in[0];
    const float* mask  = (const float*)d_in[1];
    const int*   ridx  = (const int*)  d_in[2];
    const int*   chain = (const int*)  d_in[3];
    const float* pe_w  = (const float*)d_in[4];
    const float* pe_b  = (const float*)d_in[5];
    const float* nlw   = (const float*)d_in[6];
    const float* nlb   = (const float*)d_in[7];
    const float* new_  = (const float*)d_in[8];
    const float* neb   = (const float*)d_in[9];
    const float* elw   = (const float*)d_in[10];
    const float* elb   = (const float*)d_in[11];
    const float* eew   = (const float*)d_in[12];
    const float* eeb   = (const float*)d_in[13];
    const float* nng   = (const float*)d_in[14];
    const float* nnb   = (const float*)d_in[15];
    const float* neg_  = (const float*)d_in[16];
    const float* neb_  = (const float*)d_in[17];

    float* out = (float*)d_out;
    char*  ws  = (char*)d_ws;
    int*   wsEidx = (int*)  (ws + WS_EIDX_OFF);
    float* wsDnb  = (float*)(ws + WS_DNB_OFF);
    float* wsO    = (float*)(ws + WS_O_OFF);
    float* wsV6   = (float*)(ws + WS_V6_OFF);

    geom_kernel<<<(BB*NN + 255)/256, 256, 0, stream>>>(X, wsO, wsV6);
    topk_kernel<<<BB*NN, 64, 0, stream>>>(X, mask, wsEidx, wsDnb, out + EIDX_OUT_OFF);
    node_kernel<<<BB*NN/8, 128, 0, stream>>>(wsV6, nlw, nlb, new_, neb, nng, nnb, out);
    edge_kernel<<<BB*NN/4, 256, 0, stream>>>(X, ridx, chain, wsEidx, wsDnb, wsO,
                                             pe_w, pe_b, elw, elb, eew, eeb,
                                             neg_, neb_, out + E_OUT_OFF);
}

// Round 2
// 344.303 us; speedup vs baseline: 2.2910x; 2.2910x over previous
//
#include <hip/hip_runtime.h>
#include <hip/hip_bf16.h>
#include <math.h>

#define BB 8
#define NN 2048
#define KK 30
#define NF 128
#define EF 128
#define NPE 16
#define NRBF 16
#define MAXREL 32

#define V_OUT_SZ   (BB*NN*NF)        // 2097152
#define E_OUT_OFF  (V_OUT_SZ)
#define E_OUT_SZ   (BB*NN*KK*EF)     // 62914560
#define EIDX_OUT_OFF (E_OUT_OFF + E_OUT_SZ)

// workspace byte offsets
#define WS_EIDX_OFF 0                       // int[B*N*K]
#define WS_DNB_OFF  1966080                 // float[B*N*K]
#define WS_O_OFF    3932160                 // float[B*N*9]
#define WS_V6_OFF   4521984                 // float[B*N*6]

typedef __attribute__((ext_vector_type(8))) short bf16x8;
typedef __attribute__((ext_vector_type(4))) float f32x4;
#define MFMA16(a,b,c) __builtin_amdgcn_mfma_f32_16x16x32_bf16(a,b,c,0,0,0)

struct F3 { float x, y, z; };
__device__ inline F3 f3sub(F3 a, F3 b){ return {a.x-b.x, a.y-b.y, a.z-b.z}; }
__device__ inline F3 f3cross(F3 a, F3 b){ return {a.y*b.z - a.z*b.y, a.z*b.x - a.x*b.z, a.x*b.y - a.y*b.x}; }
__device__ inline float f3dot(F3 a, F3 b){ return a.x*b.x + a.y*b.y + a.z*b.z; }
__device__ inline F3 f3norm(F3 v){
    float n = sqrtf(f3dot(v, v));
    float r = 1.0f/(n + 1e-8f);
    return {v.x*r, v.y*r, v.z*r};
}
__device__ inline float sgnf(float x){ return (x>0.f)?1.f:((x<0.f)?-1.f:0.f); }
__device__ inline short f2bf(float f){
    union { __hip_bfloat16 h; short s; } u;
    u.h = __float2bfloat16(f);
    return u.s;
}

// ---------------------------------------------------------------------------
// Kernel A: per-node geometry -> dihedral features (6) and orientation O (9)
// ---------------------------------------------------------------------------
__global__ void geom_kernel(const float* __restrict__ X,
                            float* __restrict__ wsO, float* __restrict__ wsV6)
{
    int ng = blockIdx.x * blockDim.x + threadIdx.x;
    if (ng >= BB*NN) return;
    int b = ng / NN, n = ng % NN;
    const float* Xb = X + (size_t)b * NN * 12;   // [N][4][3]

    int k0 = 3*n - 1;
    F3 P[6];
    #pragma unroll
    for (int t = 0; t < 6; ++t) {
        int m = k0 + t;
        if (m < 0) m = 0;
        if (m > 3*NN-1) m = 3*NN-1;
        int r = m / 3, a = m % 3;
        const float* p = Xb + ((size_t)r*4 + a)*3;
        P[t] = {p[0], p[1], p[2]};
    }
    F3 U[5];
    #pragma unroll
    for (int t = 0; t < 5; ++t) U[t] = f3norm(f3sub(P[t+1], P[t]));

    float Dang[3];
    #pragma unroll
    for (int t = 0; t < 3; ++t) {
        int k = k0 + t;
        if (k < 0 || k > 3*NN-4) { Dang[t] = 0.f; continue; }
        F3 u2 = U[t], u1 = U[t+1], u0 = U[t+2];
        F3 n2 = f3norm(f3cross(u2, u1));
        F3 n1 = f3norm(f3cross(u1, u0));
        float cosD = f3dot(n2, n1);
        cosD = fminf(fmaxf(cosD, -1.f + 1e-7f), 1.f - 1e-7f);
        float s = f3dot(u2, n1);
        Dang[t] = sgnf(s) * acosf(cosD);
    }
    float* v6 = wsV6 + (size_t)ng * 6;
    v6[0] = cosf(Dang[0]); v6[1] = cosf(Dang[1]); v6[2] = cosf(Dang[2]);
    v6[3] = sinf(Dang[0]); v6[4] = sinf(Dang[1]); v6[5] = sinf(Dang[2]);

    float* o = wsO + (size_t)ng * 9;
    if (n >= 1 && n <= NN-3) {
        const float* cb = X + (size_t)b * NN * 12 + 3;  // Ca = atom 1
        F3 c0 = {cb[(size_t)(n-1)*12+0], cb[(size_t)(n-1)*12+1], cb[(size_t)(n-1)*12+2]};
        F3 c1 = {cb[(size_t)(n  )*12+0], cb[(size_t)(n  )*12+1], cb[(size_t)(n  )*12+2]};
        F3 c2 = {cb[(size_t)(n+1)*12+0], cb[(size_t)(n+1)*12+1], cb[(size_t)(n+1)*12+2]};
        F3 u2 = f3norm(f3sub(c1, c0));
        F3 u1 = f3norm(f3sub(c2, c1));
        F3 n2 = f3norm(f3cross(u2, u1));
        F3 o1 = f3norm(f3sub(u2, u1));
        F3 r2 = f3cross(o1, n2);
        o[0]=o1.x; o[1]=o1.y; o[2]=o1.z;
        o[3]=n2.x; o[4]=n2.y; o[5]=n2.z;
        o[6]=r2.x; o[7]=r2.y; o[8]=r2.z;
    } else {
        #pragma unroll
        for (int m = 0; m < 9; ++m) o[m] = 0.f;
    }
}

// ---------------------------------------------------------------------------
// Kernel B: top-K nearest neighbors per row. 1 wave per row.
// ---------------------------------------------------------------------------
__global__ __launch_bounds__(64) void topk_kernel(
    const float* __restrict__ X, const float* __restrict__ mask,
    int* __restrict__ wsEidx, float* __restrict__ wsDnb,
    float* __restrict__ outEidxF)
{
    int row = blockIdx.x;          // b*N + i
    int b = row / NN, i = row % NN;
    int lane = threadIdx.x;
    __shared__ float dist[NN];

    const float* cb = X + (size_t)b * NN * 12 + 3;   // Ca base
    float cix = cb[(size_t)i*12+0], ciy = cb[(size_t)i*12+1], ciz = cb[(size_t)i*12+2];
    float mi = mask[(size_t)b*NN + i];

    float best = __builtin_inff();
    int bestIdx = 0;
    #pragma unroll 4
    for (int s = 0; s < NN/64; ++s) {
        int j = s*64 + lane;
        float dx = cix - cb[(size_t)j*12+0];
        float dy = ciy - cb[(size_t)j*12+1];
        float dz = ciz - cb[(size_t)j*12+2];
        float d = sqrtf(dx*dx + dy*dy + dz*dz + 1e-6f);
        d += (1.0f - mi * mask[(size_t)b*NN + j]) * 10000.0f;
        dist[s*64 + lane] = d;
        if (d < best) { best = d; bestIdx = j; }
    }

    size_t rb = (size_t)row * KK;
    for (int k = 0; k < KK; ++k) {
        unsigned long long key =
            ((unsigned long long)__float_as_uint(best) << 32) | (unsigned)bestIdx;
        #pragma unroll
        for (int off = 32; off; off >>= 1) {
            unsigned long long o = __shfl_xor(key, off, 64);
            if (o < key) key = o;
        }
        int jwin = (int)(key & 0xffffffffu);
        float dwin = __uint_as_float((unsigned)(key >> 32));
        if (lane == 0) {
            wsEidx[rb + k] = jwin;
            wsDnb[rb + k]  = dwin;
            outEidxF[rb + k] = (float)jwin;
        }
        if (bestIdx == jwin) {
            dist[(jwin >> 6)*64 + lane] = __builtin_inff();
            best = __builtin_inff(); bestIdx = lane;
            for (int s = 0; s < NN/64; ++s) {
                float d = dist[s*64 + lane];
                if (d < best) { best = d; bestIdx = s*64 + lane; }
            }
        }
    }
}

// ---------------------------------------------------------------------------
// Kernel C: node path (unchanged, small)
// ---------------------------------------------------------------------------
__global__ __launch_bounds__(128) void node_kernel(
    const float* __restrict__ wsV6,
    const float* __restrict__ nlw, const float* __restrict__ nlb,
    const float* __restrict__ new_, const float* __restrict__ neb,
    const float* __restrict__ nng, const float* __restrict__ nnb,
    float* __restrict__ outV)
{
    int f = threadIdx.x;
    __shared__ float h1[128];
    __shared__ float red[2][2];

    float w2[128];
    #pragma unroll
    for (int c = 0; c < 128; ++c) w2[c] = new_[c*128 + f];
    float w1[6];
    #pragma unroll
    for (int c = 0; c < 6; ++c) w1[c] = nlw[c*128 + f];
    float b1v = nlb[f], b2v = neb[f], gv = nng[f], bv = nnb[f];

    for (int gi = 0; gi < 8; ++gi) {
        int row = blockIdx.x*8 + gi;
        float acc = b1v;
        #pragma unroll
        for (int c = 0; c < 6; ++c) acc = fmaf(wsV6[(size_t)row*6 + c], w1[c], acc);
        h1[f] = acc;
        __syncthreads();

        float a2 = b2v;
        #pragma unroll
        for (int c4 = 0; c4 < 32; ++c4) {
            float4 v = *(const float4*)&h1[c4*4];
            a2 = fmaf(v.x, w2[c4*4+0], a2);
            a2 = fmaf(v.y, w2[c4*4+1], a2);
            a2 = fmaf(v.z, w2[c4*4+2], a2);
            a2 = fmaf(v.w, w2[c4*4+3], a2);
        }
        float s = a2, ss = a2*a2;
        #pragma unroll
        for (int off = 32; off; off >>= 1) {
            s  += __shfl_xor(s,  off, 64);
            ss += __shfl_xor(ss, off, 64);
        }
        int wig = f >> 6;
        if ((f & 63) == 0) { red[wig][0] = s; red[wig][1] = ss; }
        __syncthreads();
        float S = red[0][0] + red[1][0], SS = red[0][1] + red[1][1];
        float mu = S * (1.f/128.f);
        float var = SS * (1.f/128.f) - mu*mu;
        float inv = rsqrtf(var + 1e-5f);
        outV[(size_t)row*128 + f] = (a2 - mu)*inv*gv + bv;
        __syncthreads();
    }
}

// ---------------------------------------------------------------------------
// Kernel D (new): edge path with bf16 MFMA.
// 64-edge tiles, 4 waves in 2M x 2N: wave (wm,wn) owns rows wm*32..+32,
// cols wn*64..+64. W1/W2 fragments live in registers (loaded once/block,
// amortized over 8 tiles). Features f32->bf16 in LDS (stride 72: 2-way bank
// alias, free). h1 staged bf16 in LDS (stride 136). LN via shfl butterfly +
// small LDS cross-wave combine.
// ---------------------------------------------------------------------------
#define TILES_PER_BLOCK 8
#define EDGE_GRID (BB*NN*KK/64/TILES_PER_BLOCK)   // 960

__global__ __launch_bounds__(256) void edge_mfma_kernel(
    const float* __restrict__ X,
    const int* __restrict__ ridx, const int* __restrict__ chain,
    const int* __restrict__ wsEidx, const float* __restrict__ wsDnb,
    const float* __restrict__ wsO,
    const float* __restrict__ pe_w, const float* __restrict__ pe_b,
    const float* __restrict__ elw, const float* __restrict__ elb,
    const float* __restrict__ eew, const float* __restrict__ eeb,
    const float* __restrict__ lng, const float* __restrict__ lnb,
    float* __restrict__ outE)
{
    __shared__ alignas(16) short Ef[64*72];     // [edge][k<64 pad], bf16
    __shared__ alignas(16) short h1t[64*136];   // [edge][feat 128 pad], bf16
    __shared__ float redS[64][2];
    __shared__ float redSS[64][2];

    const int tid  = threadIdx.x;
    const int wave = tid >> 6, lane = tid & 63;
    const int wm = wave >> 1, wn = wave & 1;
    const int lr = lane & 15, lk = lane >> 4;

    // zero Ef once (features rewrite cols 0..38 each tile; 39..63 stay 0)
    for (int idx = tid; idx < 64*72; idx += 256) Ef[idx] = 0;

    // ---- B fragments (registers) + per-col params ----
    bf16x8 B1[2][4], B2[4][4];
    float b1v[4], b2v[4], gv[4], bv[4];
    #pragma unroll
    for (int nf = 0; nf < 4; ++nf) {
        int col = wn*64 + nf*16 + lr;
        b1v[nf] = elb[col]; b2v[nf] = eeb[col];
        gv[nf]  = lng[col]; bv[nf]  = lnb[col];
        #pragma unroll
        for (int ks = 0; ks < 2; ++ks) {
            bf16x8 v;
            #pragma unroll
            for (int j = 0; j < 8; ++j) {
                int k = ks*32 + lk*8 + j;
                v[j] = f2bf(k < 39 ? elw[k*128 + col] : 0.f);
            }
            B1[ks][nf] = v;
        }
        #pragma unroll
        for (int ks = 0; ks < 4; ++ks) {
            bf16x8 v;
            #pragma unroll
            for (int j = 0; j < 8; ++j) {
                int k = ks*32 + lk*8 + j;
                v[j] = f2bf(eew[k*128 + col]);
            }
            B2[ks][nf] = v;
        }
    }

    for (int t = 0; t < TILES_PER_BLOCK; ++t) {
        const int E0 = (blockIdx.x*TILES_PER_BLOCK + t)*64;

        // ---------------- feature phase ----------------
        if (wave == 0) {                       // geometry: dU (3) + quat (4)
            int ge = E0 + lane;
            int row = ge / KK;
            int b = row >> 11;
            int j = wsEidx[ge];
            float oi[9], oj[9];
            #pragma unroll
            for (int m = 0; m < 9; ++m) {
                oi[m] = wsO[(size_t)row*9 + m];
                oj[m] = wsO[((size_t)(b*NN) + j)*9 + m];
            }
            const float* cip = X + (size_t)row*12 + 3;
            const float* cjp = X + ((size_t)(b*NN + j))*12 + 3;
            float dx = cjp[0]-cip[0], dy = cjp[1]-cip[1], dz = cjp[2]-cip[2];
            float t0 = oi[0]*dx + oi[1]*dy + oi[2]*dz;
            float t1 = oi[3]*dx + oi[4]*dy + oi[5]*dz;
            float t2 = oi[6]*dx + oi[7]*dy + oi[8]*dz;
            float nr = sqrtf(t0*t0 + t1*t1 + t2*t2);
            float iv = 1.f/(nr + 1e-8f);
            short* ef = &Ef[lane*72];
            ef[32] = f2bf(t0*iv); ef[33] = f2bf(t1*iv); ef[34] = f2bf(t2*iv);
            float R00 = oi[0]*oj[0]+oi[3]*oj[3]+oi[6]*oj[6];
            float R01 = oi[0]*oj[1]+oi[3]*oj[4]+oi[6]*oj[7];
            float R02 = oi[0]*oj[2]+oi[3]*oj[5]+oi[6]*oj[8];
            float R10 = oi[1]*oj[0]+oi[4]*oj[3]+oi[7]*oj[6];
            float R11 = oi[1]*oj[1]+oi[4]*oj[4]+oi[7]*oj[7];
            float R12 = oi[1]*oj[2]+oi[4]*oj[5]+oi[7]*oj[8];
            float R20 = oi[2]*oj[0]+oi[5]*oj[3]+oi[8]*oj[6];
            float R21 = oi[2]*oj[1]+oi[5]*oj[4]+oi[8]*oj[7];
            float R22 = oi[2]*oj[2]+oi[5]*oj[5]+oi[8]*oj[8];
            float mx = 0.5f*sqrtf(fabsf(1.f + R00 - R11 - R22));
            float my = 0.5f*sqrtf(fabsf(1.f - R00 + R11 - R22));
            float mz = 0.5f*sqrtf(fabsf(1.f - R00 - R11 + R22));
            float qx = sgnf(R21 - R12)*mx;
            float qy = sgnf(R02 - R20)*my;
            float qz = sgnf(R10 - R01)*mz;
            float qw = 0.5f*sqrtf(fmaxf(0.f, 1.f + R00 + R11 + R22));
            float qn = sqrtf(qx*qx + qy*qy + qz*qz + qw*qw);
            float qi = 1.f/(qn + 1e-8f);
            ef[35] = f2bf(qx*qi); ef[36] = f2bf(qy*qi);
            ef[37] = f2bf(qz*qi); ef[38] = f2bf(qw*qi);
        } else if (wave == 1) {                // RBF (16)
            int ge = E0 + lane;
            float dnb = wsDnb[ge];
            short* ef = &Ef[lane*72 + 16];
            #pragma unroll
            for (int m = 0; m < 16; ++m) {
                float mu = 2.f + (20.f/15.f)*(float)m;
                float z = (dnb - mu) * 0.8f;
                ef[m] = f2bf(expf(-z*z));
            }
        } else if (wave == 2) {                // positional embedding (16)
            int ge = E0 + lane;
            int row = ge / KK;
            int b = row >> 11;
            int j = wsEidx[ge];
            int ri = ridx[row], rj = ridx[b*NN + j];
            int ch = (chain[row] == chain[b*NN + j]) ? 1 : 0;
            int dd = min(max(ri - rj + MAXREL, 0), 2*MAXREL);
            dd = ch ? dd : (2*MAXREL + 1);
            short* ef = &Ef[lane*72];
            #pragma unroll
            for (int m = 0; m < 16; ++m) ef[m] = f2bf(pe_w[dd*16 + m] + pe_b[m]);
        }
        __syncthreads();

        // ---------------- layer 1: h1 = Ef @ W1 + b1 ----------------
        f32x4 acc[2][4];
        #pragma unroll
        for (int mf = 0; mf < 2; ++mf)
            #pragma unroll
            for (int nf = 0; nf < 4; ++nf)
                acc[mf][nf] = (f32x4){0.f, 0.f, 0.f, 0.f};
        #pragma unroll
        for (int ks = 0; ks < 2; ++ks) {
            bf16x8 a0 = *(const bf16x8*)&Ef[(wm*32      + lr)*72 + ks*32 + lk*8];
            bf16x8 a1 = *(const bf16x8*)&Ef[(wm*32 + 16 + lr)*72 + ks*32 + lk*8];
            #pragma unroll
            for (int nf = 0; nf < 4; ++nf) {
                acc[0][nf] = MFMA16(a0, B1[ks][nf], acc[0][nf]);
                acc[1][nf] = MFMA16(a1, B1[ks][nf], acc[1][nf]);
            }
        }
        #pragma unroll
        for (int mf = 0; mf < 2; ++mf)
            #pragma unroll
            for (int nf = 0; nf < 4; ++nf)
                #pragma unroll
                for (int r = 0; r < 4; ++r) {
                    int row = wm*32 + mf*16 + lk*4 + r;
                    int col = wn*64 + nf*16 + lr;
                    h1t[row*136 + col] = f2bf(acc[mf][nf][r] + b1v[nf]);
                }
        __syncthreads();

        // ---------------- layer 2: h2 = h1 @ W2 + b2 ----------------
        f32x4 acc2[2][4];
        #pragma unroll
        for (int mf = 0; mf < 2; ++mf)
            #pragma unroll
            for (int nf = 0; nf < 4; ++nf)
                acc2[mf][nf] = (f32x4){0.f, 0.f, 0.f, 0.f};
        #pragma unroll
        for (int ks = 0; ks < 4; ++ks) {
            bf16x8 a0 = *(const bf16x8*)&h1t[(wm*32      + lr)*136 + ks*32 + lk*8];
            bf16x8 a1 = *(const bf16x8*)&h1t[(wm*32 + 16 + lr)*136 + ks*32 + lk*8];
            #pragma unroll
            for (int nf = 0; nf < 4; ++nf) {
                acc2[0][nf] = MFMA16(a0, B2[ks][nf], acc2[0][nf]);
                acc2[1][nf] = MFMA16(a1, B2[ks][nf], acc2[1][nf]);
            }
        }
        // finalize (add bias), partial LN sums per row
        #pragma unroll
        for (int mf = 0; mf < 2; ++mf)
            #pragma unroll
            for (int nf = 0; nf < 4; ++nf)
                #pragma unroll
                for (int r = 0; r < 4; ++r)
                    acc2[mf][nf][r] += b2v[nf];
        #pragma unroll
        for (int mf = 0; mf < 2; ++mf) {
            #pragma unroll
            for (int r = 0; r < 4; ++r) {
                float v0 = acc2[mf][0][r], v1 = acc2[mf][1][r];
                float v2 = acc2[mf][2][r], v3 = acc2[mf][3][r];
                float s = v0 + v1 + v2 + v3;
                float q = v0*v0 + v1*v1 + v2*v2 + v3*v3;
                #pragma unroll
                for (int off = 1; off < 16; off <<= 1) {
                    s += __shfl_xor(s, off, 64);
                    q += __shfl_xor(q, off, 64);
                }
                if (lr == 0) {
                    int row = wm*32 + mf*16 + lk*4 + r;
                    redS[row][wn] = s; redSS[row][wn] = q;
                }
            }
        }
        __syncthreads();

        // ---------------- LayerNorm + store ----------------
        const size_t obase = (size_t)E0 * 128;
        #pragma unroll
        for (int mf = 0; mf < 2; ++mf) {
            #pragma unroll
            for (int r = 0; r < 4; ++r) {
                int row = wm*32 + mf*16 + lk*4 + r;
                float S = redS[row][0] + redS[row][1];
                float Q = redSS[row][0] + redSS[row][1];
                float mu = S * (1.f/128.f);
                float var = Q * (1.f/128.f) - mu*mu;
                float inv = rsqrtf(var + 1e-5f);
                #pragma unroll
                for (int nf = 0; nf < 4; ++nf) {
                    int col = wn*64 + nf*16 + lr;
                    outE[obase + (size_t)row*128 + col] =
                        (acc2[mf][nf][r] - mu)*inv*gv[nf] + bv[nf];
                }
            }
        }
        __syncthreads();   // redS safe + Ef/h1t safe for next tile
    }
}

// ---------------------------------------------------------------------------
extern "C" void kernel_launch(void* const* d_in, const int* in_sizes, int n_in,
                              void* d_out, int out_size, void* d_ws, size_t ws_size,
                              hipStream_t stream)
{
    const float* X     = (const float*)d_in[0];
    const float* mask  = (const float*)d_in[1];
    const int*   ridx  = (const int*)  d_in[2];
    const int*   chain = (const int*)  d_in[3];
    const float* pe_w  = (const float*)d_in[4];
    const float* pe_b  = (const float*)d_in[5];
    const float* nlw   = (const float*)d_in[6];
    const float* nlb   = (const float*)d_in[7];
    const float* new_  = (const float*)d_in[8];
    const float* neb   = (const float*)d_in[9];
    const float* elw   = (const float*)d_in[10];
    const float* elb   = (const float*)d_in[11];
    const float* eew   = (const float*)d_in[12];
    const float* eeb   = (const float*)d_in[13];
    const float* nng   = (const float*)d_in[14];
    const float* nnb   = (const float*)d_in[15];
    const float* neg_  = (const float*)d_in[16];
    const float* neb_  = (const float*)d_in[17];

    float* out = (float*)d_out;
    char*  ws  = (char*)d_ws;
    int*   wsEidx = (int*)  (ws + WS_EIDX_OFF);
    float* wsDnb  = (float*)(ws + WS_DNB_OFF);
    float* wsO    = (float*)(ws + WS_O_OFF);
    float* wsV6   = (float*)(ws + WS_V6_OFF);

    geom_kernel<<<(BB*NN + 255)/256, 256, 0, stream>>>(X, wsO, wsV6);
    topk_kernel<<<BB*NN, 64, 0, stream>>>(X, mask, wsEidx, wsDnb, out + EIDX_OUT_OFF);
    node_kernel<<<BB*NN/8, 128, 0, stream>>>(wsV6, nlw, nlb, new_, neb, nng, nnb, out);
    edge_mfma_kernel<<<EDGE_GRID, 256, 0, stream>>>(X, ridx, chain, wsEidx, wsDnb, wsO,
                                                    pe_w, pe_b, elw, elb, eew, eeb,
                                                    neg_, neb_, out + E_OUT_OFF);
}

// Round 3
// 252.749 us; speedup vs baseline: 3.1208x; 1.3622x over previous
//
#include <hip/hip_runtime.h>
#include <hip/hip_bf16.h>
#include <math.h>

#define BB 8
#define NN 2048
#define KK 30
#define NF 128
#define EF 128
#define NPE 16
#define NRBF 16
#define MAXREL 32

#define V_OUT_SZ   (BB*NN*NF)
#define E_OUT_OFF  (V_OUT_SZ)
#define E_OUT_SZ   (BB*NN*KK*EF)
#define EIDX_OUT_OFF (E_OUT_OFF + E_OUT_SZ)

// workspace byte offsets
#define WS_EIDX_OFF 0                       // int[B*N*K]
#define WS_DNB_OFF  1966080                 // float[B*N*K]
#define WS_O_OFF    3932160                 // float[B*N*9]
#define WS_V6_OFF   4521984                 // float[B*N*6]
#define WS_CA4_OFF  4915200                 // float4[B*N]      (Ca.xyz, mask)
#define WS_W1_OFF   5177344                 // bf16[8192]   L1 frags
#define WS_W2_OFF   5193728                 // bf16[16384]  L2 frags
// end 5226496

typedef __attribute__((ext_vector_type(8))) short bf16x8;
typedef __attribute__((ext_vector_type(4))) float f32x4;
#define MFMA16(a,b,c) __builtin_amdgcn_mfma_f32_16x16x32_bf16(a,b,c,0,0,0)

struct F3 { float x, y, z; };
__device__ inline F3 f3sub(F3 a, F3 b){ return {a.x-b.x, a.y-b.y, a.z-b.z}; }
__device__ inline F3 f3cross(F3 a, F3 b){ return {a.y*b.z - a.z*b.y, a.z*b.x - a.x*b.z, a.x*b.y - a.y*b.x}; }
__device__ inline float f3dot(F3 a, F3 b){ return a.x*b.x + a.y*b.y + a.z*b.z; }
__device__ inline F3 f3norm(F3 v){
    float n = sqrtf(f3dot(v, v));
    float r = 1.0f/(n + 1e-8f);
    return {v.x*r, v.y*r, v.z*r};
}
__device__ inline float sgnf(float x){ return (x>0.f)?1.f:((x<0.f)?-1.f:0.f); }
__device__ inline short f2bf(float f){
    union { __hip_bfloat16 h; short s; } u;
    u.h = __float2bfloat16(f);
    return u.s;
}

// ---------------------------------------------------------------------------
// Kernel P: pre-convert edge-MLP weights into bf16 MFMA-fragment order.
// W1 frag idx = ((nf*2+ks)*64+lane)*8+j   (8192 elems)
// W2 frag idx = ((nf*4+ks)*64+lane)*8+j   (16384 elems)
// element: k = ks*32 + (lane>>4)*8 + j, col = nf*16 + (lane&15)
// ---------------------------------------------------------------------------
__global__ void prep_kernel(const float* __restrict__ elw,
                            const float* __restrict__ eew,
                            __hip_bfloat16* __restrict__ w1,
                            __hip_bfloat16* __restrict__ w2)
{
    int i = blockIdx.x*256 + threadIdx.x;
    if (i < 8192) {
        int j = i & 7, lane = (i>>3)&63, ks = (i>>9)&1, nf = i>>10;
        int k = ks*32 + (lane>>4)*8 + j;
        int col = nf*16 + (lane&15);
        float v = (k < 39) ? elw[k*128 + col] : 0.f;
        w1[i] = __float2bfloat16(v);
    } else if (i < 8192 + 16384) {
        int i2 = i - 8192;
        int j = i2 & 7, lane = (i2>>3)&63, ks = (i2>>9)&3, nf = i2>>11;
        int k = ks*32 + (lane>>4)*8 + j;
        int col = nf*16 + (lane&15);
        w2[i2] = __float2bfloat16(eew[k*128 + col]);
    }
}

// ---------------------------------------------------------------------------
// Kernel A: per-node geometry -> V6 (dihedral 6), O (9), packed Ca4 (xyz+mask)
// ---------------------------------------------------------------------------
__global__ void geom_kernel(const float* __restrict__ X,
                            const float* __restrict__ mask,
                            float* __restrict__ wsO, float* __restrict__ wsV6,
                            float4* __restrict__ wsCa4)
{
    int ng = blockIdx.x * blockDim.x + threadIdx.x;
    if (ng >= BB*NN) return;
    int b = ng / NN, n = ng % NN;
    const float* Xb = X + (size_t)b * NN * 12;

    // packed Ca + mask
    {
        const float* cp = X + (size_t)ng*12 + 3;
        wsCa4[ng] = make_float4(cp[0], cp[1], cp[2], mask[ng]);
    }

    int k0 = 3*n - 1;
    F3 P[6];
    #pragma unroll
    for (int t = 0; t < 6; ++t) {
        int m = k0 + t;
        if (m < 0) m = 0;
        if (m > 3*NN-1) m = 3*NN-1;
        int r = m / 3, a = m % 3;
        const float* p = Xb + ((size_t)r*4 + a)*3;
        P[t] = {p[0], p[1], p[2]};
    }
    F3 U[5];
    #pragma unroll
    for (int t = 0; t < 5; ++t) U[t] = f3norm(f3sub(P[t+1], P[t]));

    float Dang[3];
    #pragma unroll
    for (int t = 0; t < 3; ++t) {
        int k = k0 + t;
        if (k < 0 || k > 3*NN-4) { Dang[t] = 0.f; continue; }
        F3 u2 = U[t], u1 = U[t+1], u0 = U[t+2];
        F3 n2 = f3norm(f3cross(u2, u1));
        F3 n1 = f3norm(f3cross(u1, u0));
        float cosD = f3dot(n2, n1);
        cosD = fminf(fmaxf(cosD, -1.f + 1e-7f), 1.f - 1e-7f);
        float s = f3dot(u2, n1);
        Dang[t] = sgnf(s) * acosf(cosD);
    }
    float* v6 = wsV6 + (size_t)ng * 6;
    v6[0] = cosf(Dang[0]); v6[1] = cosf(Dang[1]); v6[2] = cosf(Dang[2]);
    v6[3] = sinf(Dang[0]); v6[4] = sinf(Dang[1]); v6[5] = sinf(Dang[2]);

    float* o = wsO + (size_t)ng * 9;
    if (n >= 1 && n <= NN-3) {
        const float* cb = X + (size_t)b * NN * 12 + 3;
        F3 c0 = {cb[(size_t)(n-1)*12+0], cb[(size_t)(n-1)*12+1], cb[(size_t)(n-1)*12+2]};
        F3 c1 = {cb[(size_t)(n  )*12+0], cb[(size_t)(n  )*12+1], cb[(size_t)(n  )*12+2]};
        F3 c2 = {cb[(size_t)(n+1)*12+0], cb[(size_t)(n+1)*12+1], cb[(size_t)(n+1)*12+2]};
        F3 u2 = f3norm(f3sub(c1, c0));
        F3 u1 = f3norm(f3sub(c2, c1));
        F3 n2 = f3norm(f3cross(u2, u1));
        F3 o1 = f3norm(f3sub(u2, u1));
        F3 r2 = f3cross(o1, n2);
        o[0]=o1.x; o[1]=o1.y; o[2]=o1.z;
        o[3]=n2.x; o[4]=n2.y; o[5]=n2.z;
        o[6]=r2.x; o[7]=r2.y; o[8]=r2.z;
    } else {
        #pragma unroll
        for (int m = 0; m < 9; ++m) o[m] = 0.f;
    }
}

// ---------------------------------------------------------------------------
// Kernel B: top-K. 1 wave per row. Distances in LDS, lane-major + rotated
// (conflict-free on both the stride-1-per-lane writes and the winner-row
// cooperative reads). After extracting the global (d,j)-min, all 32 lanes
// re-reduce the winner lane's 32 slots (replaces the serial 32-iter rescan).
// Exact jax.lax.top_k semantics: min (d, j) lexicographic.
// ---------------------------------------------------------------------------
__global__ __launch_bounds__(64) void topk_kernel(
    const float4* __restrict__ wsCa4,
    int* __restrict__ wsEidx, float* __restrict__ wsDnb,
    float* __restrict__ outEidxF)
{
    int row = blockIdx.x;
    int b = row >> 11, i = row & (NN-1);
    int lane = threadIdx.x;
    __shared__ float dist[NN];

    const float4* cb = wsCa4 + ((size_t)b << 11);
    float4 ci = cb[i];
    float mi = ci.w;

    float best = __builtin_inff();
    int bestIdx = 0;
    #pragma unroll 8
    for (int s = 0; s < NN/64; ++s) {
        int j = s*64 + lane;
        float4 cj = cb[j];
        float dx = ci.x - cj.x, dy = ci.y - cj.y, dz = ci.z - cj.z;
        float d = sqrtf(dx*dx + dy*dy + dz*dz + 1e-6f);
        d += (1.0f - mi * cj.w) * 10000.0f;
        dist[lane*32 + ((s + lane) & 31)] = d;
        if (d < best) { best = d; bestIdx = j; }
    }

    size_t rb = (size_t)row * KK;
    for (int k = 0; k < KK; ++k) {
        // global argmin: min d, then min j among d==dmin
        float dmin = best;
        #pragma unroll
        for (int off = 32; off; off >>= 1)
            dmin = fminf(dmin, __shfl_xor(dmin, off, 64));
        int cand = (best == dmin) ? bestIdx : 0x7fffffff;
        #pragma unroll
        for (int off = 32; off; off >>= 1)
            cand = min(cand, __shfl_xor(cand, off, 64));

        if (lane == 0) {
            wsEidx[rb + k] = cand;
            wsDnb[rb + k]  = dmin;
            outEidxF[rb + k] = (float)cand;
        }

        int lw = cand & 63, sw = cand >> 6;
        if (lane == lw) dist[lw*32 + ((sw + lw) & 31)] = __builtin_inff();
        __syncthreads();   // drain LDS write, single wave -> cheap

        // cooperative recompute of winner lane's best
        float d2 = __builtin_inff();
        int   j2 = 0x7fffffff;
        if (lane < 32) {
            d2 = dist[lw*32 + ((lane + lw) & 31)];   // slot s = lane
            j2 = lane*64 + lw;
        }
        float dmin2 = d2;
        #pragma unroll
        for (int off = 32; off; off >>= 1)
            dmin2 = fminf(dmin2, __shfl_xor(dmin2, off, 64));
        int cand2 = (d2 == dmin2) ? j2 : 0x7fffffff;
        #pragma unroll
        for (int off = 32; off; off >>= 1)
            cand2 = min(cand2, __shfl_xor(cand2, off, 64));
        if (lane == lw) { best = dmin2; bestIdx = cand2; }
    }
}

// ---------------------------------------------------------------------------
// Kernel C: node path (unchanged)
// ---------------------------------------------------------------------------
__global__ __launch_bounds__(128) void node_kernel(
    const float* __restrict__ wsV6,
    const float* __restrict__ nlw, const float* __restrict__ nlb,
    const float* __restrict__ new_, const float* __restrict__ neb,
    const float* __restrict__ nng, const float* __restrict__ nnb,
    float* __restrict__ outV)
{
    int f = threadIdx.x;
    __shared__ float h1[128];
    __shared__ float red[2][2];

    float w2[128];
    #pragma unroll
    for (int c = 0; c < 128; ++c) w2[c] = new_[c*128 + f];
    float w1[6];
    #pragma unroll
    for (int c = 0; c < 6; ++c) w1[c] = nlw[c*128 + f];
    float b1v = nlb[f], b2v = neb[f], gv = nng[f], bv = nnb[f];

    for (int gi = 0; gi < 8; ++gi) {
        int row = blockIdx.x*8 + gi;
        float acc = b1v;
        #pragma unroll
        for (int c = 0; c < 6; ++c) acc = fmaf(wsV6[(size_t)row*6 + c], w1[c], acc);
        h1[f] = acc;
        __syncthreads();

        float a2 = b2v;
        #pragma unroll
        for (int c4 = 0; c4 < 32; ++c4) {
            float4 v = *(const float4*)&h1[c4*4];
            a2 = fmaf(v.x, w2[c4*4+0], a2);
            a2 = fmaf(v.y, w2[c4*4+1], a2);
            a2 = fmaf(v.z, w2[c4*4+2], a2);
            a2 = fmaf(v.w, w2[c4*4+3], a2);
        }
        float s = a2, ss = a2*a2;
        #pragma unroll
        for (int off = 32; off; off >>= 1) {
            s  += __shfl_xor(s,  off, 64);
            ss += __shfl_xor(ss, off, 64);
        }
        int wig = f >> 6;
        if ((f & 63) == 0) { red[wig][0] = s; red[wig][1] = ss; }
        __syncthreads();
        float S = red[0][0] + red[1][0], SS = red[0][1] + red[1][1];
        float mu = S * (1.f/128.f);
        float var = SS * (1.f/128.f) - mu*mu;
        float inv = rsqrtf(var + 1e-5f);
        outV[(size_t)row*128 + f] = (a2 - mu)*inv*gv + bv;
        __syncthreads();
    }
}

// ---------------------------------------------------------------------------
// Kernel D: edge MFMA, 1 tile (64 edges) per block, grid 7680.
// Weights streamed as bf16 dwordx4 fragments from ws (L2-resident).
// LDS: Ef[64][72] (LN-red aliased on top) + h1t[64][136] = 26.6 KB.
// ---------------------------------------------------------------------------
__global__ __launch_bounds__(256, 4) void edge_mfma_kernel(
    const float4* __restrict__ wsCa4,
    const int* __restrict__ ridx, const int* __restrict__ chain,
    const int* __restrict__ wsEidx, const float* __restrict__ wsDnb,
    const float* __restrict__ wsO,
    const float* __restrict__ pe_w, const float* __restrict__ pe_b,
    const __hip_bfloat16* __restrict__ wsW1, const __hip_bfloat16* __restrict__ wsW2,
    const float* __restrict__ elb, const float* __restrict__ eeb,
    const float* __restrict__ lng, const float* __restrict__ lnb,
    float* __restrict__ outE)
{
    __shared__ char smem[64*72*2 + 64*136*2];     // 26624 B
    short* Ef  = (short*)smem;                    // [64][72]
    short* h1t = (short*)(smem + 64*72*2);        // [64][136]
    float* redS  = (float*)smem;                  // [64][2], alias Ef (safe: used after L1 barrier)
    float* redSS = (float*)(smem + 512);

    const int tid  = threadIdx.x;
    const int wave = tid >> 6, lane = tid & 63;
    const int wm = wave >> 1, wn = wave & 1;
    const int lr = lane & 15, lk = lane >> 4;

    float b1v[4], b2v[4], gv[4], bv[4];
    #pragma unroll
    for (int nf = 0; nf < 4; ++nf) {
        int col = wn*64 + nf*16 + lr;
        b1v[nf] = elb[col]; b2v[nf] = eeb[col];
        gv[nf]  = lng[col]; bv[nf]  = lnb[col];
    }

    // zero only K-pad cols 39..63 (disjoint from feature writes -> no barrier)
    for (int idx = tid; idx < 64*25; idx += 256) {
        int r = idx / 25, c = 39 + idx % 25;
        Ef[r*72 + c] = 0;
    }

    const int E0 = blockIdx.x * 64;

    // ---------------- feature phase ----------------
    if (wave == 0) {                       // geometry: dU (3) + quat (4)
        int ge = E0 + lane;
        int row = ge / KK;
        int b = row >> 11;
        int j = wsEidx[ge];
        float oi[9], oj[9];
        #pragma unroll
        for (int m = 0; m < 9; ++m) {
            oi[m] = wsO[(size_t)row*9 + m];
            oj[m] = wsO[((size_t)(b*NN) + j)*9 + m];
        }
        float4 ci = wsCa4[row];
        float4 cj = wsCa4[(size_t)b*NN + j];
        float dx = cj.x-ci.x, dy = cj.y-ci.y, dz = cj.z-ci.z;
        float t0 = oi[0]*dx + oi[1]*dy + oi[2]*dz;
        float t1 = oi[3]*dx + oi[4]*dy + oi[5]*dz;
        float t2 = oi[6]*dx + oi[7]*dy + oi[8]*dz;
        float nr = sqrtf(t0*t0 + t1*t1 + t2*t2);
        float iv = 1.f/(nr + 1e-8f);
        short* ef = &Ef[lane*72];
        ef[32] = f2bf(t0*iv); ef[33] = f2bf(t1*iv); ef[34] = f2bf(t2*iv);
        float R00 = oi[0]*oj[0]+oi[3]*oj[3]+oi[6]*oj[6];
        float R01 = oi[0]*oj[1]+oi[3]*oj[4]+oi[6]*oj[7];
        float R02 = oi[0]*oj[2]+oi[3]*oj[5]+oi[6]*oj[8];
        float R10 = oi[1]*oj[0]+oi[4]*oj[3]+oi[7]*oj[6];
        float R11 = oi[1]*oj[1]+oi[4]*oj[4]+oi[7]*oj[7];
        float R12 = oi[1]*oj[2]+oi[4]*oj[5]+oi[7]*oj[8];
        float R20 = oi[2]*oj[0]+oi[5]*oj[3]+oi[8]*oj[6];
        float R21 = oi[2]*oj[1]+oi[5]*oj[4]+oi[8]*oj[7];
        float R22 = oi[2]*oj[2]+oi[5]*oj[5]+oi[8]*oj[8];
        float mx = 0.5f*sqrtf(fabsf(1.f + R00 - R11 - R22));
        float my = 0.5f*sqrtf(fabsf(1.f - R00 + R11 - R22));
        float mz = 0.5f*sqrtf(fabsf(1.f - R00 - R11 + R22));
        float qx = sgnf(R21 - R12)*mx;
        float qy = sgnf(R02 - R20)*my;
        float qz = sgnf(R10 - R01)*mz;
        float qw = 0.5f*sqrtf(fmaxf(0.f, 1.f + R00 + R11 + R22));
        float qn = sqrtf(qx*qx + qy*qy + qz*qz + qw*qw);
        float qi = 1.f/(qn + 1e-8f);
        ef[35] = f2bf(qx*qi); ef[36] = f2bf(qy*qi);
        ef[37] = f2bf(qz*qi); ef[38] = f2bf(qw*qi);
    } else if (wave == 1) {                // RBF (16)
        int ge = E0 + lane;
        float dnb = wsDnb[ge];
        short* ef = &Ef[lane*72 + 16];
        #pragma unroll
        for (int m = 0; m < 16; ++m) {
            float mu = 2.f + (20.f/15.f)*(float)m;
            float z = (dnb - mu) * 0.8f;
            ef[m] = f2bf(expf(-z*z));
        }
    } else if (wave == 2) {                // positional embedding (16)
        int ge = E0 + lane;
        int row = ge / KK;
        int b = row >> 11;
        int j = wsEidx[ge];
        int ri = ridx[row], rj = ridx[b*NN + j];
        int ch = (chain[row] == chain[b*NN + j]) ? 1 : 0;
        int dd = min(max(ri - rj + MAXREL, 0), 2*MAXREL);
        dd = ch ? dd : (2*MAXREL + 1);
        short* ef = &Ef[lane*72];
        #pragma unroll
        for (int m = 0; m < 16; ++m) ef[m] = f2bf(pe_w[dd*16 + m] + pe_b[m]);
    }
    __syncthreads();

    // ---------------- layer 1 ----------------
    const bf16x8* W1f = (const bf16x8*)wsW1;
    const bf16x8* W2f = (const bf16x8*)wsW2;

    f32x4 acc[2][4];
    #pragma unroll
    for (int mf = 0; mf < 2; ++mf)
        #pragma unroll
        for (int nf = 0; nf < 4; ++nf)
            acc[mf][nf] = (f32x4){0.f, 0.f, 0.f, 0.f};
    #pragma unroll
    for (int ks = 0; ks < 2; ++ks) {
        bf16x8 a0 = *(const bf16x8*)&Ef[(wm*32      + lr)*72 + ks*32 + lk*8];
        bf16x8 a1 = *(const bf16x8*)&Ef[(wm*32 + 16 + lr)*72 + ks*32 + lk*8];
        #pragma unroll
        for (int nf = 0; nf < 4; ++nf) {
            bf16x8 Bf = W1f[((wn*4 + nf)*2 + ks)*64 + lane];
            acc[0][nf] = MFMA16(a0, Bf, acc[0][nf]);
            acc[1][nf] = MFMA16(a1, Bf, acc[1][nf]);
        }
    }
    #pragma unroll
    for (int mf = 0; mf < 2; ++mf)
        #pragma unroll
        for (int nf = 0; nf < 4; ++nf)
            #pragma unroll
            for (int r = 0; r < 4; ++r) {
                int row = wm*32 + mf*16 + lk*4 + r;
                int col = wn*64 + nf*16 + lr;
                h1t[row*136 + col] = f2bf(acc[mf][nf][r] + b1v[nf]);
            }
    __syncthreads();

    // ---------------- layer 2 ----------------
    f32x4 acc2[2][4];
    #pragma unroll
    for (int mf = 0; mf < 2; ++mf)
        #pragma unroll
        for (int nf = 0; nf < 4; ++nf)
            acc2[mf][nf] = (f32x4){0.f, 0.f, 0.f, 0.f};
    #pragma unroll
    for (int ks = 0; ks < 4; ++ks) {
        bf16x8 a0 = *(const bf16x8*)&h1t[(wm*32      + lr)*136 + ks*32 + lk*8];
        bf16x8 a1 = *(const bf16x8*)&h1t[(wm*32 + 16 + lr)*136 + ks*32 + lk*8];
        #pragma unroll
        for (int nf = 0; nf < 4; ++nf) {
            bf16x8 Bf = W2f[((wn*4 + nf)*4 + ks)*64 + lane];
            acc2[0][nf] = MFMA16(a0, Bf, acc2[0][nf]);
            acc2[1][nf] = MFMA16(a1, Bf, acc2[1][nf]);
        }
    }
    #pragma unroll
    for (int mf = 0; mf < 2; ++mf)
        #pragma unroll
        for (int nf = 0; nf < 4; ++nf)
            #pragma unroll
            for (int r = 0; r < 4; ++r)
                acc2[mf][nf][r] += b2v[nf];

    #pragma unroll
    for (int mf = 0; mf < 2; ++mf) {
        #pragma unroll
        for (int r = 0; r < 4; ++r) {
            float v0 = acc2[mf][0][r], v1 = acc2[mf][1][r];
            float v2 = acc2[mf][2][r], v3 = acc2[mf][3][r];
            float s = v0 + v1 + v2 + v3;
            float q = v0*v0 + v1*v1 + v2*v2 + v3*v3;
            #pragma unroll
            for (int off = 1; off < 16; off <<= 1) {
                s += __shfl_xor(s, off, 64);
                q += __shfl_xor(q, off, 64);
            }
            if (lr == 0) {
                int row = wm*32 + mf*16 + lk*4 + r;
                redS[row*2 + wn] = s; redSS[row*2 + wn] = q;
            }
        }
    }
    __syncthreads();

    // ---------------- LayerNorm + store ----------------
    const size_t obase = (size_t)E0 * 128;
    #pragma unroll
    for (int mf = 0; mf < 2; ++mf) {
        #pragma unroll
        for (int r = 0; r < 4; ++r) {
            int row = wm*32 + mf*16 + lk*4 + r;
            float S = redS[row*2 + 0] + redS[row*2 + 1];
            float Q = redSS[row*2 + 0] + redSS[row*2 + 1];
            float mu = S * (1.f/128.f);
            float var = Q * (1.f/128.f) - mu*mu;
            float inv = rsqrtf(var + 1e-5f);
            #pragma unroll
            for (int nf = 0; nf < 4; ++nf) {
                int col = wn*64 + nf*16 + lr;
                outE[obase + (size_t)row*128 + col] =
                    (acc2[mf][nf][r] - mu)*inv*gv[nf] + bv[nf];
            }
        }
    }
}

// ---------------------------------------------------------------------------
extern "C" void kernel_launch(void* const* d_in, const int* in_sizes, int n_in,
                              void* d_out, int out_size, void* d_ws, size_t ws_size,
                              hipStream_t stream)
{
    const float* X     = (const float*)d_in[0];
    const float* mask  = (const float*)d_in[1];
    const int*   ridx  = (const int*)  d_in[2];
    const int*   chain = (const int*)  d_in[3];
    const float* pe_w  = (const float*)d_in[4];
    const float* pe_b  = (const float*)d_in[5];
    const float* nlw   = (const float*)d_in[6];
    const float* nlb   = (const float*)d_in[7];
    const float* new_  = (const float*)d_in[8];
    const float* neb   = (const float*)d_in[9];
    const float* elw   = (const float*)d_in[10];
    const float* elb   = (const float*)d_in[11];
    const float* eew   = (const float*)d_in[12];
    const float* eeb   = (const float*)d_in[13];
    const float* nng   = (const float*)d_in[14];
    const float* nnb   = (const float*)d_in[15];
    const float* neg_  = (const float*)d_in[16];
    const float* neb_  = (const float*)d_in[17];

    float* out = (float*)d_out;
    char*  ws  = (char*)d_ws;
    int*    wsEidx = (int*)   (ws + WS_EIDX_OFF);
    float*  wsDnb  = (float*) (ws + WS_DNB_OFF);
    float*  wsO    = (float*) (ws + WS_O_OFF);
    float*  wsV6   = (float*) (ws + WS_V6_OFF);
    float4* wsCa4  = (float4*)(ws + WS_CA4_OFF);
    __hip_bfloat16* wsW1 = (__hip_bfloat16*)(ws + WS_W1_OFF);
    __hip_bfloat16* wsW2 = (__hip_bfloat16*)(ws + WS_W2_OFF);

    prep_kernel<<<96, 256, 0, stream>>>(elw, eew, wsW1, wsW2);
    geom_kernel<<<(BB*NN + 255)/256, 256, 0, stream>>>(X, mask, wsO, wsV6, wsCa4);
    topk_kernel<<<BB*NN, 64, 0, stream>>>(wsCa4, wsEidx, wsDnb, out + EIDX_OUT_OFF);
    node_kernel<<<BB*NN/8, 128, 0, stream>>>(wsV6, nlw, nlb, new_, neb, nng, nnb, out);
    edge_mfma_kernel<<<BB*NN*KK/64, 256, 0, stream>>>(wsCa4, ridx, chain, wsEidx, wsDnb, wsO,
                                                      pe_w, pe_b, wsW1, wsW2,
                                                      elb, eeb, neg_, neb_, out + E_OUT_OFF);
}

// Round 4
// 240.048 us; speedup vs baseline: 3.2860x; 1.0529x over previous
//
#include <hip/hip_runtime.h>
#include <hip/hip_bf16.h>
#include <math.h>

#define BB 8
#define NN 2048
#define KK 30
#define NF 128
#define EF 128
#define NPE 16
#define NRBF 16
#define MAXREL 32

#define V_OUT_SZ   (BB*NN*NF)
#define E_OUT_OFF  (V_OUT_SZ)
#define E_OUT_SZ   (BB*NN*KK*EF)
#define EIDX_OUT_OFF (E_OUT_OFF + E_OUT_SZ)

// workspace byte offsets
#define WS_EIDX_OFF 0                       // int[B*N*K]
#define WS_DNB_OFF  1966080                 // float[B*N*K]
#define WS_O_OFF    3932160                 // float[B*N*9]
#define WS_V6_OFF   4521984                 // float[B*N*6]
#define WS_CA4_OFF  4915200                 // float4[B*N]      (Ca.xyz, mask)
#define WS_W1_OFF   5177344                 // bf16[8192]   L1 frags
#define WS_W2_OFF   5193728                 // bf16[16384]  L2 frags
// end 5226496

typedef __attribute__((ext_vector_type(8))) short bf16x8;
typedef __attribute__((ext_vector_type(4))) float f32x4;
#define MFMA16(a,b,c) __builtin_amdgcn_mfma_f32_16x16x32_bf16(a,b,c,0,0,0)

struct F3 { float x, y, z; };
__device__ inline F3 f3sub(F3 a, F3 b){ return {a.x-b.x, a.y-b.y, a.z-b.z}; }
__device__ inline F3 f3cross(F3 a, F3 b){ return {a.y*b.z - a.z*b.y, a.z*b.x - a.x*b.z, a.x*b.y - a.y*b.x}; }
__device__ inline float f3dot(F3 a, F3 b){ return a.x*b.x + a.y*b.y + a.z*b.z; }
__device__ inline F3 f3norm(F3 v){
    float n = sqrtf(f3dot(v, v));
    float r = 1.0f/(n + 1e-8f);
    return {v.x*r, v.y*r, v.z*r};
}
__device__ inline float sgnf(float x){ return (x>0.f)?1.f:((x<0.f)?-1.f:0.f); }
__device__ inline short f2bf(float f){
    union { __hip_bfloat16 h; short s; } u;
    u.h = __float2bfloat16(f);
    return u.s;
}

// ---------------------------------------------------------------------------
// Kernel P: pre-convert edge-MLP weights into bf16 MFMA-fragment order.
// ---------------------------------------------------------------------------
__global__ void prep_kernel(const float* __restrict__ elw,
                            const float* __restrict__ eew,
                            __hip_bfloat16* __restrict__ w1,
                            __hip_bfloat16* __restrict__ w2)
{
    int i = blockIdx.x*256 + threadIdx.x;
    if (i < 8192) {
        int j = i & 7, lane = (i>>3)&63, ks = (i>>9)&1, nf = i>>10;
        int k = ks*32 + (lane>>4)*8 + j;
        int col = nf*16 + (lane&15);
        float v = (k < 39) ? elw[k*128 + col] : 0.f;
        w1[i] = __float2bfloat16(v);
    } else if (i < 8192 + 16384) {
        int i2 = i - 8192;
        int j = i2 & 7, lane = (i2>>3)&63, ks = (i2>>9)&3, nf = i2>>11;
        int k = ks*32 + (lane>>4)*8 + j;
        int col = nf*16 + (lane&15);
        w2[i2] = __float2bfloat16(eew[k*128 + col]);
    }
}

// ---------------------------------------------------------------------------
// Kernel A: per-node geometry -> V6 (dihedral 6), O (9), packed Ca4 (xyz+mask)
// ---------------------------------------------------------------------------
__global__ void geom_kernel(const float* __restrict__ X,
                            const float* __restrict__ mask,
                            float* __restrict__ wsO, float* __restrict__ wsV6,
                            float4* __restrict__ wsCa4)
{
    int ng = blockIdx.x * blockDim.x + threadIdx.x;
    if (ng >= BB*NN) return;
    int b = ng / NN, n = ng % NN;
    const float* Xb = X + (size_t)b * NN * 12;

    {
        const float* cp = X + (size_t)ng*12 + 3;
        wsCa4[ng] = make_float4(cp[0], cp[1], cp[2], mask[ng]);
    }

    int k0 = 3*n - 1;
    F3 P[6];
    #pragma unroll
    for (int t = 0; t < 6; ++t) {
        int m = k0 + t;
        if (m < 0) m = 0;
        if (m > 3*NN-1) m = 3*NN-1;
        int r = m / 3, a = m % 3;
        const float* p = Xb + ((size_t)r*4 + a)*3;
        P[t] = {p[0], p[1], p[2]};
    }
    F3 U[5];
    #pragma unroll
    for (int t = 0; t < 5; ++t) U[t] = f3norm(f3sub(P[t+1], P[t]));

    float Dang[3];
    #pragma unroll
    for (int t = 0; t < 3; ++t) {
        int k = k0 + t;
        if (k < 0 || k > 3*NN-4) { Dang[t] = 0.f; continue; }
        F3 u2 = U[t], u1 = U[t+1], u0 = U[t+2];
        F3 n2 = f3norm(f3cross(u2, u1));
        F3 n1 = f3norm(f3cross(u1, u0));
        float cosD = f3dot(n2, n1);
        cosD = fminf(fmaxf(cosD, -1.f + 1e-7f), 1.f - 1e-7f);
        float s = f3dot(u2, n1);
        Dang[t] = sgnf(s) * acosf(cosD);
    }
    float* v6 = wsV6 + (size_t)ng * 6;
    v6[0] = cosf(Dang[0]); v6[1] = cosf(Dang[1]); v6[2] = cosf(Dang[2]);
    v6[3] = sinf(Dang[0]); v6[4] = sinf(Dang[1]); v6[5] = sinf(Dang[2]);

    float* o = wsO + (size_t)ng * 9;
    if (n >= 1 && n <= NN-3) {
        const float* cb = X + (size_t)b * NN * 12 + 3;
        F3 c0 = {cb[(size_t)(n-1)*12+0], cb[(size_t)(n-1)*12+1], cb[(size_t)(n-1)*12+2]};
        F3 c1 = {cb[(size_t)(n  )*12+0], cb[(size_t)(n  )*12+1], cb[(size_t)(n  )*12+2]};
        F3 c2 = {cb[(size_t)(n+1)*12+0], cb[(size_t)(n+1)*12+1], cb[(size_t)(n+1)*12+2]};
        F3 u2 = f3norm(f3sub(c1, c0));
        F3 u1 = f3norm(f3sub(c2, c1));
        F3 n2 = f3norm(f3cross(u2, u1));
        F3 o1 = f3norm(f3sub(u2, u1));
        F3 r2 = f3cross(o1, n2);
        o[0]=o1.x; o[1]=o1.y; o[2]=o1.z;
        o[3]=n2.x; o[4]=n2.y; o[5]=n2.z;
        o[6]=r2.x; o[7]=r2.y; o[8]=r2.z;
    } else {
        #pragma unroll
        for (int m = 0; m < 9; ++m) o[m] = 0.f;
    }
}

// ---------------------------------------------------------------------------
// Kernel B: top-K. 4 rows per 256-thread block, one wave per row (no barriers,
// each wave owns a private 8KB LDS slice). Exact (d, j) lexicographic order
// via u64 keys (dist_bits<<32 | j) reinterpreted as positive doubles:
// v_min_f64 == unsigned 64-bit min for positive patterns -> single fmin
// butterfly per extraction. Winner-lane re-min done cooperatively by 32 lanes
// over the winner's LDS column (rotated layout, conflict-free).
// ---------------------------------------------------------------------------
#define TOPK_SENT 1.0e300

__global__ __launch_bounds__(256) void topk_kernel(
    const float4* __restrict__ wsCa4,
    int* __restrict__ wsEidx, float* __restrict__ wsDnb,
    float* __restrict__ outEidxF)
{
    __shared__ float dist[4][NN];
    const int wave = threadIdx.x >> 6, lane = threadIdx.x & 63;
    const int row = blockIdx.x*4 + wave;
    const int b = row >> 11, i = row & (NN-1);
    float* dd = dist[wave];

    const float4* cb = wsCa4 + ((size_t)b << 11);
    float4 ci = cb[i];
    float mi = ci.w;

    double lmin = TOPK_SENT;
    #pragma unroll 8
    for (int s = 0; s < NN/64; ++s) {
        int j = s*64 + lane;
        float4 cj = cb[j];
        float dx = ci.x - cj.x, dy = ci.y - cj.y, dz = ci.z - cj.z;
        float d = sqrtf(dx*dx + dy*dy + dz*dz + 1e-6f);
        d += (1.0f - mi * cj.w) * 10000.0f;
        dd[s*64 + ((lane + s) & 63)] = d;
        unsigned long long key =
            ((unsigned long long)__float_as_uint(d) << 32) | (unsigned)j;
        lmin = fmin(lmin, __longlong_as_double((long long)key));
    }

    const size_t rb = (size_t)row * KK;
    for (int k = 0; k < KK; ++k) {
        // global min over 64 lanes: one 6-step f64 butterfly (exact u64 min)
        double g = lmin;
        #pragma unroll
        for (int off = 32; off; off >>= 1)
            g = fmin(g, __shfl_xor(g, off, 64));
        unsigned long long gk = (unsigned long long)__double_as_longlong(g);
        int j = (int)(unsigned)gk;
        float dwin = __uint_as_float((unsigned)(gk >> 32));
        if (lane == 0) {
            wsEidx[rb + k] = j;
            wsDnb[rb + k]  = dwin;
            outEidxF[rb + k] = (float)j;
        }
        const int wl = j & 63, ws = j >> 6;

        // mask extracted slot (uniform address; one lane writes)
        if (lane == 0) dd[ws*64 + ((wl + ws) & 63)] = 3.402823466e+38f;
        // DS ops are wave-ordered; aliasing forces compiler ordering.

        // cooperative re-min of winner lane's 32 slots (both lane halves
        // compute the same reduction; broadcast from lane 0)
        int s = lane & 31;
        float dr = dd[s*64 + ((wl + s) & 63)];
        unsigned long long ck =
            ((unsigned long long)__float_as_uint(dr) << 32) | (unsigned)s;
        double c = __longlong_as_double((long long)ck);
        #pragma unroll
        for (int off = 16; off; off >>= 1)
            c = fmin(c, __shfl_xor(c, off, 64));
        double c0 = __shfl(c, 0, 64);
        unsigned long long ck0 = (unsigned long long)__double_as_longlong(c0);
        unsigned s2 = (unsigned)ck0;
        unsigned long long nk =
            (ck0 & 0xFFFFFFFF00000000ULL) | (unsigned)(s2*64 + wl);
        if (lane == wl) lmin = __longlong_as_double((long long)nk);
    }
}

// ---------------------------------------------------------------------------
// Kernel C: node path (unchanged)
// ---------------------------------------------------------------------------
__global__ __launch_bounds__(128) void node_kernel(
    const float* __restrict__ wsV6,
    const float* __restrict__ nlw, const float* __restrict__ nlb,
    const float* __restrict__ new_, const float* __restrict__ neb,
    const float* __restrict__ nng, const float* __restrict__ nnb,
    float* __restrict__ outV)
{
    int f = threadIdx.x;
    __shared__ float h1[128];
    __shared__ float red[2][2];

    float w2[128];
    #pragma unroll
    for (int c = 0; c < 128; ++c) w2[c] = new_[c*128 + f];
    float w1[6];
    #pragma unroll
    for (int c = 0; c < 6; ++c) w1[c] = nlw[c*128 + f];
    float b1v = nlb[f], b2v = neb[f], gv = nng[f], bv = nnb[f];

    for (int gi = 0; gi < 8; ++gi) {
        int row = blockIdx.x*8 + gi;
        float acc = b1v;
        #pragma unroll
        for (int c = 0; c < 6; ++c) acc = fmaf(wsV6[(size_t)row*6 + c], w1[c], acc);
        h1[f] = acc;
        __syncthreads();

        float a2 = b2v;
        #pragma unroll
        for (int c4 = 0; c4 < 32; ++c4) {
            float4 v = *(const float4*)&h1[c4*4];
            a2 = fmaf(v.x, w2[c4*4+0], a2);
            a2 = fmaf(v.y, w2[c4*4+1], a2);
            a2 = fmaf(v.z, w2[c4*4+2], a2);
            a2 = fmaf(v.w, w2[c4*4+3], a2);
        }
        float s = a2, ss = a2*a2;
        #pragma unroll
        for (int off = 32; off; off >>= 1) {
            s  += __shfl_xor(s,  off, 64);
            ss += __shfl_xor(ss, off, 64);
        }
        int wig = f >> 6;
        if ((f & 63) == 0) { red[wig][0] = s; red[wig][1] = ss; }
        __syncthreads();
        float S = red[0][0] + red[1][0], SS = red[0][1] + red[1][1];
        float mu = S * (1.f/128.f);
        float var = SS * (1.f/128.f) - mu*mu;
        float inv = rsqrtf(var + 1e-5f);
        outV[(size_t)row*128 + f] = (a2 - mu)*inv*gv + bv;
        __syncthreads();
    }
}

// ---------------------------------------------------------------------------
// Kernel D: edge MFMA (unchanged from round 3)
// ---------------------------------------------------------------------------
__global__ __launch_bounds__(256, 4) void edge_mfma_kernel(
    const float4* __restrict__ wsCa4,
    const int* __restrict__ ridx, const int* __restrict__ chain,
    const int* __restrict__ wsEidx, const float* __restrict__ wsDnb,
    const float* __restrict__ wsO,
    const float* __restrict__ pe_w, const float* __restrict__ pe_b,
    const __hip_bfloat16* __restrict__ wsW1, const __hip_bfloat16* __restrict__ wsW2,
    const float* __restrict__ elb, const float* __restrict__ eeb,
    const float* __restrict__ lng, const float* __restrict__ lnb,
    float* __restrict__ outE)
{
    __shared__ char smem[64*72*2 + 64*136*2];
    short* Ef  = (short*)smem;
    short* h1t = (short*)(smem + 64*72*2);
    float* redS  = (float*)smem;
    float* redSS = (float*)(smem + 512);

    const int tid  = threadIdx.x;
    const int wave = tid >> 6, lane = tid & 63;
    const int wm = wave >> 1, wn = wave & 1;
    const int lr = lane & 15, lk = lane >> 4;

    float b1v[4], b2v[4], gv[4], bv[4];
    #pragma unroll
    for (int nf = 0; nf < 4; ++nf) {
        int col = wn*64 + nf*16 + lr;
        b1v[nf] = elb[col]; b2v[nf] = eeb[col];
        gv[nf]  = lng[col]; bv[nf]  = lnb[col];
    }

    for (int idx = tid; idx < 64*25; idx += 256) {
        int r = idx / 25, c = 39 + idx % 25;
        Ef[r*72 + c] = 0;
    }

    const int E0 = blockIdx.x * 64;

    if (wave == 0) {
        int ge = E0 + lane;
        int row = ge / KK;
        int b = row >> 11;
        int j = wsEidx[ge];
        float oi[9], oj[9];
        #pragma unroll
        for (int m = 0; m < 9; ++m) {
            oi[m] = wsO[(size_t)row*9 + m];
            oj[m] = wsO[((size_t)(b*NN) + j)*9 + m];
        }
        float4 ci = wsCa4[row];
        float4 cj = wsCa4[(size_t)b*NN + j];
        float dx = cj.x-ci.x, dy = cj.y-ci.y, dz = cj.z-ci.z;
        float t0 = oi[0]*dx + oi[1]*dy + oi[2]*dz;
        float t1 = oi[3]*dx + oi[4]*dy + oi[5]*dz;
        float t2 = oi[6]*dx + oi[7]*dy + oi[8]*dz;
        float nr = sqrtf(t0*t0 + t1*t1 + t2*t2);
        float iv = 1.f/(nr + 1e-8f);
        short* ef = &Ef[lane*72];
        ef[32] = f2bf(t0*iv); ef[33] = f2bf(t1*iv); ef[34] = f2bf(t2*iv);
        float R00 = oi[0]*oj[0]+oi[3]*oj[3]+oi[6]*oj[6];
        float R01 = oi[0]*oj[1]+oi[3]*oj[4]+oi[6]*oj[7];
        float R02 = oi[0]*oj[2]+oi[3]*oj[5]+oi[6]*oj[8];
        float R10 = oi[1]*oj[0]+oi[4]*oj[3]+oi[7]*oj[6];
        float R11 = oi[1]*oj[1]+oi[4]*oj[4]+oi[7]*oj[7];
        float R12 = oi[1]*oj[2]+oi[4]*oj[5]+oi[7]*oj[8];
        float R20 = oi[2]*oj[0]+oi[5]*oj[3]+oi[8]*oj[6];
        float R21 = oi[2]*oj[1]+oi[5]*oj[4]+oi[8]*oj[7];
        float R22 = oi[2]*oj[2]+oi[5]*oj[5]+oi[8]*oj[8];
        float mx = 0.5f*sqrtf(fabsf(1.f + R00 - R11 - R22));
        float my = 0.5f*sqrtf(fabsf(1.f - R00 + R11 - R22));
        float mz = 0.5f*sqrtf(fabsf(1.f - R00 - R11 + R22));
        float qx = sgnf(R21 - R12)*mx;
        float qy = sgnf(R02 - R20)*my;
        float qz = sgnf(R10 - R01)*mz;
        float qw = 0.5f*sqrtf(fmaxf(0.f, 1.f + R00 + R11 + R22));
        float qn = sqrtf(qx*qx + qy*qy + qz*qz + qw*qw);
        float qi = 1.f/(qn + 1e-8f);
        ef[35] = f2bf(qx*qi); ef[36] = f2bf(qy*qi);
        ef[37] = f2bf(qz*qi); ef[38] = f2bf(qw*qi);
    } else if (wave == 1) {
        int ge = E0 + lane;
        float dnb = wsDnb[ge];
        short* ef = &Ef[lane*72 + 16];
        #pragma unroll
        for (int m = 0; m < 16; ++m) {
            float mu = 2.f + (20.f/15.f)*(float)m;
            float z = (dnb - mu) * 0.8f;
            ef[m] = f2bf(expf(-z*z));
        }
    } else if (wave == 2) {
        int ge = E0 + lane;
        int row = ge / KK;
        int b = row >> 11;
        int j = wsEidx[ge];
        int ri = ridx[row], rj = ridx[b*NN + j];
        int ch = (chain[row] == chain[b*NN + j]) ? 1 : 0;
        int dd = min(max(ri - rj + MAXREL, 0), 2*MAXREL);
        dd = ch ? dd : (2*MAXREL + 1);
        short* ef = &Ef[lane*72];
        #pragma unroll
        for (int m = 0; m < 16; ++m) ef[m] = f2bf(pe_w[dd*16 + m] + pe_b[m]);
    }
    __syncthreads();

    const bf16x8* W1f = (const bf16x8*)wsW1;
    const bf16x8* W2f = (const bf16x8*)wsW2;

    f32x4 acc[2][4];
    #pragma unroll
    for (int mf = 0; mf < 2; ++mf)
        #pragma unroll
        for (int nf = 0; nf < 4; ++nf)
            acc[mf][nf] = (f32x4){0.f, 0.f, 0.f, 0.f};
    #pragma unroll
    for (int ks = 0; ks < 2; ++ks) {
        bf16x8 a0 = *(const bf16x8*)&Ef[(wm*32      + lr)*72 + ks*32 + lk*8];
        bf16x8 a1 = *(const bf16x8*)&Ef[(wm*32 + 16 + lr)*72 + ks*32 + lk*8];
        #pragma unroll
        for (int nf = 0; nf < 4; ++nf) {
            bf16x8 Bf = W1f[((wn*4 + nf)*2 + ks)*64 + lane];
            acc[0][nf] = MFMA16(a0, Bf, acc[0][nf]);
            acc[1][nf] = MFMA16(a1, Bf, acc[1][nf]);
        }
    }
    #pragma unroll
    for (int mf = 0; mf < 2; ++mf)
        #pragma unroll
        for (int nf = 0; nf < 4; ++nf)
            #pragma unroll
            for (int r = 0; r < 4; ++r) {
                int row = wm*32 + mf*16 + lk*4 + r;
                int col = wn*64 + nf*16 + lr;
                h1t[row*136 + col] = f2bf(acc[mf][nf][r] + b1v[nf]);
            }
    __syncthreads();

    f32x4 acc2[2][4];
    #pragma unroll
    for (int mf = 0; mf < 2; ++mf)
        #pragma unroll
        for (int nf = 0; nf < 4; ++nf)
            acc2[mf][nf] = (f32x4){0.f, 0.f, 0.f, 0.f};
    #pragma unroll
    for (int ks = 0; ks < 4; ++ks) {
        bf16x8 a0 = *(const bf16x8*)&h1t[(wm*32      + lr)*136 + ks*32 + lk*8];
        bf16x8 a1 = *(const bf16x8*)&h1t[(wm*32 + 16 + lr)*136 + ks*32 + lk*8];
        #pragma unroll
        for (int nf = 0; nf < 4; ++nf) {
            bf16x8 Bf = W2f[((wn*4 + nf)*4 + ks)*64 + lane];
            acc2[0][nf] = MFMA16(a0, Bf, acc2[0][nf]);
            acc2[1][nf] = MFMA16(a1, Bf, acc2[1][nf]);
        }
    }
    #pragma unroll
    for (int mf = 0; mf < 2; ++mf)
        #pragma unroll
        for (int nf = 0; nf < 4; ++nf)
            #pragma unroll
            for (int r = 0; r < 4; ++r)
                acc2[mf][nf][r] += b2v[nf];

    #pragma unroll
    for (int mf = 0; mf < 2; ++mf) {
        #pragma unroll
        for (int r = 0; r < 4; ++r) {
            float v0 = acc2[mf][0][r], v1 = acc2[mf][1][r];
            float v2 = acc2[mf][2][r], v3 = acc2[mf][3][r];
            float s = v0 + v1 + v2 + v3;
            float q = v0*v0 + v1*v1 + v2*v2 + v3*v3;
            #pragma unroll
            for (int off = 1; off < 16; off <<= 1) {
                s += __shfl_xor(s, off, 64);
                q += __shfl_xor(q, off, 64);
            }
            if (lr == 0) {
                int row = wm*32 + mf*16 + lk*4 + r;
                redS[row*2 + wn] = s; redSS[row*2 + wn] = q;
            }
        }
    }
    __syncthreads();

    const size_t obase = (size_t)E0 * 128;
    #pragma unroll
    for (int mf = 0; mf < 2; ++mf) {
        #pragma unroll
        for (int r = 0; r < 4; ++r) {
            int row = wm*32 + mf*16 + lk*4 + r;
            float S = redS[row*2 + 0] + redS[row*2 + 1];
            float Q = redSS[row*2 + 0] + redSS[row*2 + 1];
            float mu = S * (1.f/128.f);
            float var = Q * (1.f/128.f) - mu*mu;
            float inv = rsqrtf(var + 1e-5f);
            #pragma unroll
            for (int nf = 0; nf < 4; ++nf) {
                int col = wn*64 + nf*16 + lr;
                outE[obase + (size_t)row*128 + col] =
                    (acc2[mf][nf][r] - mu)*inv*gv[nf] + bv[nf];
            }
        }
    }
}

// ---------------------------------------------------------------------------
extern "C" void kernel_launch(void* const* d_in, const int* in_sizes, int n_in,
                              void* d_out, int out_size, void* d_ws, size_t ws_size,
                              hipStream_t stream)
{
    const float* X     = (const float*)d_in[0];
    const float* mask  = (const float*)d_in[1];
    const int*   ridx  = (const int*)  d_in[2];
    const int*   chain = (const int*)  d_in[3];
    const float* pe_w  = (const float*)d_in[4];
    const float* pe_b  = (const float*)d_in[5];
    const float* nlw   = (const float*)d_in[6];
    const float* nlb   = (const float*)d_in[7];
    const float* new_  = (const float*)d_in[8];
    const float* neb   = (const float*)d_in[9];
    const float* elw   = (const float*)d_in[10];
    const float* elb   = (const float*)d_in[11];
    const float* eew   = (const float*)d_in[12];
    const float* eeb   = (const float*)d_in[13];
    const float* nng   = (const float*)d_in[14];
    const float* nnb   = (const float*)d_in[15];
    const float* neg_  = (const float*)d_in[16];
    const float* neb_  = (const float*)d_in[17];

    float* out = (float*)d_out;
    char*  ws  = (char*)d_ws;
    int*    wsEidx = (int*)   (ws + WS_EIDX_OFF);
    float*  wsDnb  = (float*) (ws + WS_DNB_OFF);
    float*  wsO    = (float*) (ws + WS_O_OFF);
    float*  wsV6   = (float*) (ws + WS_V6_OFF);
    float4* wsCa4  = (float4*)(ws + WS_CA4_OFF);
    __hip_bfloat16* wsW1 = (__hip_bfloat16*)(ws + WS_W1_OFF);
    __hip_bfloat16* wsW2 = (__hip_bfloat16*)(ws + WS_W2_OFF);

    prep_kernel<<<96, 256, 0, stream>>>(elw, eew, wsW1, wsW2);
    geom_kernel<<<(BB*NN + 255)/256, 256, 0, stream>>>(X, mask, wsO, wsV6, wsCa4);
    topk_kernel<<<BB*NN/4, 256, 0, stream>>>(wsCa4, wsEidx, wsDnb, out + EIDX_OUT_OFF);
    node_kernel<<<BB*NN/8, 128, 0, stream>>>(wsV6, nlw, nlb, new_, neb, nng, nnb, out);
    edge_mfma_kernel<<<BB*NN*KK/64, 256, 0, stream>>>(wsCa4, ridx, chain, wsEidx, wsDnb, wsO,
                                                      pe_w, pe_b, wsW1, wsW2,
                                                      elb, eeb, neg_, neb_, out + E_OUT_OFF);
}

// Round 5
// 201.963 us; speedup vs baseline: 3.9056x; 1.1886x over previous
//
#include <hip/hip_runtime.h>
#include <hip/hip_bf16.h>
#include <math.h>

#define BB 8
#define NN 2048
#define KK 30
#define NF 128
#define EF 128
#define NPE 16
#define NRBF 16
#define MAXREL 32

#define V_OUT_SZ   (BB*NN*NF)
#define E_OUT_OFF  (V_OUT_SZ)
#define E_OUT_SZ   (BB*NN*KK*EF)
#define EIDX_OUT_OFF (E_OUT_OFF + E_OUT_SZ)

// workspace byte offsets
#define WS_EIDX_OFF 0                       // int[B*N*K]
#define WS_DNB_OFF  1966080                 // float[B*N*K]
#define WS_O_OFF    3932160                 // float[B*N*9]
#define WS_V6_OFF   4521984                 // float[B*N*6]
#define WS_CA4_OFF  4915200                 // float4[B*N]      (Ca.xyz, mask)
#define WS_W1_OFF   5177344                 // bf16[8192]   L1 frags
#define WS_W2_OFF   5193728                 // bf16[16384]  L2 frags
// end 5226496

typedef __attribute__((ext_vector_type(8))) short bf16x8;
typedef __attribute__((ext_vector_type(4))) float f32x4;
#define MFMA16(a,b,c) __builtin_amdgcn_mfma_f32_16x16x32_bf16(a,b,c,0,0,0)

struct F3 { float x, y, z; };
__device__ inline F3 f3sub(F3 a, F3 b){ return {a.x-b.x, a.y-b.y, a.z-b.z}; }
__device__ inline F3 f3cross(F3 a, F3 b){ return {a.y*b.z - a.z*b.y, a.z*b.x - a.x*b.z, a.x*b.y - a.y*b.x}; }
__device__ inline float f3dot(F3 a, F3 b){ return a.x*b.x + a.y*b.y + a.z*b.z; }
__device__ inline F3 f3norm(F3 v){
    float n = sqrtf(f3dot(v, v));
    float r = 1.0f/(n + 1e-8f);
    return {v.x*r, v.y*r, v.z*r};
}
__device__ inline float sgnf(float x){ return (x>0.f)?1.f:((x<0.f)?-1.f:0.f); }
__device__ inline short f2bf(float f){
    union { __hip_bfloat16 h; short s; } u;
    u.h = __float2bfloat16(f);
    return u.s;
}

// ---------------------------------------------------------------------------
// VALU-only cross-lane u64-key min helpers (keys are positive-double packed
// (dist_bits<<32 | idx); positive doubles order like their bit patterns).
// DPP handles xor 1/2/4/8 within 16-lane rows (rotate-combine), gfx950
// permlane16/32_swap handle the row/half exchanges. ZERO DS-pipe traffic.
// ---------------------------------------------------------------------------
template<int CTRL>
__device__ __forceinline__ double kmin_dpp(double key){
    int hi = __double2hiint(key), lo = __double2loint(key);
    int ohi = __builtin_amdgcn_update_dpp(hi, hi, CTRL, 0xf, 0xf, false);
    int olo = __builtin_amdgcn_update_dpp(lo, lo, CTRL, 0xf, 0xf, false);
    return fmin(key, __hiloint2double(ohi, olo));
}

#if __has_builtin(__builtin_amdgcn_permlane16_swap)
__device__ __forceinline__ double kmin_x16(double key){
    unsigned hi = (unsigned)__double2hiint(key), lo = (unsigned)__double2loint(key);
    auto rh = __builtin_amdgcn_permlane16_swap(hi, hi, false, false);
    auto rl = __builtin_amdgcn_permlane16_swap(lo, lo, false, false);
    // fed (x,x), results are {x[lane], x[lane^16]} in some order; min of both
    // with key is ordering-agnostic (min with self is a no-op).
    double a = __hiloint2double((int)rh[0], (int)rl[0]);
    double b = __hiloint2double((int)rh[1], (int)rl[1]);
    return fmin(key, fmin(a, b));
}
#else
__device__ __forceinline__ double kmin_x16(double key){
    int hi = __double2hiint(key), lo = __double2loint(key);
    int ohi = __builtin_amdgcn_ds_swizzle(hi, 0x401F);   // xor 16, BitMode
    int olo = __builtin_amdgcn_ds_swizzle(lo, 0x401F);
    return fmin(key, __hiloint2double(ohi, olo));
}
#endif

#if __has_builtin(__builtin_amdgcn_permlane32_swap)
__device__ __forceinline__ double kmin_x32(double key){
    unsigned hi = (unsigned)__double2hiint(key), lo = (unsigned)__double2loint(key);
    auto rh = __builtin_amdgcn_permlane32_swap(hi, hi, false, false);
    auto rl = __builtin_amdgcn_permlane32_swap(lo, lo, false, false);
    double a = __hiloint2double((int)rh[0], (int)rl[0]);
    double b = __hiloint2double((int)rh[1], (int)rl[1]);
    return fmin(key, fmin(a, b));
}
#else
__device__ __forceinline__ double kmin_x32(double key){
    return fmin(key, __shfl_xor(key, 32, 64));
}
#endif

__device__ __forceinline__ double wave_min64(double k){
    k = kmin_dpp<0xB1>(k);    // quad_perm [1,0,3,2] : xor 1
    k = kmin_dpp<0x4E>(k);    // quad_perm [2,3,0,1] : xor 2
    k = kmin_dpp<0x124>(k);   // row_ror:4
    k = kmin_dpp<0x128>(k);   // row_ror:8
    k = kmin_x16(k);
    k = kmin_x32(k);
    return k;                 // all 64 lanes hold the global min
}

__device__ __forceinline__ double half_min32(double k){
    k = kmin_dpp<0xB1>(k);
    k = kmin_dpp<0x4E>(k);
    k = kmin_dpp<0x124>(k);
    k = kmin_dpp<0x128>(k);
    k = kmin_x16(k);
    return k;                 // min within each 32-lane half
}

// ---------------------------------------------------------------------------
// Kernel P: pre-convert edge-MLP weights into bf16 MFMA-fragment order.
// ---------------------------------------------------------------------------
__global__ void prep_kernel(const float* __restrict__ elw,
                            const float* __restrict__ eew,
                            __hip_bfloat16* __restrict__ w1,
                            __hip_bfloat16* __restrict__ w2)
{
    int i = blockIdx.x*256 + threadIdx.x;
    if (i < 8192) {
        int j = i & 7, lane = (i>>3)&63, ks = (i>>9)&1, nf = i>>10;
        int k = ks*32 + (lane>>4)*8 + j;
        int col = nf*16 + (lane&15);
        float v = (k < 39) ? elw[k*128 + col] : 0.f;
        w1[i] = __float2bfloat16(v);
    } else if (i < 8192 + 16384) {
        int i2 = i - 8192;
        int j = i2 & 7, lane = (i2>>3)&63, ks = (i2>>9)&3, nf = i2>>11;
        int k = ks*32 + (lane>>4)*8 + j;
        int col = nf*16 + (lane&15);
        w2[i2] = __float2bfloat16(eew[k*128 + col]);
    }
}

// ---------------------------------------------------------------------------
// Kernel A: per-node geometry -> V6 (dihedral 6), O (9), packed Ca4 (xyz+mask)
// ---------------------------------------------------------------------------
__global__ void geom_kernel(const float* __restrict__ X,
                            const float* __restrict__ mask,
                            float* __restrict__ wsO, float* __restrict__ wsV6,
                            float4* __restrict__ wsCa4)
{
    int ng = blockIdx.x * blockDim.x + threadIdx.x;
    if (ng >= BB*NN) return;
    int b = ng / NN, n = ng % NN;
    const float* Xb = X + (size_t)b * NN * 12;

    {
        const float* cp = X + (size_t)ng*12 + 3;
        wsCa4[ng] = make_float4(cp[0], cp[1], cp[2], mask[ng]);
    }

    int k0 = 3*n - 1;
    F3 P[6];
    #pragma unroll
    for (int t = 0; t < 6; ++t) {
        int m = k0 + t;
        if (m < 0) m = 0;
        if (m > 3*NN-1) m = 3*NN-1;
        int r = m / 3, a = m % 3;
        const float* p = Xb + ((size_t)r*4 + a)*3;
        P[t] = {p[0], p[1], p[2]};
    }
    F3 U[5];
    #pragma unroll
    for (int t = 0; t < 5; ++t) U[t] = f3norm(f3sub(P[t+1], P[t]));

    float Dang[3];
    #pragma unroll
    for (int t = 0; t < 3; ++t) {
        int k = k0 + t;
        if (k < 0 || k > 3*NN-4) { Dang[t] = 0.f; continue; }
        F3 u2 = U[t], u1 = U[t+1], u0 = U[t+2];
        F3 n2 = f3norm(f3cross(u2, u1));
        F3 n1 = f3norm(f3cross(u1, u0));
        float cosD = f3dot(n2, n1);
        cosD = fminf(fmaxf(cosD, -1.f + 1e-7f), 1.f - 1e-7f);
        float s = f3dot(u2, n1);
        Dang[t] = sgnf(s) * acosf(cosD);
    }
    float* v6 = wsV6 + (size_t)ng * 6;
    v6[0] = cosf(Dang[0]); v6[1] = cosf(Dang[1]); v6[2] = cosf(Dang[2]);
    v6[3] = sinf(Dang[0]); v6[4] = sinf(Dang[1]); v6[5] = sinf(Dang[2]);

    float* o = wsO + (size_t)ng * 9;
    if (n >= 1 && n <= NN-3) {
        const float* cb = X + (size_t)b * NN * 12 + 3;
        F3 c0 = {cb[(size_t)(n-1)*12+0], cb[(size_t)(n-1)*12+1], cb[(size_t)(n-1)*12+2]};
        F3 c1 = {cb[(size_t)(n  )*12+0], cb[(size_t)(n  )*12+1], cb[(size_t)(n  )*12+2]};
        F3 c2 = {cb[(size_t)(n+1)*12+0], cb[(size_t)(n+1)*12+1], cb[(size_t)(n+1)*12+2]};
        F3 u2 = f3norm(f3sub(c1, c0));
        F3 u1 = f3norm(f3sub(c2, c1));
        F3 n2 = f3norm(f3cross(u2, u1));
        F3 o1 = f3norm(f3sub(u2, u1));
        F3 r2 = f3cross(o1, n2);
        o[0]=o1.x; o[1]=o1.y; o[2]=o1.z;
        o[3]=n2.x; o[4]=n2.y; o[5]=n2.z;
        o[6]=r2.x; o[7]=r2.y; o[8]=r2.z;
    } else {
        #pragma unroll
        for (int m = 0; m < 9; ++m) o[m] = 0.f;
    }
}

// ---------------------------------------------------------------------------
// Kernel B: top-K. 4 rows per 256-thread block, one wave per row (no barriers,
// each wave owns a private 8KB LDS slice). Exact (d, j) lexicographic order
// via u64 keys as positive doubles; all reductions on the VALU pipe (DPP +
// permlane swaps) -> only 2 DS ops per extraction round.
// ---------------------------------------------------------------------------
#define TOPK_SENT 1.0e300

__global__ __launch_bounds__(256) void topk_kernel(
    const float4* __restrict__ wsCa4,
    int* __restrict__ wsEidx, float* __restrict__ wsDnb,
    float* __restrict__ outEidxF)
{
    __shared__ float dist[4][NN];
    const int wave = threadIdx.x >> 6, lane = threadIdx.x & 63;
    const int row = blockIdx.x*4 + wave;
    const int b = row >> 11, i = row & (NN-1);
    float* dd = dist[wave];

    const float4* cb = wsCa4 + ((size_t)b << 11);
    float4 ci = cb[i];
    float mi = ci.w;

    double lmin = TOPK_SENT;
    #pragma unroll 8
    for (int s = 0; s < NN/64; ++s) {
        int j = s*64 + lane;
        float4 cj = cb[j];
        float dx = ci.x - cj.x, dy = ci.y - cj.y, dz = ci.z - cj.z;
        float d = sqrtf(dx*dx + dy*dy + dz*dz + 1e-6f);
        d += (1.0f - mi * cj.w) * 10000.0f;
        dd[s*64 + ((lane + s) & 63)] = d;
        unsigned long long key =
            ((unsigned long long)__float_as_uint(d) << 32) | (unsigned)j;
        lmin = fmin(lmin, __longlong_as_double((long long)key));
    }

    const size_t rb = (size_t)row * KK;
    for (int k = 0; k < KK; ++k) {
        // global min over 64 lanes, result in ALL lanes (VALU-only butterfly)
        double g = wave_min64(lmin);
        unsigned long long gk = (unsigned long long)__double_as_longlong(g);
        int j = (int)(unsigned)gk;
        float dwin = __uint_as_float((unsigned)(gk >> 32));
        if (lane == 0) {
            wsEidx[rb + k] = j;
            wsDnb[rb + k]  = dwin;
            outEidxF[rb + k] = (float)j;
        }
        const int wl = j & 63, wslot = j >> 6;

        // mask extracted slot (uniform address; one lane writes)
        if (lane == 0) dd[wslot*64 + ((wl + wslot) & 63)] = 3.402823466e+38f;
        // DS ops are wave-ordered; aliasing forces compiler ordering.

        // cooperative re-min of winner lane's 32 slots: both 32-lane halves
        // read identical data, so half_min32 leaves the full min in all lanes
        int s = lane & 31;
        float dr = dd[s*64 + ((wl + s) & 63)];
        unsigned long long ck =
            ((unsigned long long)__float_as_uint(dr) << 32) | (unsigned)s;
        double c = half_min32(__longlong_as_double((long long)ck));
        unsigned long long ck0 = (unsigned long long)__double_as_longlong(c);
        unsigned s2 = (unsigned)ck0;
        unsigned long long nk =
            (ck0 & 0xFFFFFFFF00000000ULL) | (unsigned)(s2*64 + wl);
        if (lane == wl) lmin = __longlong_as_double((long long)nk);
    }
}

// ---------------------------------------------------------------------------
// Kernel C: node path (unchanged)
// ---------------------------------------------------------------------------
__global__ __launch_bounds__(128) void node_kernel(
    const float* __restrict__ wsV6,
    const float* __restrict__ nlw, const float* __restrict__ nlb,
    const float* __restrict__ new_, const float* __restrict__ neb,
    const float* __restrict__ nng, const float* __restrict__ nnb,
    float* __restrict__ outV)
{
    int f = threadIdx.x;
    __shared__ float h1[128];
    __shared__ float red[2][2];

    float w2[128];
    #pragma unroll
    for (int c = 0; c < 128; ++c) w2[c] = new_[c*128 + f];
    float w1[6];
    #pragma unroll
    for (int c = 0; c < 6; ++c) w1[c] = nlw[c*128 + f];
    float b1v = nlb[f], b2v = neb[f], gv = nng[f], bv = nnb[f];

    for (int gi = 0; gi < 8; ++gi) {
        int row = blockIdx.x*8 + gi;
        float acc = b1v;
        #pragma unroll
        for (int c = 0; c < 6; ++c) acc = fmaf(wsV6[(size_t)row*6 + c], w1[c], acc);
        h1[f] = acc;
        __syncthreads();

        float a2 = b2v;
        #pragma unroll
        for (int c4 = 0; c4 < 32; ++c4) {
            float4 v = *(const float4*)&h1[c4*4];
            a2 = fmaf(v.x, w2[c4*4+0], a2);
            a2 = fmaf(v.y, w2[c4*4+1], a2);
            a2 = fmaf(v.z, w2[c4*4+2], a2);
            a2 = fmaf(v.w, w2[c4*4+3], a2);
        }
        float s = a2, ss = a2*a2;
        #pragma unroll
        for (int off = 32; off; off >>= 1) {
            s  += __shfl_xor(s,  off, 64);
            ss += __shfl_xor(ss, off, 64);
        }
        int wig = f >> 6;
        if ((f & 63) == 0) { red[wig][0] = s; red[wig][1] = ss; }
        __syncthreads();
        float S = red[0][0] + red[1][0], SS = red[0][1] + red[1][1];
        float mu = S * (1.f/128.f);
        float var = SS * (1.f/128.f) - mu*mu;
        float inv = rsqrtf(var + 1e-5f);
        outV[(size_t)row*128 + f] = (a2 - mu)*inv*gv + bv;
        __syncthreads();
    }
}

// ---------------------------------------------------------------------------
// Kernel D: edge MFMA (unchanged)
// ---------------------------------------------------------------------------
__global__ __launch_bounds__(256, 4) void edge_mfma_kernel(
    const float4* __restrict__ wsCa4,
    const int* __restrict__ ridx, const int* __restrict__ chain,
    const int* __restrict__ wsEidx, const float* __restrict__ wsDnb,
    const float* __restrict__ wsO,
    const float* __restrict__ pe_w, const float* __restrict__ pe_b,
    const __hip_bfloat16* __restrict__ wsW1, const __hip_bfloat16* __restrict__ wsW2,
    const float* __restrict__ elb, const float* __restrict__ eeb,
    const float* __restrict__ lng, const float* __restrict__ lnb,
    float* __restrict__ outE)
{
    __shared__ char smem[64*72*2 + 64*136*2];
    short* Ef  = (short*)smem;
    short* h1t = (short*)(smem + 64*72*2);
    float* redS  = (float*)smem;
    float* redSS = (float*)(smem + 512);

    const int tid  = threadIdx.x;
    const int wave = tid >> 6, lane = tid & 63;
    const int wm = wave >> 1, wn = wave & 1;
    const int lr = lane & 15, lk = lane >> 4;

    float b1v[4], b2v[4], gv[4], bv[4];
    #pragma unroll
    for (int nf = 0; nf < 4; ++nf) {
        int col = wn*64 + nf*16 + lr;
        b1v[nf] = elb[col]; b2v[nf] = eeb[col];
        gv[nf]  = lng[col]; bv[nf]  = lnb[col];
    }

    for (int idx = tid; idx < 64*25; idx += 256) {
        int r = idx / 25, c = 39 + idx % 25;
        Ef[r*72 + c] = 0;
    }

    const int E0 = blockIdx.x * 64;

    if (wave == 0) {
        int ge = E0 + lane;
        int row = ge / KK;
        int b = row >> 11;
        int j = wsEidx[ge];
        float oi[9], oj[9];
        #pragma unroll
        for (int m = 0; m < 9; ++m) {
            oi[m] = wsO[(size_t)row*9 + m];
            oj[m] = wsO[((size_t)(b*NN) + j)*9 + m];
        }
        float4 ci = wsCa4[row];
        float4 cj = wsCa4[(size_t)b*NN + j];
        float dx = cj.x-ci.x, dy = cj.y-ci.y, dz = cj.z-ci.z;
        float t0 = oi[0]*dx + oi[1]*dy + oi[2]*dz;
        float t1 = oi[3]*dx + oi[4]*dy + oi[5]*dz;
        float t2 = oi[6]*dx + oi[7]*dy + oi[8]*dz;
        float nr = sqrtf(t0*t0 + t1*t1 + t2*t2);
        float iv = 1.f/(nr + 1e-8f);
        short* ef = &Ef[lane*72];
        ef[32] = f2bf(t0*iv); ef[33] = f2bf(t1*iv); ef[34] = f2bf(t2*iv);
        float R00 = oi[0]*oj[0]+oi[3]*oj[3]+oi[6]*oj[6];
        float R01 = oi[0]*oj[1]+oi[3]*oj[4]+oi[6]*oj[7];
        float R02 = oi[0]*oj[2]+oi[3]*oj[5]+oi[6]*oj[8];
        float R10 = oi[1]*oj[0]+oi[4]*oj[3]+oi[7]*oj[6];
        float R11 = oi[1]*oj[1]+oi[4]*oj[4]+oi[7]*oj[7];
        float R12 = oi[1]*oj[2]+oi[4]*oj[5]+oi[7]*oj[8];
        float R20 = oi[2]*oj[0]+oi[5]*oj[3]+oi[8]*oj[6];
        float R21 = oi[2]*oj[1]+oi[5]*oj[4]+oi[8]*oj[7];
        float R22 = oi[2]*oj[2]+oi[5]*oj[5]+oi[8]*oj[8];
        float mx = 0.5f*sqrtf(fabsf(1.f + R00 - R11 - R22));
        float my = 0.5f*sqrtf(fabsf(1.f - R00 + R11 - R22));
        float mz = 0.5f*sqrtf(fabsf(1.f - R00 - R11 + R22));
        float qx = sgnf(R21 - R12)*mx;
        float qy = sgnf(R02 - R20)*my;
        float qz = sgnf(R10 - R01)*mz;
        float qw = 0.5f*sqrtf(fmaxf(0.f, 1.f + R00 + R11 + R22));
        float qn = sqrtf(qx*qx + qy*qy + qz*qz + qw*qw);
        float qi = 1.f/(qn + 1e-8f);
        ef[35] = f2bf(qx*qi); ef[36] = f2bf(qy*qi);
        ef[37] = f2bf(qz*qi); ef[38] = f2bf(qw*qi);
    } else if (wave == 1) {
        int ge = E0 + lane;
        float dnb = wsDnb[ge];
        short* ef = &Ef[lane*72 + 16];
        #pragma unroll
        for (int m = 0; m < 16; ++m) {
            float mu = 2.f + (20.f/15.f)*(float)m;
            float z = (dnb - mu) * 0.8f;
            ef[m] = f2bf(expf(-z*z));
        }
    } else if (wave == 2) {
        int ge = E0 + lane;
        int row = ge / KK;
        int b = row >> 11;
        int j = wsEidx[ge];
        int ri = ridx[row], rj = ridx[b*NN + j];
        int ch = (chain[row] == chain[b*NN + j]) ? 1 : 0;
        int dd = min(max(ri - rj + MAXREL, 0), 2*MAXREL);
        dd = ch ? dd : (2*MAXREL + 1);
        short* ef = &Ef[lane*72];
        #pragma unroll
        for (int m = 0; m < 16; ++m) ef[m] = f2bf(pe_w[dd*16 + m] + pe_b[m]);
    }
    __syncthreads();

    const bf16x8* W1f = (const bf16x8*)wsW1;
    const bf16x8* W2f = (const bf16x8*)wsW2;

    f32x4 acc[2][4];
    #pragma unroll
    for (int mf = 0; mf < 2; ++mf)
        #pragma unroll
        for (int nf = 0; nf < 4; ++nf)
            acc[mf][nf] = (f32x4){0.f, 0.f, 0.f, 0.f};
    #pragma unroll
    for (int ks = 0; ks < 2; ++ks) {
        bf16x8 a0 = *(const bf16x8*)&Ef[(wm*32      + lr)*72 + ks*32 + lk*8];
        bf16x8 a1 = *(const bf16x8*)&Ef[(wm*32 + 16 + lr)*72 + ks*32 + lk*8];
        #pragma unroll
        for (int nf = 0; nf < 4; ++nf) {
            bf16x8 Bf = W1f[((wn*4 + nf)*2 + ks)*64 + lane];
            acc[0][nf] = MFMA16(a0, Bf, acc[0][nf]);
            acc[1][nf] = MFMA16(a1, Bf, acc[1][nf]);
        }
    }
    #pragma unroll
    for (int mf = 0; mf < 2; ++mf)
        #pragma unroll
        for (int nf = 0; nf < 4; ++nf)
            #pragma unroll
            for (int r = 0; r < 4; ++r) {
                int row = wm*32 + mf*16 + lk*4 + r;
                int col = wn*64 + nf*16 + lr;
                h1t[row*136 + col] = f2bf(acc[mf][nf][r] + b1v[nf]);
            }
    __syncthreads();

    f32x4 acc2[2][4];
    #pragma unroll
    for (int mf = 0; mf < 2; ++mf)
        #pragma unroll
        for (int nf = 0; nf < 4; ++nf)
            acc2[mf][nf] = (f32x4){0.f, 0.f, 0.f, 0.f};
    #pragma unroll
    for (int ks = 0; ks < 4; ++ks) {
        bf16x8 a0 = *(const bf16x8*)&h1t[(wm*32      + lr)*136 + ks*32 + lk*8];
        bf16x8 a1 = *(const bf16x8*)&h1t[(wm*32 + 16 + lr)*136 + ks*32 + lk*8];
        #pragma unroll
        for (int nf = 0; nf < 4; ++nf) {
            bf16x8 Bf = W2f[((wn*4 + nf)*4 + ks)*64 + lane];
            acc2[0][nf] = MFMA16(a0, Bf, acc2[0][nf]);
            acc2[1][nf] = MFMA16(a1, Bf, acc2[1][nf]);
        }
    }
    #pragma unroll
    for (int mf = 0; mf < 2; ++mf)
        #pragma unroll
        for (int nf = 0; nf < 4; ++nf)
            #pragma unroll
            for (int r = 0; r < 4; ++r)
                acc2[mf][nf][r] += b2v[nf];

    #pragma unroll
    for (int mf = 0; mf < 2; ++mf) {
        #pragma unroll
        for (int r = 0; r < 4; ++r) {
            float v0 = acc2[mf][0][r], v1 = acc2[mf][1][r];
            float v2 = acc2[mf][2][r], v3 = acc2[mf][3][r];
            float s = v0 + v1 + v2 + v3;
            float q = v0*v0 + v1*v1 + v2*v2 + v3*v3;
            #pragma unroll
            for (int off = 1; off < 16; off <<= 1) {
                s += __shfl_xor(s, off, 64);
                q += __shfl_xor(q, off, 64);
            }
            if (lr == 0) {
                int row = wm*32 + mf*16 + lk*4 + r;
                redS[row*2 + wn] = s; redSS[row*2 + wn] = q;
            }
        }
    }
    __syncthreads();

    const size_t obase = (size_t)E0 * 128;
    #pragma unroll
    for (int mf = 0; mf < 2; ++mf) {
        #pragma unroll
        for (int r = 0; r < 4; ++r) {
            int row = wm*32 + mf*16 + lk*4 + r;
            float S = redS[row*2 + 0] + redS[row*2 + 1];
            float Q = redSS[row*2 + 0] + redSS[row*2 + 1];
            float mu = S * (1.f/128.f);
            float var = Q * (1.f/128.f) - mu*mu;
            float inv = rsqrtf(var + 1e-5f);
            #pragma unroll
            for (int nf = 0; nf < 4; ++nf) {
                int col = wn*64 + nf*16 + lr;
                outE[obase + (size_t)row*128 + col] =
                    (acc2[mf][nf][r] - mu)*inv*gv[nf] + bv[nf];
            }
        }
    }
}

// ---------------------------------------------------------------------------
extern "C" void kernel_launch(void* const* d_in, const int* in_sizes, int n_in,
                              void* d_out, int out_size, void* d_ws, size_t ws_size,
                              hipStream_t stream)
{
    const float* X     = (const float*)d_in[0];
    const float* mask  = (const float*)d_in[1];
    const int*   ridx  = (const int*)  d_in[2];
    const int*   chain = (const int*)  d_in[3];
    const float* pe_w  = (const float*)d_in[4];
    const float* pe_b  = (const float*)d_in[5];
    const float* nlw   = (const float*)d_in[6];
    const float* nlb   = (const float*)d_in[7];
    const float* new_  = (const float*)d_in[8];
    const float* neb   = (const float*)d_in[9];
    const float* elw   = (const float*)d_in[10];
    const float* elb   = (const float*)d_in[11];
    const float* eew   = (const float*)d_in[12];
    const float* eeb   = (const float*)d_in[13];
    const float* nng   = (const float*)d_in[14];
    const float* nnb   = (const float*)d_in[15];
    const float* neg_  = (const float*)d_in[16];
    const float* neb_  = (const float*)d_in[17];

    float* out = (float*)d_out;
    char*  ws  = (char*)d_ws;
    int*    wsEidx = (int*)   (ws + WS_EIDX_OFF);
    float*  wsDnb  = (float*) (ws + WS_DNB_OFF);
    float*  wsO    = (float*) (ws + WS_O_OFF);
    float*  wsV6   = (float*) (ws + WS_V6_OFF);
    float4* wsCa4  = (float4*)(ws + WS_CA4_OFF);
    __hip_bfloat16* wsW1 = (__hip_bfloat16*)(ws + WS_W1_OFF);
    __hip_bfloat16* wsW2 = (__hip_bfloat16*)(ws + WS_W2_OFF);

    prep_kernel<<<96, 256, 0, stream>>>(elw, eew, wsW1, wsW2);
    geom_kernel<<<(BB*NN + 255)/256, 256, 0, stream>>>(X, mask, wsO, wsV6, wsCa4);
    topk_kernel<<<BB*NN/4, 256, 0, stream>>>(wsCa4, wsEidx, wsDnb, out + EIDX_OUT_OFF);
    node_kernel<<<BB*NN/8, 128, 0, stream>>>(wsV6, nlw, nlb, new_, neb, nng, nnb, out);
    edge_mfma_kernel<<<BB*NN*KK/64, 256, 0, stream>>>(wsCa4, ridx, chain, wsEidx, wsDnb, wsO,
                                                      pe_w, pe_b, wsW1, wsW2,
                                                      elb, eeb, neg_, neb_, out + E_OUT_OFF);
}

// Round 6
// 187.682 us; speedup vs baseline: 4.2028x; 1.0761x over previous
//
#include <hip/hip_runtime.h>
#include <hip/hip_bf16.h>
#include <math.h>

#define BB 8
#define NN 2048
#define KK 30
#define NF 128
#define EF 128
#define NPE 16
#define NRBF 16
#define MAXREL 32

#define V_OUT_SZ   (BB*NN*NF)
#define E_OUT_OFF  (V_OUT_SZ)
#define E_OUT_SZ   (BB*NN*KK*EF)
#define EIDX_OUT_OFF (E_OUT_OFF + E_OUT_SZ)

// workspace byte offsets
#define WS_EIDX_OFF 0                       // int[B*N*K]
#define WS_DNB_OFF  1966080                 // float[B*N*K]
#define WS_O_OFF    3932160                 // float[B*N*9]
#define WS_V6_OFF   4521984                 // float[B*N*6]
#define WS_CA4_OFF  4915200                 // float4[B*N]      (Ca.xyz, mask)
#define WS_W1_OFF   5177344                 // bf16[8192]   L1 frags
#define WS_W2_OFF   5193728                 // bf16[16384]  L2 frags
// end 5226496

typedef __attribute__((ext_vector_type(8))) short bf16x8;
typedef __attribute__((ext_vector_type(4))) float f32x4;
#define MFMA16(a,b,c) __builtin_amdgcn_mfma_f32_16x16x32_bf16(a,b,c,0,0,0)

struct F3 { float x, y, z; };
__device__ inline F3 f3sub(F3 a, F3 b){ return {a.x-b.x, a.y-b.y, a.z-b.z}; }
__device__ inline F3 f3cross(F3 a, F3 b){ return {a.y*b.z - a.z*b.y, a.z*b.x - a.x*b.z, a.x*b.y - a.y*b.x}; }
__device__ inline float f3dot(F3 a, F3 b){ return a.x*b.x + a.y*b.y + a.z*b.z; }
__device__ inline F3 f3norm(F3 v){
    float n = sqrtf(f3dot(v, v));
    float r = 1.0f/(n + 1e-8f);
    return {v.x*r, v.y*r, v.z*r};
}
__device__ inline float sgnf(float x){ return (x>0.f)?1.f:((x<0.f)?-1.f:0.f); }
__device__ inline short f2bf(float f){
    union { __hip_bfloat16 h; short s; } u;
    u.h = __float2bfloat16(f);
    return u.s;
}

// ---------------------------------------------------------------------------
// VALU-only cross-lane u64-key min helpers (keys are positive-double packed
// (dist_bits<<32 | idx); positive doubles order like their bit patterns).
// ---------------------------------------------------------------------------
template<int CTRL>
__device__ __forceinline__ double kmin_dpp(double key){
    int hi = __double2hiint(key), lo = __double2loint(key);
    int ohi = __builtin_amdgcn_update_dpp(hi, hi, CTRL, 0xf, 0xf, false);
    int olo = __builtin_amdgcn_update_dpp(lo, lo, CTRL, 0xf, 0xf, false);
    return fmin(key, __hiloint2double(ohi, olo));
}

#if __has_builtin(__builtin_amdgcn_permlane16_swap)
__device__ __forceinline__ double kmin_x16(double key){
    unsigned hi = (unsigned)__double2hiint(key), lo = (unsigned)__double2loint(key);
    auto rh = __builtin_amdgcn_permlane16_swap(hi, hi, false, false);
    auto rl = __builtin_amdgcn_permlane16_swap(lo, lo, false, false);
    double a = __hiloint2double((int)rh[0], (int)rl[0]);
    double b = __hiloint2double((int)rh[1], (int)rl[1]);
    return fmin(key, fmin(a, b));
}
#else
__device__ __forceinline__ double kmin_x16(double key){
    int hi = __double2hiint(key), lo = __double2loint(key);
    int ohi = __builtin_amdgcn_ds_swizzle(hi, 0x401F);
    int olo = __builtin_amdgcn_ds_swizzle(lo, 0x401F);
    return fmin(key, __hiloint2double(ohi, olo));
}
#endif

#if __has_builtin(__builtin_amdgcn_permlane32_swap)
__device__ __forceinline__ double kmin_x32(double key){
    unsigned hi = (unsigned)__double2hiint(key), lo = (unsigned)__double2loint(key);
    auto rh = __builtin_amdgcn_permlane32_swap(hi, hi, false, false);
    auto rl = __builtin_amdgcn_permlane32_swap(lo, lo, false, false);
    double a = __hiloint2double((int)rh[0], (int)rl[0]);
    double b = __hiloint2double((int)rh[1], (int)rl[1]);
    return fmin(key, fmin(a, b));
}
#else
__device__ __forceinline__ double kmin_x32(double key){
    return fmin(key, __shfl_xor(key, 32, 64));
}
#endif

__device__ __forceinline__ double wave_min64(double k){
    k = kmin_dpp<0xB1>(k);    // quad_perm xor 1
    k = kmin_dpp<0x4E>(k);    // quad_perm xor 2
    k = kmin_dpp<0x124>(k);   // row_ror:4
    k = kmin_dpp<0x128>(k);   // row_ror:8
    k = kmin_x16(k);
    k = kmin_x32(k);
    return k;                 // all 64 lanes hold the global min
}

// ---------------------------------------------------------------------------
// Kernel P: pre-convert edge-MLP weights into bf16 MFMA-fragment order.
// ---------------------------------------------------------------------------
__global__ void prep_kernel(const float* __restrict__ elw,
                            const float* __restrict__ eew,
                            __hip_bfloat16* __restrict__ w1,
                            __hip_bfloat16* __restrict__ w2)
{
    int i = blockIdx.x*256 + threadIdx.x;
    if (i < 8192) {
        int j = i & 7, lane = (i>>3)&63, ks = (i>>9)&1, nf = i>>10;
        int k = ks*32 + (lane>>4)*8 + j;
        int col = nf*16 + (lane&15);
        float v = (k < 39) ? elw[k*128 + col] : 0.f;
        w1[i] = __float2bfloat16(v);
    } else if (i < 8192 + 16384) {
        int i2 = i - 8192;
        int j = i2 & 7, lane = (i2>>3)&63, ks = (i2>>9)&3, nf = i2>>11;
        int k = ks*32 + (lane>>4)*8 + j;
        int col = nf*16 + (lane&15);
        w2[i2] = __float2bfloat16(eew[k*128 + col]);
    }
}

// ---------------------------------------------------------------------------
// Kernel A: per-node geometry -> V6 (dihedral 6), O (9), packed Ca4 (xyz+mask)
// ---------------------------------------------------------------------------
__global__ void geom_kernel(const float* __restrict__ X,
                            const float* __restrict__ mask,
                            float* __restrict__ wsO, float* __restrict__ wsV6,
                            float4* __restrict__ wsCa4)
{
    int ng = blockIdx.x * blockDim.x + threadIdx.x;
    if (ng >= BB*NN) return;
    int b = ng / NN, n = ng % NN;
    const float* Xb = X + (size_t)b * NN * 12;

    {
        const float* cp = X + (size_t)ng*12 + 3;
        wsCa4[ng] = make_float4(cp[0], cp[1], cp[2], mask[ng]);
    }

    int k0 = 3*n - 1;
    F3 P[6];
    #pragma unroll
    for (int t = 0; t < 6; ++t) {
        int m = k0 + t;
        if (m < 0) m = 0;
        if (m > 3*NN-1) m = 3*NN-1;
        int r = m / 3, a = m % 3;
        const float* p = Xb + ((size_t)r*4 + a)*3;
        P[t] = {p[0], p[1], p[2]};
    }
    F3 U[5];
    #pragma unroll
    for (int t = 0; t < 5; ++t) U[t] = f3norm(f3sub(P[t+1], P[t]));

    float Dang[3];
    #pragma unroll
    for (int t = 0; t < 3; ++t) {
        int k = k0 + t;
        if (k < 0 || k > 3*NN-4) { Dang[t] = 0.f; continue; }
        F3 u2 = U[t], u1 = U[t+1], u0 = U[t+2];
        F3 n2 = f3norm(f3cross(u2, u1));
        F3 n1 = f3norm(f3cross(u1, u0));
        float cosD = f3dot(n2, n1);
        cosD = fminf(fmaxf(cosD, -1.f + 1e-7f), 1.f - 1e-7f);
        float s = f3dot(u2, n1);
        Dang[t] = sgnf(s) * acosf(cosD);
    }
    float* v6 = wsV6 + (size_t)ng * 6;
    v6[0] = cosf(Dang[0]); v6[1] = cosf(Dang[1]); v6[2] = cosf(Dang[2]);
    v6[3] = sinf(Dang[0]); v6[4] = sinf(Dang[1]); v6[5] = sinf(Dang[2]);

    float* o = wsO + (size_t)ng * 9;
    if (n >= 1 && n <= NN-3) {
        const float* cb = X + (size_t)b * NN * 12 + 3;
        F3 c0 = {cb[(size_t)(n-1)*12+0], cb[(size_t)(n-1)*12+1], cb[(size_t)(n-1)*12+2]};
        F3 c1 = {cb[(size_t)(n  )*12+0], cb[(size_t)(n  )*12+1], cb[(size_t)(n  )*12+2]};
        F3 c2 = {cb[(size_t)(n+1)*12+0], cb[(size_t)(n+1)*12+1], cb[(size_t)(n+1)*12+2]};
        F3 u2 = f3norm(f3sub(c1, c0));
        F3 u1 = f3norm(f3sub(c2, c1));
        F3 n2 = f3norm(f3cross(u2, u1));
        F3 o1 = f3norm(f3sub(u2, u1));
        F3 r2 = f3cross(o1, n2);
        o[0]=o1.x; o[1]=o1.y; o[2]=o1.z;
        o[3]=n2.x; o[4]=n2.y; o[5]=n2.z;
        o[6]=r2.x; o[7]=r2.y; o[8]=r2.z;
    } else {
        #pragma unroll
        for (int m = 0; m < 9; ++m) o[m] = 0.f;
    }
}

// ---------------------------------------------------------------------------
// Kernel B: top-K, register-queue version. 1 wave per row, 4 rows/block,
// ZERO LDS. Each lane caches its 32 distances in VGPRs and keeps a sorted
// 3-element queue of packed (d_bits<<32|j) keys as positive doubles
// (v_min_f64 = exact lexicographic min). Per round: one DPP/permlane
// butterfly over queue heads + 1-lane pop. Queue refill (lane won 4+ times)
// rescans the cached 32 distances for keys > last-popped (exact: keys are
// unique, pops monotone increasing).
// Distances use __fmul_rn/__fadd_rn (no fma contraction) to match numpy's
// (dx*dx + dy*dy) + dz*dz + 1e-6 rounding exactly.
// ---------------------------------------------------------------------------
#define KEMPTY 8.9884656743115795e+307   // 0x7FE0...0, > any real key

__device__ __forceinline__ double make_key(float d, int j){
    unsigned long long k =
        ((unsigned long long)__float_as_uint(d) << 32) | (unsigned)j;
    return __longlong_as_double((long long)k);
}

__device__ __forceinline__ void ins3(double& q0, double& q1, double& q2, double k){
    double k2 = fmin(k, q2);          // drop max(k, q2)
    double t1 = fmin(q1, k2); q2 = fmax(q1, k2);
    double t0 = fmin(q0, t1); q1 = fmax(q0, t1);
    q0 = t0;
}

__global__ __launch_bounds__(256, 4) void topk_kernel(
    const float4* __restrict__ wsCa4,
    int* __restrict__ wsEidx, float* __restrict__ wsDnb,
    float* __restrict__ outEidxF)
{
    const int wave = threadIdx.x >> 6, lane = threadIdx.x & 63;
    const int row = blockIdx.x*4 + wave;
    const int b = row >> 11, i = row & (NN-1);

    const float4* cb = wsCa4 + ((size_t)b << 11);
    float4 ci = cb[i];
    float mi = ci.w;

    float dloc[32];
    double q0 = KEMPTY, q1 = KEMPTY, q2 = KEMPTY;
    #pragma unroll 8
    for (int s = 0; s < 32; ++s) {
        int j = s*64 + lane;
        float4 cj = cb[j];
        float dx = __fsub_rn(ci.x, cj.x);
        float dy = __fsub_rn(ci.y, cj.y);
        float dz = __fsub_rn(ci.z, cj.z);
        float d2 = __fadd_rn(__fadd_rn(__fadd_rn(__fmul_rn(dx,dx),
                                                 __fmul_rn(dy,dy)),
                                       __fmul_rn(dz,dz)), 1e-6f);
        float d = sqrtf(d2);
        d = __fadd_rn(d, __fmul_rn(__fsub_rn(1.0f, __fmul_rn(mi, cj.w)), 10000.0f));
        dloc[s] = d;
        ins3(q0, q1, q2, make_key(d, j));
    }

    double res = KEMPTY;
    for (int k = 0; k < KK; ++k) {
        double g = wave_min64(q0);
        if (lane == k) res = g;
        if (__double_as_longlong(q0) == __double_as_longlong(g)) {
            // this lane's head was extracted (keys unique -> exactly 1 lane)
            q0 = q1; q1 = q2; q2 = KEMPTY;
            if (__double_as_longlong(q0) == __double_as_longlong(KEMPTY)) {
                // refill: 3 smallest keys strictly greater than g
                #pragma unroll 4
                for (int s = 0; s < 32; ++s) {
                    double kk = make_key(dloc[s], s*64 + lane);
                    if (!(kk > g)) kk = KEMPTY;
                    ins3(q0, q1, q2, kk);
                }
            }
        }
    }

    if (lane < KK) {
        const size_t rb = (size_t)row * KK;
        unsigned long long gk = (unsigned long long)__double_as_longlong(res);
        int j = (int)(unsigned)gk;
        float dwin = __uint_as_float((unsigned)(gk >> 32));
        wsEidx[rb + lane] = j;
        wsDnb[rb + lane]  = dwin;
        outEidxF[rb + lane] = (float)j;
    }
}

// ---------------------------------------------------------------------------
// Kernel C: node path (unchanged)
// ---------------------------------------------------------------------------
__global__ __launch_bounds__(128) void node_kernel(
    const float* __restrict__ wsV6,
    const float* __restrict__ nlw, const float* __restrict__ nlb,
    const float* __restrict__ new_, const float* __restrict__ neb,
    const float* __restrict__ nng, const float* __restrict__ nnb,
    float* __restrict__ outV)
{
    int f = threadIdx.x;
    __shared__ float h1[128];
    __shared__ float red[2][2];

    float w2[128];
    #pragma unroll
    for (int c = 0; c < 128; ++c) w2[c] = new_[c*128 + f];
    float w1[6];
    #pragma unroll
    for (int c = 0; c < 6; ++c) w1[c] = nlw[c*128 + f];
    float b1v = nlb[f], b2v = neb[f], gv = nng[f], bv = nnb[f];

    for (int gi = 0; gi < 8; ++gi) {
        int row = blockIdx.x*8 + gi;
        float acc = b1v;
        #pragma unroll
        for (int c = 0; c < 6; ++c) acc = fmaf(wsV6[(size_t)row*6 + c], w1[c], acc);
        h1[f] = acc;
        __syncthreads();

        float a2 = b2v;
        #pragma unroll
        for (int c4 = 0; c4 < 32; ++c4) {
            float4 v = *(const float4*)&h1[c4*4];
            a2 = fmaf(v.x, w2[c4*4+0], a2);
            a2 = fmaf(v.y, w2[c4*4+1], a2);
            a2 = fmaf(v.z, w2[c4*4+2], a2);
            a2 = fmaf(v.w, w2[c4*4+3], a2);
        }
        float s = a2, ss = a2*a2;
        #pragma unroll
        for (int off = 32; off; off >>= 1) {
            s  += __shfl_xor(s,  off, 64);
            ss += __shfl_xor(ss, off, 64);
        }
        int wig = f >> 6;
        if ((f & 63) == 0) { red[wig][0] = s; red[wig][1] = ss; }
        __syncthreads();
        float S = red[0][0] + red[1][0], SS = red[0][1] + red[1][1];
        float mu = S * (1.f/128.f);
        float var = SS * (1.f/128.f) - mu*mu;
        float inv = rsqrtf(var + 1e-5f);
        outV[(size_t)row*128 + f] = (a2 - mu)*inv*gv + bv;
        __syncthreads();
    }
}

// ---------------------------------------------------------------------------
// Kernel D: edge MFMA (unchanged)
// ---------------------------------------------------------------------------
__global__ __launch_bounds__(256, 4) void edge_mfma_kernel(
    const float4* __restrict__ wsCa4,
    const int* __restrict__ ridx, const int* __restrict__ chain,
    const int* __restrict__ wsEidx, const float* __restrict__ wsDnb,
    const float* __restrict__ wsO,
    const float* __restrict__ pe_w, const float* __restrict__ pe_b,
    const __hip_bfloat16* __restrict__ wsW1, const __hip_bfloat16* __restrict__ wsW2,
    const float* __restrict__ elb, const float* __restrict__ eeb,
    const float* __restrict__ lng, const float* __restrict__ lnb,
    float* __restrict__ outE)
{
    __shared__ char smem[64*72*2 + 64*136*2];
    short* Ef  = (short*)smem;
    short* h1t = (short*)(smem + 64*72*2);
    float* redS  = (float*)smem;
    float* redSS = (float*)(smem + 512);

    const int tid  = threadIdx.x;
    const int wave = tid >> 6, lane = tid & 63;
    const int wm = wave >> 1, wn = wave & 1;
    const int lr = lane & 15, lk = lane >> 4;

    float b1v[4], b2v[4], gv[4], bv[4];
    #pragma unroll
    for (int nf = 0; nf < 4; ++nf) {
        int col = wn*64 + nf*16 + lr;
        b1v[nf] = elb[col]; b2v[nf] = eeb[col];
        gv[nf]  = lng[col]; bv[nf]  = lnb[col];
    }

    for (int idx = tid; idx < 64*25; idx += 256) {
        int r = idx / 25, c = 39 + idx % 25;
        Ef[r*72 + c] = 0;
    }

    const int E0 = blockIdx.x * 64;

    if (wave == 0) {
        int ge = E0 + lane;
        int row = ge / KK;
        int b = row >> 11;
        int j = wsEidx[ge];
        float oi[9], oj[9];
        #pragma unroll
        for (int m = 0; m < 9; ++m) {
            oi[m] = wsO[(size_t)row*9 + m];
            oj[m] = wsO[((size_t)(b*NN) + j)*9 + m];
        }
        float4 ci = wsCa4[row];
        float4 cj = wsCa4[(size_t)b*NN + j];
        float dx = cj.x-ci.x, dy = cj.y-ci.y, dz = cj.z-ci.z;
        float t0 = oi[0]*dx + oi[1]*dy + oi[2]*dz;
        float t1 = oi[3]*dx + oi[4]*dy + oi[5]*dz;
        float t2 = oi[6]*dx + oi[7]*dy + oi[8]*dz;
        float nr = sqrtf(t0*t0 + t1*t1 + t2*t2);
        float iv = 1.f/(nr + 1e-8f);
        short* ef = &Ef[lane*72];
        ef[32] = f2bf(t0*iv); ef[33] = f2bf(t1*iv); ef[34] = f2bf(t2*iv);
        float R00 = oi[0]*oj[0]+oi[3]*oj[3]+oi[6]*oj[6];
        float R01 = oi[0]*oj[1]+oi[3]*oj[4]+oi[6]*oj[7];
        float R02 = oi[0]*oj[2]+oi[3]*oj[5]+oi[6]*oj[8];
        float R10 = oi[1]*oj[0]+oi[4]*oj[3]+oi[7]*oj[6];
        float R11 = oi[1]*oj[1]+oi[4]*oj[4]+oi[7]*oj[7];
        float R12 = oi[1]*oj[2]+oi[4]*oj[5]+oi[7]*oj[8];
        float R20 = oi[2]*oj[0]+oi[5]*oj[3]+oi[8]*oj[6];
        float R21 = oi[2]*oj[1]+oi[5]*oj[4]+oi[8]*oj[7];
        float R22 = oi[2]*oj[2]+oi[5]*oj[5]+oi[8]*oj[8];
        float mx = 0.5f*sqrtf(fabsf(1.f + R00 - R11 - R22));
        float my = 0.5f*sqrtf(fabsf(1.f - R00 + R11 - R22));
        float mz = 0.5f*sqrtf(fabsf(1.f - R00 - R11 + R22));
        float qx = sgnf(R21 - R12)*mx;
        float qy = sgnf(R02 - R20)*my;
        float qz = sgnf(R10 - R01)*mz;
        float qw = 0.5f*sqrtf(fmaxf(0.f, 1.f + R00 + R11 + R22));
        float qn = sqrtf(qx*qx + qy*qy + qz*qz + qw*qw);
        float qi = 1.f/(qn + 1e-8f);
        ef[35] = f2bf(qx*qi); ef[36] = f2bf(qy*qi);
        ef[37] = f2bf(qz*qi); ef[38] = f2bf(qw*qi);
    } else if (wave == 1) {
        int ge = E0 + lane;
        float dnb = wsDnb[ge];
        short* ef = &Ef[lane*72 + 16];
        #pragma unroll
        for (int m = 0; m < 16; ++m) {
            float mu = 2.f + (20.f/15.f)*(float)m;
            float z = (dnb - mu) * 0.8f;
            ef[m] = f2bf(expf(-z*z));
        }
    } else if (wave == 2) {
        int ge = E0 + lane;
        int row = ge / KK;
        int b = row >> 11;
        int j = wsEidx[ge];
        int ri = ridx[row], rj = ridx[b*NN + j];
        int ch = (chain[row] == chain[b*NN + j]) ? 1 : 0;
        int dd = min(max(ri - rj + MAXREL, 0), 2*MAXREL);
        dd = ch ? dd : (2*MAXREL + 1);
        short* ef = &Ef[lane*72];
        #pragma unroll
        for (int m = 0; m < 16; ++m) ef[m] = f2bf(pe_w[dd*16 + m] + pe_b[m]);
    }
    __syncthreads();

    const bf16x8* W1f = (const bf16x8*)wsW1;
    const bf16x8* W2f = (const bf16x8*)wsW2;

    f32x4 acc[2][4];
    #pragma unroll
    for (int mf = 0; mf < 2; ++mf)
        #pragma unroll
        for (int nf = 0; nf < 4; ++nf)
            acc[mf][nf] = (f32x4){0.f, 0.f, 0.f, 0.f};
    #pragma unroll
    for (int ks = 0; ks < 2; ++ks) {
        bf16x8 a0 = *(const bf16x8*)&Ef[(wm*32      + lr)*72 + ks*32 + lk*8];
        bf16x8 a1 = *(const bf16x8*)&Ef[(wm*32 + 16 + lr)*72 + ks*32 + lk*8];
        #pragma unroll
        for (int nf = 0; nf < 4; ++nf) {
            bf16x8 Bf = W1f[((wn*4 + nf)*2 + ks)*64 + lane];
            acc[0][nf] = MFMA16(a0, Bf, acc[0][nf]);
            acc[1][nf] = MFMA16(a1, Bf, acc[1][nf]);
        }
    }
    #pragma unroll
    for (int mf = 0; mf < 2; ++mf)
        #pragma unroll
        for (int nf = 0; nf < 4; ++nf)
            #pragma unroll
            for (int r = 0; r < 4; ++r) {
                int row = wm*32 + mf*16 + lk*4 + r;
                int col = wn*64 + nf*16 + lr;
                h1t[row*136 + col] = f2bf(acc[mf][nf][r] + b1v[nf]);
            }
    __syncthreads();

    f32x4 acc2[2][4];
    #pragma unroll
    for (int mf = 0; mf < 2; ++mf)
        #pragma unroll
        for (int nf = 0; nf < 4; ++nf)
            acc2[mf][nf] = (f32x4){0.f, 0.f, 0.f, 0.f};
    #pragma unroll
    for (int ks = 0; ks < 4; ++ks) {
        bf16x8 a0 = *(const bf16x8*)&h1t[(wm*32      + lr)*136 + ks*32 + lk*8];
        bf16x8 a1 = *(const bf16x8*)&h1t[(wm*32 + 16 + lr)*136 + ks*32 + lk*8];
        #pragma unroll
        for (int nf = 0; nf < 4; ++nf) {
            bf16x8 Bf = W2f[((wn*4 + nf)*4 + ks)*64 + lane];
            acc2[0][nf] = MFMA16(a0, Bf, acc2[0][nf]);
            acc2[1][nf] = MFMA16(a1, Bf, acc2[1][nf]);
        }
    }
    #pragma unroll
    for (int mf = 0; mf < 2; ++mf)
        #pragma unroll
        for (int nf = 0; nf < 4; ++nf)
            #pragma unroll
            for (int r = 0; r < 4; ++r)
                acc2[mf][nf][r] += b2v[nf];

    #pragma unroll
    for (int mf = 0; mf < 2; ++mf) {
        #pragma unroll
        for (int r = 0; r < 4; ++r) {
            float v0 = acc2[mf][0][r], v1 = acc2[mf][1][r];
            float v2 = acc2[mf][2][r], v3 = acc2[mf][3][r];
            float s = v0 + v1 + v2 + v3;
            float q = v0*v0 + v1*v1 + v2*v2 + v3*v3;
            #pragma unroll
            for (int off = 1; off < 16; off <<= 1) {
                s += __shfl_xor(s, off, 64);
                q += __shfl_xor(q, off, 64);
            }
            if (lr == 0) {
                int row = wm*32 + mf*16 + lk*4 + r;
                redS[row*2 + wn] = s; redSS[row*2 + wn] = q;
            }
        }
    }
    __syncthreads();

    const size_t obase = (size_t)E0 * 128;
    #pragma unroll
    for (int mf = 0; mf < 2; ++mf) {
        #pragma unroll
        for (int r = 0; r < 4; ++r) {
            int row = wm*32 + mf*16 + lk*4 + r;
            float S = redS[row*2 + 0] + redS[row*2 + 1];
            float Q = redSS[row*2 + 0] + redSS[row*2 + 1];
            float mu = S * (1.f/128.f);
            float var = Q * (1.f/128.f) - mu*mu;
            float inv = rsqrtf(var + 1e-5f);
            #pragma unroll
            for (int nf = 0; nf < 4; ++nf) {
                int col = wn*64 + nf*16 + lr;
                outE[obase + (size_t)row*128 + col] =
                    (acc2[mf][nf][r] - mu)*inv*gv[nf] + bv[nf];
            }
        }
    }
}

// ---------------------------------------------------------------------------
extern "C" void kernel_launch(void* const* d_in, const int* in_sizes, int n_in,
                              void* d_out, int out_size, void* d_ws, size_t ws_size,
                              hipStream_t stream)
{
    const float* X     = (const float*)d_in[0];
    const float* mask  = (const float*)d_in[1];
    const int*   ridx  = (const int*)  d_in[2];
    const int*   chain = (const int*)  d_in[3];
    const float* pe_w  = (const float*)d_in[4];
    const float* pe_b  = (const float*)d_in[5];
    const float* nlw   = (const float*)d_in[6];
    const float* nlb   = (const float*)d_in[7];
    const float* new_  = (const float*)d_in[8];
    const float* neb   = (const float*)d_in[9];
    const float* elw   = (const float*)d_in[10];
    const float* elb   = (const float*)d_in[11];
    const float* eew   = (const float*)d_in[12];
    const float* eeb   = (const float*)d_in[13];
    const float* nng   = (const float*)d_in[14];
    const float* nnb   = (const float*)d_in[15];
    const float* neg_  = (const float*)d_in[16];
    const float* neb_  = (const float*)d_in[17];

    float* out = (float*)d_out;
    char*  ws  = (char*)d_ws;
    int*    wsEidx = (int*)   (ws + WS_EIDX_OFF);
    float*  wsDnb  = (float*) (ws + WS_DNB_OFF);
    float*  wsO    = (float*) (ws + WS_O_OFF);
    float*  wsV6   = (float*) (ws + WS_V6_OFF);
    float4* wsCa4  = (float4*)(ws + WS_CA4_OFF);
    __hip_bfloat16* wsW1 = (__hip_bfloat16*)(ws + WS_W1_OFF);
    __hip_bfloat16* wsW2 = (__hip_bfloat16*)(ws + WS_W2_OFF);

    prep_kernel<<<96, 256, 0, stream>>>(elw, eew, wsW1, wsW2);
    geom_kernel<<<(BB*NN + 255)/256, 256, 0, stream>>>(X, mask, wsO, wsV6, wsCa4);
    topk_kernel<<<BB*NN/4, 256, 0, stream>>>(wsCa4, wsEidx, wsDnb, out + EIDX_OUT_OFF);
    node_kernel<<<BB*NN/8, 128, 0, stream>>>(wsV6, nlw, nlb, new_, neb, nng, nnb, out);
    edge_mfma_kernel<<<BB*NN*KK/64, 256, 0, stream>>>(wsCa4, ridx, chain, wsEidx, wsDnb, wsO,
                                                      pe_w, pe_b, wsW1, wsW2,
                                                      elb, eeb, neg_, neb_, out + E_OUT_OFF);
}

// Round 7
// 176.999 us; speedup vs baseline: 4.4564x; 1.0604x over previous
//
#include <hip/hip_runtime.h>
#include <hip/hip_bf16.h>
#include <math.h>

#define BB 8
#define NN 2048
#define KK 30
#define NF 128
#define EF 128
#define NPE 16
#define NRBF 16
#define MAXREL 32

#define V_OUT_SZ   (BB*NN*NF)
#define E_OUT_OFF  (V_OUT_SZ)
#define E_OUT_SZ   (BB*NN*KK*EF)
#define EIDX_OUT_OFF (E_OUT_OFF + E_OUT_SZ)

// workspace byte offsets
#define WS_EIDX_OFF 0                       // int[B*N*K]
#define WS_DNB_OFF  1966080                 // float[B*N*K]
#define WS_O_OFF    3932160                 // float[B*N*9]
#define WS_V6_OFF   4521984                 // float[B*N*6]
#define WS_CA4_OFF  4915200                 // float4[B*N]      (Ca.xyz, mask)
#define WS_W1_OFF   5177344                 // bf16[8192]   L1 frags
#define WS_W2_OFF   5193728                 // bf16[16384]  L2 frags
// end 5226496

typedef __attribute__((ext_vector_type(8))) short bf16x8;
typedef __attribute__((ext_vector_type(4))) float f32x4;
#define MFMA16(a,b,c) __builtin_amdgcn_mfma_f32_16x16x32_bf16(a,b,c,0,0,0)

struct F3 { float x, y, z; };
__device__ inline F3 f3sub(F3 a, F3 b){ return {a.x-b.x, a.y-b.y, a.z-b.z}; }
__device__ inline F3 f3cross(F3 a, F3 b){ return {a.y*b.z - a.z*b.y, a.z*b.x - a.x*b.z, a.x*b.y - a.y*b.x}; }
__device__ inline float f3dot(F3 a, F3 b){ return a.x*b.x + a.y*b.y + a.z*b.z; }
__device__ inline F3 f3norm(F3 v){
    float n = sqrtf(f3dot(v, v));
    float r = 1.0f/(n + 1e-8f);
    return {v.x*r, v.y*r, v.z*r};
}
__device__ inline float sgnf(float x){ return (x>0.f)?1.f:((x<0.f)?-1.f:0.f); }
__device__ inline short f2bf(float f){
    union { __hip_bfloat16 h; short s; } u;
    u.h = __float2bfloat16(f);
    return u.s;
}

// ---------------------------------------------------------------------------
// VALU-only cross-lane u64-key min helpers (keys are positive-double packed
// (dist_bits<<32 | idx); positive doubles order like their bit patterns).
// ---------------------------------------------------------------------------
template<int CTRL>
__device__ __forceinline__ double kmin_dpp(double key){
    int hi = __double2hiint(key), lo = __double2loint(key);
    int ohi = __builtin_amdgcn_update_dpp(hi, hi, CTRL, 0xf, 0xf, false);
    int olo = __builtin_amdgcn_update_dpp(lo, lo, CTRL, 0xf, 0xf, false);
    return fmin(key, __hiloint2double(ohi, olo));
}

#if __has_builtin(__builtin_amdgcn_permlane16_swap)
__device__ __forceinline__ double kmin_x16(double key){
    unsigned hi = (unsigned)__double2hiint(key), lo = (unsigned)__double2loint(key);
    auto rh = __builtin_amdgcn_permlane16_swap(hi, hi, false, false);
    auto rl = __builtin_amdgcn_permlane16_swap(lo, lo, false, false);
    double a = __hiloint2double((int)rh[0], (int)rl[0]);
    double b = __hiloint2double((int)rh[1], (int)rl[1]);
    return fmin(key, fmin(a, b));
}
#else
__device__ __forceinline__ double kmin_x16(double key){
    int hi = __double2hiint(key), lo = __double2loint(key);
    int ohi = __builtin_amdgcn_ds_swizzle(hi, 0x401F);
    int olo = __builtin_amdgcn_ds_swizzle(lo, 0x401F);
    return fmin(key, __hiloint2double(ohi, olo));
}
#endif

#if __has_builtin(__builtin_amdgcn_permlane32_swap)
__device__ __forceinline__ double kmin_x32(double key){
    unsigned hi = (unsigned)__double2hiint(key), lo = (unsigned)__double2loint(key);
    auto rh = __builtin_amdgcn_permlane32_swap(hi, hi, false, false);
    auto rl = __builtin_amdgcn_permlane32_swap(lo, lo, false, false);
    double a = __hiloint2double((int)rh[0], (int)rl[0]);
    double b = __hiloint2double((int)rh[1], (int)rl[1]);
    return fmin(key, fmin(a, b));
}
#else
__device__ __forceinline__ double kmin_x32(double key){
    return fmin(key, __shfl_xor(key, 32, 64));
}
#endif

__device__ __forceinline__ double wave_min64(double k){
    k = kmin_dpp<0xB1>(k);    // quad_perm xor 1
    k = kmin_dpp<0x4E>(k);    // quad_perm xor 2
    k = kmin_dpp<0x124>(k);   // row_ror:4
    k = kmin_dpp<0x128>(k);   // row_ror:8
    k = kmin_x16(k);
    k = kmin_x32(k);
    return k;                 // all 64 lanes hold the global min
}

// ---------------------------------------------------------------------------
// Kernel P: pre-convert edge-MLP weights into bf16 MFMA-fragment order.
// ---------------------------------------------------------------------------
__global__ void prep_kernel(const float* __restrict__ elw,
                            const float* __restrict__ eew,
                            __hip_bfloat16* __restrict__ w1,
                            __hip_bfloat16* __restrict__ w2)
{
    int i = blockIdx.x*256 + threadIdx.x;
    if (i < 8192) {
        int j = i & 7, lane = (i>>3)&63, ks = (i>>9)&1, nf = i>>10;
        int k = ks*32 + (lane>>4)*8 + j;
        int col = nf*16 + (lane&15);
        float v = (k < 39) ? elw[k*128 + col] : 0.f;
        w1[i] = __float2bfloat16(v);
    } else if (i < 8192 + 16384) {
        int i2 = i - 8192;
        int j = i2 & 7, lane = (i2>>3)&63, ks = (i2>>9)&3, nf = i2>>11;
        int k = ks*32 + (lane>>4)*8 + j;
        int col = nf*16 + (lane&15);
        w2[i2] = __float2bfloat16(eew[k*128 + col]);
    }
}

// ---------------------------------------------------------------------------
// Kernel A: per-node geometry -> V6 (dihedral 6), O (9), packed Ca4 (xyz+mask)
// ---------------------------------------------------------------------------
__global__ void geom_kernel(const float* __restrict__ X,
                            const float* __restrict__ mask,
                            float* __restrict__ wsO, float* __restrict__ wsV6,
                            float4* __restrict__ wsCa4)
{
    int ng = blockIdx.x * blockDim.x + threadIdx.x;
    if (ng >= BB*NN) return;
    int b = ng / NN, n = ng % NN;
    const float* Xb = X + (size_t)b * NN * 12;

    {
        const float* cp = X + (size_t)ng*12 + 3;
        wsCa4[ng] = make_float4(cp[0], cp[1], cp[2], mask[ng]);
    }

    int k0 = 3*n - 1;
    F3 P[6];
    #pragma unroll
    for (int t = 0; t < 6; ++t) {
        int m = k0 + t;
        if (m < 0) m = 0;
        if (m > 3*NN-1) m = 3*NN-1;
        int r = m / 3, a = m % 3;
        const float* p = Xb + ((size_t)r*4 + a)*3;
        P[t] = {p[0], p[1], p[2]};
    }
    F3 U[5];
    #pragma unroll
    for (int t = 0; t < 5; ++t) U[t] = f3norm(f3sub(P[t+1], P[t]));

    float Dang[3];
    #pragma unroll
    for (int t = 0; t < 3; ++t) {
        int k = k0 + t;
        if (k < 0 || k > 3*NN-4) { Dang[t] = 0.f; continue; }
        F3 u2 = U[t], u1 = U[t+1], u0 = U[t+2];
        F3 n2 = f3norm(f3cross(u2, u1));
        F3 n1 = f3norm(f3cross(u1, u0));
        float cosD = f3dot(n2, n1);
        cosD = fminf(fmaxf(cosD, -1.f + 1e-7f), 1.f - 1e-7f);
        float s = f3dot(u2, n1);
        Dang[t] = sgnf(s) * acosf(cosD);
    }
    float* v6 = wsV6 + (size_t)ng * 6;
    v6[0] = cosf(Dang[0]); v6[1] = cosf(Dang[1]); v6[2] = cosf(Dang[2]);
    v6[3] = sinf(Dang[0]); v6[4] = sinf(Dang[1]); v6[5] = sinf(Dang[2]);

    float* o = wsO + (size_t)ng * 9;
    if (n >= 1 && n <= NN-3) {
        const float* cb = X + (size_t)b * NN * 12 + 3;
        F3 c0 = {cb[(size_t)(n-1)*12+0], cb[(size_t)(n-1)*12+1], cb[(size_t)(n-1)*12+2]};
        F3 c1 = {cb[(size_t)(n  )*12+0], cb[(size_t)(n  )*12+1], cb[(size_t)(n  )*12+2]};
        F3 c2 = {cb[(size_t)(n+1)*12+0], cb[(size_t)(n+1)*12+1], cb[(size_t)(n+1)*12+2]};
        F3 u2 = f3norm(f3sub(c1, c0));
        F3 u1 = f3norm(f3sub(c2, c1));
        F3 n2 = f3norm(f3cross(u2, u1));
        F3 o1 = f3norm(f3sub(u2, u1));
        F3 r2 = f3cross(o1, n2);
        o[0]=o1.x; o[1]=o1.y; o[2]=o1.z;
        o[3]=n2.x; o[4]=n2.y; o[5]=n2.z;
        o[6]=r2.x; o[7]=r2.y; o[8]=r2.z;
    } else {
        #pragma unroll
        for (int m = 0; m < 9; ++m) o[m] = 0.f;
    }
}

// ---------------------------------------------------------------------------
// Kernel B: top-K, register-queue version. 1 wave per row, 4 rows/block,
// ZERO LDS. Each lane caches its 32 distances in VGPRs (ALL loops touching
// dloc are FULLY unrolled -> compile-time indices only; rule #20: partial
// unroll would force dloc to scratch, which was the R6 97us failure).
// Sorted 3-element queue of packed (d_bits<<32|j) keys as positive doubles
// (v_min_f64 = exact lexicographic min). Per round: one DPP/permlane
// butterfly over queue heads + 1-lane pop. Refill (lane popped 3x, rare)
// rescans the 32 cached distances for keys > last-popped.
// Distances use __f*_rn ops (no fma contraction) to match numpy rounding.
// ---------------------------------------------------------------------------
#define KEMPTY 8.9884656743115795e+307   // 0x7FE0...0, > any real key

__device__ __forceinline__ double make_key(float d, int j){
    unsigned long long k =
        ((unsigned long long)__float_as_uint(d) << 32) | (unsigned)j;
    return __longlong_as_double((long long)k);
}

__device__ __forceinline__ void ins3(double& q0, double& q1, double& q2, double k){
    double k2 = fmin(k, q2);          // drop max(k, q2)
    double t1 = fmin(q1, k2); q2 = fmax(q1, k2);
    double t0 = fmin(q0, t1); q1 = fmax(q0, t1);
    q0 = t0;
}

__global__ __launch_bounds__(256, 4) void topk_kernel(
    const float4* __restrict__ wsCa4,
    int* __restrict__ wsEidx, float* __restrict__ wsDnb,
    float* __restrict__ outEidxF)
{
    const int wave = threadIdx.x >> 6, lane = threadIdx.x & 63;
    const int row = blockIdx.x*4 + wave;
    const int b = row >> 11, i = row & (NN-1);

    const float4* cb = wsCa4 + ((size_t)b << 11);
    float4 ci = cb[i];
    float mi = ci.w;

    float dloc[32];
    double q0 = KEMPTY, q1 = KEMPTY, q2 = KEMPTY;
    #pragma unroll
    for (int s = 0; s < 32; ++s) {
        int j = s*64 + lane;
        float4 cj = cb[j];
        float dx = __fsub_rn(ci.x, cj.x);
        float dy = __fsub_rn(ci.y, cj.y);
        float dz = __fsub_rn(ci.z, cj.z);
        float d2 = __fadd_rn(__fadd_rn(__fadd_rn(__fmul_rn(dx,dx),
                                                 __fmul_rn(dy,dy)),
                                       __fmul_rn(dz,dz)), 1e-6f);
        float d = sqrtf(d2);
        d = __fadd_rn(d, __fmul_rn(__fsub_rn(1.0f, __fmul_rn(mi, cj.w)), 10000.0f));
        dloc[s] = d;
        ins3(q0, q1, q2, make_key(d, j));
    }

    double res = KEMPTY;
    for (int k = 0; k < KK; ++k) {
        double g = wave_min64(q0);
        if (lane == k) res = g;
        if (__double_as_longlong(q0) == __double_as_longlong(g)) {
            // this lane's head was extracted (keys unique -> exactly 1 lane)
            q0 = q1; q1 = q2; q2 = KEMPTY;
            if (__double_as_longlong(q0) == __double_as_longlong(KEMPTY)) {
                // refill: 3 smallest keys strictly greater than g.
                // FULL unroll: dloc indices stay compile-time constants.
                #pragma unroll
                for (int s = 0; s < 32; ++s) {
                    double kk = make_key(dloc[s], s*64 + lane);
                    if (!(kk > g)) kk = KEMPTY;
                    ins3(q0, q1, q2, kk);
                }
            }
        }
    }

    if (lane < KK) {
        const size_t rb = (size_t)row * KK;
        unsigned long long gk = (unsigned long long)__double_as_longlong(res);
        int j = (int)(unsigned)gk;
        float dwin = __uint_as_float((unsigned)(gk >> 32));
        wsEidx[rb + lane] = j;
        wsDnb[rb + lane]  = dwin;
        outEidxF[rb + lane] = (float)j;
    }
}

// ---------------------------------------------------------------------------
// Kernel C: node path (unchanged)
// ---------------------------------------------------------------------------
__global__ __launch_bounds__(128) void node_kernel(
    const float* __restrict__ wsV6,
    const float* __restrict__ nlw, const float* __restrict__ nlb,
    const float* __restrict__ new_, const float* __restrict__ neb,
    const float* __restrict__ nng, const float* __restrict__ nnb,
    float* __restrict__ outV)
{
    int f = threadIdx.x;
    __shared__ float h1[128];
    __shared__ float red[2][2];

    float w2[128];
    #pragma unroll
    for (int c = 0; c < 128; ++c) w2[c] = new_[c*128 + f];
    float w1[6];
    #pragma unroll
    for (int c = 0; c < 6; ++c) w1[c] = nlw[c*128 + f];
    float b1v = nlb[f], b2v = neb[f], gv = nng[f], bv = nnb[f];

    for (int gi = 0; gi < 8; ++gi) {
        int row = blockIdx.x*8 + gi;
        float acc = b1v;
        #pragma unroll
        for (int c = 0; c < 6; ++c) acc = fmaf(wsV6[(size_t)row*6 + c], w1[c], acc);
        h1[f] = acc;
        __syncthreads();

        float a2 = b2v;
        #pragma unroll
        for (int c4 = 0; c4 < 32; ++c4) {
            float4 v = *(const float4*)&h1[c4*4];
            a2 = fmaf(v.x, w2[c4*4+0], a2);
            a2 = fmaf(v.y, w2[c4*4+1], a2);
            a2 = fmaf(v.z, w2[c4*4+2], a2);
            a2 = fmaf(v.w, w2[c4*4+3], a2);
        }
        float s = a2, ss = a2*a2;
        #pragma unroll
        for (int off = 32; off; off >>= 1) {
            s  += __shfl_xor(s,  off, 64);
            ss += __shfl_xor(ss, off, 64);
        }
        int wig = f >> 6;
        if ((f & 63) == 0) { red[wig][0] = s; red[wig][1] = ss; }
        __syncthreads();
        float S = red[0][0] + red[1][0], SS = red[0][1] + red[1][1];
        float mu = S * (1.f/128.f);
        float var = SS * (1.f/128.f) - mu*mu;
        float inv = rsqrtf(var + 1e-5f);
        outV[(size_t)row*128 + f] = (a2 - mu)*inv*gv + bv;
        __syncthreads();
    }
}

// ---------------------------------------------------------------------------
// Kernel D: edge MFMA (unchanged)
// ---------------------------------------------------------------------------
__global__ __launch_bounds__(256, 4) void edge_mfma_kernel(
    const float4* __restrict__ wsCa4,
    const int* __restrict__ ridx, const int* __restrict__ chain,
    const int* __restrict__ wsEidx, const float* __restrict__ wsDnb,
    const float* __restrict__ wsO,
    const float* __restrict__ pe_w, const float* __restrict__ pe_b,
    const __hip_bfloat16* __restrict__ wsW1, const __hip_bfloat16* __restrict__ wsW2,
    const float* __restrict__ elb, const float* __restrict__ eeb,
    const float* __restrict__ lng, const float* __restrict__ lnb,
    float* __restrict__ outE)
{
    __shared__ char smem[64*72*2 + 64*136*2];
    short* Ef  = (short*)smem;
    short* h1t = (short*)(smem + 64*72*2);
    float* redS  = (float*)smem;
    float* redSS = (float*)(smem + 512);

    const int tid  = threadIdx.x;
    const int wave = tid >> 6, lane = tid & 63;
    const int wm = wave >> 1, wn = wave & 1;
    const int lr = lane & 15, lk = lane >> 4;

    float b1v[4], b2v[4], gv[4], bv[4];
    #pragma unroll
    for (int nf = 0; nf < 4; ++nf) {
        int col = wn*64 + nf*16 + lr;
        b1v[nf] = elb[col]; b2v[nf] = eeb[col];
        gv[nf]  = lng[col]; bv[nf]  = lnb[col];
    }

    for (int idx = tid; idx < 64*25; idx += 256) {
        int r = idx / 25, c = 39 + idx % 25;
        Ef[r*72 + c] = 0;
    }

    const int E0 = blockIdx.x * 64;

    if (wave == 0) {
        int ge = E0 + lane;
        int row = ge / KK;
        int b = row >> 11;
        int j = wsEidx[ge];
        float oi[9], oj[9];
        #pragma unroll
        for (int m = 0; m < 9; ++m) {
            oi[m] = wsO[(size_t)row*9 + m];
            oj[m] = wsO[((size_t)(b*NN) + j)*9 + m];
        }
        float4 ci = wsCa4[row];
        float4 cj = wsCa4[(size_t)b*NN + j];
        float dx = cj.x-ci.x, dy = cj.y-ci.y, dz = cj.z-ci.z;
        float t0 = oi[0]*dx + oi[1]*dy + oi[2]*dz;
        float t1 = oi[3]*dx + oi[4]*dy + oi[5]*dz;
        float t2 = oi[6]*dx + oi[7]*dy + oi[8]*dz;
        float nr = sqrtf(t0*t0 + t1*t1 + t2*t2);
        float iv = 1.f/(nr + 1e-8f);
        short* ef = &Ef[lane*72];
        ef[32] = f2bf(t0*iv); ef[33] = f2bf(t1*iv); ef[34] = f2bf(t2*iv);
        float R00 = oi[0]*oj[0]+oi[3]*oj[3]+oi[6]*oj[6];
        float R01 = oi[0]*oj[1]+oi[3]*oj[4]+oi[6]*oj[7];
        float R02 = oi[0]*oj[2]+oi[3]*oj[5]+oi[6]*oj[8];
        float R10 = oi[1]*oj[0]+oi[4]*oj[3]+oi[7]*oj[6];
        float R11 = oi[1]*oj[1]+oi[4]*oj[4]+oi[7]*oj[7];
        float R12 = oi[1]*oj[2]+oi[4]*oj[5]+oi[7]*oj[8];
        float R20 = oi[2]*oj[0]+oi[5]*oj[3]+oi[8]*oj[6];
        float R21 = oi[2]*oj[1]+oi[5]*oj[4]+oi[8]*oj[7];
        float R22 = oi[2]*oj[2]+oi[5]*oj[5]+oi[8]*oj[8];
        float mx = 0.5f*sqrtf(fabsf(1.f + R00 - R11 - R22));
        float my = 0.5f*sqrtf(fabsf(1.f - R00 + R11 - R22));
        float mz = 0.5f*sqrtf(fabsf(1.f - R00 - R11 + R22));
        float qx = sgnf(R21 - R12)*mx;
        float qy = sgnf(R02 - R20)*my;
        float qz = sgnf(R10 - R01)*mz;
        float qw = 0.5f*sqrtf(fmaxf(0.f, 1.f + R00 + R11 + R22));
        float qn = sqrtf(qx*qx + qy*qy + qz*qz + qw*qw);
        float qi = 1.f/(qn + 1e-8f);
        ef[35] = f2bf(qx*qi); ef[36] = f2bf(qy*qi);
        ef[37] = f2bf(qz*qi); ef[38] = f2bf(qw*qi);
    } else if (wave == 1) {
        int ge = E0 + lane;
        float dnb = wsDnb[ge];
        short* ef = &Ef[lane*72 + 16];
        #pragma unroll
        for (int m = 0; m < 16; ++m) {
            float mu = 2.f + (20.f/15.f)*(float)m;
            float z = (dnb - mu) * 0.8f;
            ef[m] = f2bf(expf(-z*z));
        }
    } else if (wave == 2) {
        int ge = E0 + lane;
        int row = ge / KK;
        int b = row >> 11;
        int j = wsEidx[ge];
        int ri = ridx[row], rj = ridx[b*NN + j];
        int ch = (chain[row] == chain[b*NN + j]) ? 1 : 0;
        int dd = min(max(ri - rj + MAXREL, 0), 2*MAXREL);
        dd = ch ? dd : (2*MAXREL + 1);
        short* ef = &Ef[lane*72];
        #pragma unroll
        for (int m = 0; m < 16; ++m) ef[m] = f2bf(pe_w[dd*16 + m] + pe_b[m]);
    }
    __syncthreads();

    const bf16x8* W1f = (const bf16x8*)wsW1;
    const bf16x8* W2f = (const bf16x8*)wsW2;

    f32x4 acc[2][4];
    #pragma unroll
    for (int mf = 0; mf < 2; ++mf)
        #pragma unroll
        for (int nf = 0; nf < 4; ++nf)
            acc[mf][nf] = (f32x4){0.f, 0.f, 0.f, 0.f};
    #pragma unroll
    for (int ks = 0; ks < 2; ++ks) {
        bf16x8 a0 = *(const bf16x8*)&Ef[(wm*32      + lr)*72 + ks*32 + lk*8];
        bf16x8 a1 = *(const bf16x8*)&Ef[(wm*32 + 16 + lr)*72 + ks*32 + lk*8];
        #pragma unroll
        for (int nf = 0; nf < 4; ++nf) {
            bf16x8 Bf = W1f[((wn*4 + nf)*2 + ks)*64 + lane];
            acc[0][nf] = MFMA16(a0, Bf, acc[0][nf]);
            acc[1][nf] = MFMA16(a1, Bf, acc[1][nf]);
        }
    }
    #pragma unroll
    for (int mf = 0; mf < 2; ++mf)
        #pragma unroll
        for (int nf = 0; nf < 4; ++nf)
            #pragma unroll
            for (int r = 0; r < 4; ++r) {
                int row = wm*32 + mf*16 + lk*4 + r;
                int col = wn*64 + nf*16 + lr;
                h1t[row*136 + col] = f2bf(acc[mf][nf][r] + b1v[nf]);
            }
    __syncthreads();

    f32x4 acc2[2][4];
    #pragma unroll
    for (int mf = 0; mf < 2; ++mf)
        #pragma unroll
        for (int nf = 0; nf < 4; ++nf)
            acc2[mf][nf] = (f32x4){0.f, 0.f, 0.f, 0.f};
    #pragma unroll
    for (int ks = 0; ks < 4; ++ks) {
        bf16x8 a0 = *(const bf16x8*)&h1t[(wm*32      + lr)*136 + ks*32 + lk*8];
        bf16x8 a1 = *(const bf16x8*)&h1t[(wm*32 + 16 + lr)*136 + ks*32 + lk*8];
        #pragma unroll
        for (int nf = 0; nf < 4; ++nf) {
            bf16x8 Bf = W2f[((wn*4 + nf)*4 + ks)*64 + lane];
            acc2[0][nf] = MFMA16(a0, Bf, acc2[0][nf]);
            acc2[1][nf] = MFMA16(a1, Bf, acc2[1][nf]);
        }
    }
    #pragma unroll
    for (int mf = 0; mf < 2; ++mf)
        #pragma unroll
        for (int nf = 0; nf < 4; ++nf)
            #pragma unroll
            for (int r = 0; r < 4; ++r)
                acc2[mf][nf][r] += b2v[nf];

    #pragma unroll
    for (int mf = 0; mf < 2; ++mf) {
        #pragma unroll
        for (int r = 0; r < 4; ++r) {
            float v0 = acc2[mf][0][r], v1 = acc2[mf][1][r];
            float v2 = acc2[mf][2][r], v3 = acc2[mf][3][r];
            float s = v0 + v1 + v2 + v3;
            float q = v0*v0 + v1*v1 + v2*v2 + v3*v3;
            #pragma unroll
            for (int off = 1; off < 16; off <<= 1) {
                s += __shfl_xor(s, off, 64);
                q += __shfl_xor(q, off, 64);
            }
            if (lr == 0) {
                int row = wm*32 + mf*16 + lk*4 + r;
                redS[row*2 + wn] = s; redSS[row*2 + wn] = q;
            }
        }
    }
    __syncthreads();

    const size_t obase = (size_t)E0 * 128;
    #pragma unroll
    for (int mf = 0; mf < 2; ++mf) {
        #pragma unroll
        for (int r = 0; r < 4; ++r) {
            int row = wm*32 + mf*16 + lk*4 + r;
            float S = redS[row*2 + 0] + redS[row*2 + 1];
            float Q = redSS[row*2 + 0] + redSS[row*2 + 1];
            float mu = S * (1.f/128.f);
            float var = Q * (1.f/128.f) - mu*mu;
            float inv = rsqrtf(var + 1e-5f);
            #pragma unroll
            for (int nf = 0; nf < 4; ++nf) {
                int col = wn*64 + nf*16 + lr;
                outE[obase + (size_t)row*128 + col] =
                    (acc2[mf][nf][r] - mu)*inv*gv[nf] + bv[nf];
            }
        }
    }
}

// ---------------------------------------------------------------------------
extern "C" void kernel_launch(void* const* d_in, const int* in_sizes, int n_in,
                              void* d_out, int out_size, void* d_ws, size_t ws_size,
                              hipStream_t stream)
{
    const float* X     = (const float*)d_in[0];
    const float* mask  = (const float*)d_in[1];
    const int*   ridx  = (const int*)  d_in[2];
    const int*   chain = (const int*)  d_in[3];
    const float* pe_w  = (const float*)d_in[4];
    const float* pe_b  = (const float*)d_in[5];
    const float* nlw   = (const float*)d_in[6];
    const float* nlb   = (const float*)d_in[7];
    const float* new_  = (const float*)d_in[8];
    const float* neb   = (const float*)d_in[9];
    const float* elw   = (const float*)d_in[10];
    const float* elb   = (const float*)d_in[11];
    const float* eew   = (const float*)d_in[12];
    const float* eeb   = (const float*)d_in[13];
    const float* nng   = (const float*)d_in[14];
    const float* nnb   = (const float*)d_in[15];
    const float* neg_  = (const float*)d_in[16];
    const float* neb_  = (const float*)d_in[17];

    float* out = (float*)d_out;
    char*  ws  = (char*)d_ws;
    int*    wsEidx = (int*)   (ws + WS_EIDX_OFF);
    float*  wsDnb  = (float*) (ws + WS_DNB_OFF);
    float*  wsO    = (float*) (ws + WS_O_OFF);
    float*  wsV6   = (float*) (ws + WS_V6_OFF);
    float4* wsCa4  = (float4*)(ws + WS_CA4_OFF);
    __hip_bfloat16* wsW1 = (__hip_bfloat16*)(ws + WS_W1_OFF);
    __hip_bfloat16* wsW2 = (__hip_bfloat16*)(ws + WS_W2_OFF);

    prep_kernel<<<96, 256, 0, stream>>>(elw, eew, wsW1, wsW2);
    geom_kernel<<<(BB*NN + 255)/256, 256, 0, stream>>>(X, mask, wsO, wsV6, wsCa4);
    topk_kernel<<<BB*NN/4, 256, 0, stream>>>(wsCa4, wsEidx, wsDnb, out + EIDX_OUT_OFF);
    node_kernel<<<BB*NN/8, 128, 0, stream>>>(wsV6, nlw, nlb, new_, neb, nng, nnb, out);
    edge_mfma_kernel<<<BB*NN*KK/64, 256, 0, stream>>>(wsCa4, ridx, chain, wsEidx, wsDnb, wsO,
                                                      pe_w, pe_b, wsW1, wsW2,
                                                      elb, eeb, neg_, neb_, out + E_OUT_OFF);
}

// Round 8
// 173.552 us; speedup vs baseline: 4.5450x; 1.0199x over previous
//
#include <hip/hip_runtime.h>
#include <hip/hip_bf16.h>
#include <math.h>

#define BB 8
#define NN 2048
#define KK 30
#define NF 128
#define EF 128
#define NPE 16
#define NRBF 16
#define MAXREL 32

#define V_OUT_SZ   (BB*NN*NF)
#define E_OUT_OFF  (V_OUT_SZ)
#define E_OUT_SZ   (BB*NN*KK*EF)
#define EIDX_OUT_OFF (E_OUT_OFF + E_OUT_SZ)

// workspace byte offsets
#define WS_EIDX_OFF 0                       // int[B*N*K]
#define WS_DNB_OFF  1966080                 // float[B*N*K]
#define WS_O_OFF    3932160                 // float[B*N*9]
#define WS_V6_OFF   4521984                 // float[B*N*6]
#define WS_CA4_OFF  4915200                 // float4[B*N]      (Ca.xyz, mask)
#define WS_W1_OFF   5177344                 // bf16[8192]   L1 frags
#define WS_W2_OFF   5193728                 // bf16[16384]  L2 frags
// end 5226496

typedef __attribute__((ext_vector_type(8))) short bf16x8;
typedef __attribute__((ext_vector_type(4))) float f32x4;
#define MFMA16(a,b,c) __builtin_amdgcn_mfma_f32_16x16x32_bf16(a,b,c,0,0,0)

struct F3 { float x, y, z; };
__device__ inline F3 f3sub(F3 a, F3 b){ return {a.x-b.x, a.y-b.y, a.z-b.z}; }
__device__ inline F3 f3cross(F3 a, F3 b){ return {a.y*b.z - a.z*b.y, a.z*b.x - a.x*b.z, a.x*b.y - a.y*b.x}; }
__device__ inline float f3dot(F3 a, F3 b){ return a.x*b.x + a.y*b.y + a.z*b.z; }
__device__ inline F3 f3norm(F3 v){
    float n = sqrtf(f3dot(v, v));
    float r = 1.0f/(n + 1e-8f);
    return {v.x*r, v.y*r, v.z*r};
}
__device__ inline float sgnf(float x){ return (x>0.f)?1.f:((x<0.f)?-1.f:0.f); }
__device__ inline short f2bf(float f){
    union { __hip_bfloat16 h; short s; } u;
    u.h = __float2bfloat16(f);
    return u.s;
}

// ---------------------------------------------------------------------------
// VALU-only cross-lane min butterflies (f32 value phase + u32 index phase).
// DPP covers xor1/2 + ror4/8 within 16-lane rows; gfx950 permlane16/32_swap
// covers the row/half exchange. Fallbacks guarded by __has_builtin.
// ---------------------------------------------------------------------------
template<int CTRL>
__device__ __forceinline__ float fmin_dpp(float x){
    int xi = __float_as_int(x);
    int yi = __builtin_amdgcn_update_dpp(xi, xi, CTRL, 0xf, 0xf, false);
    return fminf(x, __int_as_float(yi));
}
template<int CTRL>
__device__ __forceinline__ unsigned umin_dpp(unsigned x){
    int yi = __builtin_amdgcn_update_dpp((int)x, (int)x, CTRL, 0xf, 0xf, false);
    return min(x, (unsigned)yi);
}

#if __has_builtin(__builtin_amdgcn_permlane16_swap)
__device__ __forceinline__ float fmin_x16(float x){
    unsigned xb = __float_as_uint(x);
    auto r = __builtin_amdgcn_permlane16_swap(xb, xb, false, false);
    return fminf(x, fminf(__uint_as_float(r[0]), __uint_as_float(r[1])));
}
__device__ __forceinline__ unsigned umin_x16(unsigned x){
    auto r = __builtin_amdgcn_permlane16_swap(x, x, false, false);
    return min(x, min((unsigned)r[0], (unsigned)r[1]));
}
#else
__device__ __forceinline__ float fmin_x16(float x){
    int yi = __builtin_amdgcn_ds_swizzle(__float_as_int(x), 0x401F);
    return fminf(x, __int_as_float(yi));
}
__device__ __forceinline__ unsigned umin_x16(unsigned x){
    int yi = __builtin_amdgcn_ds_swizzle((int)x, 0x401F);
    return min(x, (unsigned)yi);
}
#endif

#if __has_builtin(__builtin_amdgcn_permlane32_swap)
__device__ __forceinline__ float fmin_x32(float x){
    unsigned xb = __float_as_uint(x);
    auto r = __builtin_amdgcn_permlane32_swap(xb, xb, false, false);
    return fminf(x, fminf(__uint_as_float(r[0]), __uint_as_float(r[1])));
}
__device__ __forceinline__ unsigned umin_x32(unsigned x){
    auto r = __builtin_amdgcn_permlane32_swap(x, x, false, false);
    return min(x, min((unsigned)r[0], (unsigned)r[1]));
}
#else
__device__ __forceinline__ float fmin_x32(float x){
    return fminf(x, __shfl_xor(x, 32, 64));
}
__device__ __forceinline__ unsigned umin_x32(unsigned x){
    return min(x, (unsigned)__shfl_xor((int)x, 32, 64));
}
#endif

__device__ __forceinline__ float wave_fmin(float x){
    x = fmin_dpp<0xB1>(x);    // quad_perm xor 1
    x = fmin_dpp<0x4E>(x);    // quad_perm xor 2
    x = fmin_dpp<0x124>(x);   // row_ror:4
    x = fmin_dpp<0x128>(x);   // row_ror:8
    x = fmin_x16(x);
    x = fmin_x32(x);
    return x;                 // all 64 lanes hold the min
}
__device__ __forceinline__ unsigned wave_umin(unsigned x){
    x = umin_dpp<0xB1>(x);
    x = umin_dpp<0x4E>(x);
    x = umin_dpp<0x124>(x);
    x = umin_dpp<0x128>(x);
    x = umin_x16(x);
    x = umin_x32(x);
    return x;
}

// ---------------------------------------------------------------------------
// Kernel P: pre-convert edge-MLP weights into bf16 MFMA-fragment order.
// ---------------------------------------------------------------------------
__global__ void prep_kernel(const float* __restrict__ elw,
                            const float* __restrict__ eew,
                            __hip_bfloat16* __restrict__ w1,
                            __hip_bfloat16* __restrict__ w2)
{
    int i = blockIdx.x*256 + threadIdx.x;
    if (i < 8192) {
        int j = i & 7, lane = (i>>3)&63, ks = (i>>9)&1, nf = i>>10;
        int k = ks*32 + (lane>>4)*8 + j;
        int col = nf*16 + (lane&15);
        float v = (k < 39) ? elw[k*128 + col] : 0.f;
        w1[i] = __float2bfloat16(v);
    } else if (i < 8192 + 16384) {
        int i2 = i - 8192;
        int j = i2 & 7, lane = (i2>>3)&63, ks = (i2>>9)&3, nf = i2>>11;
        int k = ks*32 + (lane>>4)*8 + j;
        int col = nf*16 + (lane&15);
        w2[i2] = __float2bfloat16(eew[k*128 + col]);
    }
}

// ---------------------------------------------------------------------------
// Kernel A: per-node geometry -> V6 (dihedral 6), O (9), packed Ca4 (xyz+mask)
// ---------------------------------------------------------------------------
__global__ void geom_kernel(const float* __restrict__ X,
                            const float* __restrict__ mask,
                            float* __restrict__ wsO, float* __restrict__ wsV6,
                            float4* __restrict__ wsCa4)
{
    int ng = blockIdx.x * blockDim.x + threadIdx.x;
    if (ng >= BB*NN) return;
    int b = ng / NN, n = ng % NN;
    const float* Xb = X + (size_t)b * NN * 12;

    {
        const float* cp = X + (size_t)ng*12 + 3;
        wsCa4[ng] = make_float4(cp[0], cp[1], cp[2], mask[ng]);
    }

    int k0 = 3*n - 1;
    F3 P[6];
    #pragma unroll
    for (int t = 0; t < 6; ++t) {
        int m = k0 + t;
        if (m < 0) m = 0;
        if (m > 3*NN-1) m = 3*NN-1;
        int r = m / 3, a = m % 3;
        const float* p = Xb + ((size_t)r*4 + a)*3;
        P[t] = {p[0], p[1], p[2]};
    }
    F3 U[5];
    #pragma unroll
    for (int t = 0; t < 5; ++t) U[t] = f3norm(f3sub(P[t+1], P[t]));

    float Dang[3];
    #pragma unroll
    for (int t = 0; t < 3; ++t) {
        int k = k0 + t;
        if (k < 0 || k > 3*NN-4) { Dang[t] = 0.f; continue; }
        F3 u2 = U[t], u1 = U[t+1], u0 = U[t+2];
        F3 n2 = f3norm(f3cross(u2, u1));
        F3 n1 = f3norm(f3cross(u1, u0));
        float cosD = f3dot(n2, n1);
        cosD = fminf(fmaxf(cosD, -1.f + 1e-7f), 1.f - 1e-7f);
        float s = f3dot(u2, n1);
        Dang[t] = sgnf(s) * acosf(cosD);
    }
    float* v6 = wsV6 + (size_t)ng * 6;
    v6[0] = cosf(Dang[0]); v6[1] = cosf(Dang[1]); v6[2] = cosf(Dang[2]);
    v6[3] = sinf(Dang[0]); v6[4] = sinf(Dang[1]); v6[5] = sinf(Dang[2]);

    float* o = wsO + (size_t)ng * 9;
    if (n >= 1 && n <= NN-3) {
        const float* cb = X + (size_t)b * NN * 12 + 3;
        F3 c0 = {cb[(size_t)(n-1)*12+0], cb[(size_t)(n-1)*12+1], cb[(size_t)(n-1)*12+2]};
        F3 c1 = {cb[(size_t)(n  )*12+0], cb[(size_t)(n  )*12+1], cb[(size_t)(n  )*12+2]};
        F3 c2 = {cb[(size_t)(n+1)*12+0], cb[(size_t)(n+1)*12+1], cb[(size_t)(n+1)*12+2]};
        F3 u2 = f3norm(f3sub(c1, c0));
        F3 u1 = f3norm(f3sub(c2, c1));
        F3 n2 = f3norm(f3cross(u2, u1));
        F3 o1 = f3norm(f3sub(u2, u1));
        F3 r2 = f3cross(o1, n2);
        o[0]=o1.x; o[1]=o1.y; o[2]=o1.z;
        o[3]=n2.x; o[4]=n2.y; o[5]=n2.z;
        o[6]=r2.x; o[7]=r2.y; o[8]=r2.z;
    } else {
        #pragma unroll
        for (int m = 0; m < 9; ++m) o[m] = 0.f;
    }
}

// ---------------------------------------------------------------------------
// Kernel B: top-K, register-queue. 1 wave/row, 4 rows/block, zero LDS.
// dloc fully in VGPRs (all dloc loops fully unrolled: rule #20).
// k-loop is FORCED NOT to unroll (#pragma unroll 1): R7's ~10K-instr unrolled
// body thrashed the 32KB I-cache (the ~86us plateau). One ~3KB body instead.
// Per round: f32 DPP butterfly on queue-head distances, then u32 butterfly
// on indices where d==dmin (exact lexicographic (d,j), numpy tie semantics).
// Distances use __f*_rn ops (no contraction) to match numpy rounding.
// ---------------------------------------------------------------------------
#define KEMPTY 8.9884656743115795e+307   // 0x7FE0...0: d_bits=huge, j=0

__device__ __forceinline__ double make_key(float d, int j){
    unsigned long long k =
        ((unsigned long long)__float_as_uint(d) << 32) | (unsigned)j;
    return __longlong_as_double((long long)k);
}

__device__ __forceinline__ void ins3(double& q0, double& q1, double& q2, double k){
    double k2 = fmin(k, q2);          // drop max(k, q2)
    double t1 = fmin(q1, k2); q2 = fmax(q1, k2);
    double t0 = fmin(q0, t1); q1 = fmax(q0, t1);
    q0 = t0;
}

__global__ __launch_bounds__(256, 4) void topk_kernel(
    const float4* __restrict__ wsCa4,
    int* __restrict__ wsEidx, float* __restrict__ wsDnb,
    float* __restrict__ outEidxF)
{
    const int wave = threadIdx.x >> 6, lane = threadIdx.x & 63;
    const int row = blockIdx.x*4 + wave;
    const int b = row >> 11, i = row & (NN-1);

    const float4* cb = wsCa4 + ((size_t)b << 11);
    float4 ci = cb[i];
    float mi = ci.w;

    float dloc[32];
    double q0 = KEMPTY, q1 = KEMPTY, q2 = KEMPTY;
    #pragma unroll
    for (int s = 0; s < 32; ++s) {
        int j = s*64 + lane;
        float4 cj = cb[j];
        float dx = __fsub_rn(ci.x, cj.x);
        float dy = __fsub_rn(ci.y, cj.y);
        float dz = __fsub_rn(ci.z, cj.z);
        float d2 = __fadd_rn(__fadd_rn(__fadd_rn(__fmul_rn(dx,dx),
                                                 __fmul_rn(dy,dy)),
                                       __fmul_rn(dz,dz)), 1e-6f);
        float d = sqrtf(d2);
        d = __fadd_rn(d, __fmul_rn(__fsub_rn(1.0f, __fmul_rn(mi, cj.w)), 10000.0f));
        dloc[s] = d;
        ins3(q0, q1, q2, make_key(d, j));
    }

    double res = KEMPTY;
    #pragma unroll 1
    for (int k = 0; k < KK; ++k) {
        unsigned long long q0b = (unsigned long long)__double_as_longlong(q0);
        float    hd = __uint_as_float((unsigned)(q0b >> 32));
        unsigned hj = (unsigned)q0b;

        float dmin = wave_fmin(hd);
        unsigned cand = (hd == dmin) ? hj : 0xFFFFFFFFu;
        unsigned jmin = wave_umin(cand);

        if (lane == k)
            res = __longlong_as_double((long long)(
                ((unsigned long long)__float_as_uint(dmin) << 32) | jmin));

        if (hd == dmin && hj == jmin) {   // exactly one lane (j unique)
            q0 = q1; q1 = q2; q2 = KEMPTY;
            if (__double_as_longlong(q0) == __double_as_longlong(KEMPTY)) {
                // refill with 3 smallest keys > g (monotone pops -> exact)
                double g = __longlong_as_double((long long)(
                    ((unsigned long long)__float_as_uint(dmin) << 32) | jmin));
                #pragma unroll
                for (int s = 0; s < 32; ++s) {
                    double kk = make_key(dloc[s], s*64 + lane);
                    if (!(kk > g)) kk = KEMPTY;
                    ins3(q0, q1, q2, kk);
                }
            }
        }
    }

    if (lane < KK) {
        const size_t rb = (size_t)row * KK;
        unsigned long long gk = (unsigned long long)__double_as_longlong(res);
        int j = (int)(unsigned)gk;
        float dwin = __uint_as_float((unsigned)(gk >> 32));
        wsEidx[rb + lane] = j;
        wsDnb[rb + lane]  = dwin;
        outEidxF[rb + lane] = (float)j;
    }
}

// ---------------------------------------------------------------------------
// Kernel C: node path (unchanged)
// ---------------------------------------------------------------------------
__global__ __launch_bounds__(128) void node_kernel(
    const float* __restrict__ wsV6,
    const float* __restrict__ nlw, const float* __restrict__ nlb,
    const float* __restrict__ new_, const float* __restrict__ neb,
    const float* __restrict__ nng, const float* __restrict__ nnb,
    float* __restrict__ outV)
{
    int f = threadIdx.x;
    __shared__ float h1[128];
    __shared__ float red[2][2];

    float w2[128];
    #pragma unroll
    for (int c = 0; c < 128; ++c) w2[c] = new_[c*128 + f];
    float w1[6];
    #pragma unroll
    for (int c = 0; c < 6; ++c) w1[c] = nlw[c*128 + f];
    float b1v = nlb[f], b2v = neb[f], gv = nng[f], bv = nnb[f];

    for (int gi = 0; gi < 8; ++gi) {
        int row = blockIdx.x*8 + gi;
        float acc = b1v;
        #pragma unroll
        for (int c = 0; c < 6; ++c) acc = fmaf(wsV6[(size_t)row*6 + c], w1[c], acc);
        h1[f] = acc;
        __syncthreads();

        float a2 = b2v;
        #pragma unroll
        for (int c4 = 0; c4 < 32; ++c4) {
            float4 v = *(const float4*)&h1[c4*4];
            a2 = fmaf(v.x, w2[c4*4+0], a2);
            a2 = fmaf(v.y, w2[c4*4+1], a2);
            a2 = fmaf(v.z, w2[c4*4+2], a2);
            a2 = fmaf(v.w, w2[c4*4+3], a2);
        }
        float s = a2, ss = a2*a2;
        #pragma unroll
        for (int off = 32; off; off >>= 1) {
            s  += __shfl_xor(s,  off, 64);
            ss += __shfl_xor(ss, off, 64);
        }
        int wig = f >> 6;
        if ((f & 63) == 0) { red[wig][0] = s; red[wig][1] = ss; }
        __syncthreads();
        float S = red[0][0] + red[1][0], SS = red[0][1] + red[1][1];
        float mu = S * (1.f/128.f);
        float var = SS * (1.f/128.f) - mu*mu;
        float inv = rsqrtf(var + 1e-5f);
        outV[(size_t)row*128 + f] = (a2 - mu)*inv*gv + bv;
        __syncthreads();
    }
}

// ---------------------------------------------------------------------------
// Kernel D: edge MFMA (unchanged)
// ---------------------------------------------------------------------------
__global__ __launch_bounds__(256, 4) void edge_mfma_kernel(
    const float4* __restrict__ wsCa4,
    const int* __restrict__ ridx, const int* __restrict__ chain,
    const int* __restrict__ wsEidx, const float* __restrict__ wsDnb,
    const float* __restrict__ wsO,
    const float* __restrict__ pe_w, const float* __restrict__ pe_b,
    const __hip_bfloat16* __restrict__ wsW1, const __hip_bfloat16* __restrict__ wsW2,
    const float* __restrict__ elb, const float* __restrict__ eeb,
    const float* __restrict__ lng, const float* __restrict__ lnb,
    float* __restrict__ outE)
{
    __shared__ char smem[64*72*2 + 64*136*2];
    short* Ef  = (short*)smem;
    short* h1t = (short*)(smem + 64*72*2);
    float* redS  = (float*)smem;
    float* redSS = (float*)(smem + 512);

    const int tid  = threadIdx.x;
    const int wave = tid >> 6, lane = tid & 63;
    const int wm = wave >> 1, wn = wave & 1;
    const int lr = lane & 15, lk = lane >> 4;

    float b1v[4], b2v[4], gv[4], bv[4];
    #pragma unroll
    for (int nf = 0; nf < 4; ++nf) {
        int col = wn*64 + nf*16 + lr;
        b1v[nf] = elb[col]; b2v[nf] = eeb[col];
        gv[nf]  = lng[col]; bv[nf]  = lnb[col];
    }

    for (int idx = tid; idx < 64*25; idx += 256) {
        int r = idx / 25, c = 39 + idx % 25;
        Ef[r*72 + c] = 0;
    }

    const int E0 = blockIdx.x * 64;

    if (wave == 0) {
        int ge = E0 + lane;
        int row = ge / KK;
        int b = row >> 11;
        int j = wsEidx[ge];
        float oi[9], oj[9];
        #pragma unroll
        for (int m = 0; m < 9; ++m) {
            oi[m] = wsO[(size_t)row*9 + m];
            oj[m] = wsO[((size_t)(b*NN) + j)*9 + m];
        }
        float4 ci = wsCa4[row];
        float4 cj = wsCa4[(size_t)b*NN + j];
        float dx = cj.x-ci.x, dy = cj.y-ci.y, dz = cj.z-ci.z;
        float t0 = oi[0]*dx + oi[1]*dy + oi[2]*dz;
        float t1 = oi[3]*dx + oi[4]*dy + oi[5]*dz;
        float t2 = oi[6]*dx + oi[7]*dy + oi[8]*dz;
        float nr = sqrtf(t0*t0 + t1*t1 + t2*t2);
        float iv = 1.f/(nr + 1e-8f);
        short* ef = &Ef[lane*72];
        ef[32] = f2bf(t0*iv); ef[33] = f2bf(t1*iv); ef[34] = f2bf(t2*iv);
        float R00 = oi[0]*oj[0]+oi[3]*oj[3]+oi[6]*oj[6];
        float R01 = oi[0]*oj[1]+oi[3]*oj[4]+oi[6]*oj[7];
        float R02 = oi[0]*oj[2]+oi[3]*oj[5]+oi[6]*oj[8];
        float R10 = oi[1]*oj[0]+oi[4]*oj[3]+oi[7]*oj[6];
        float R11 = oi[1]*oj[1]+oi[4]*oj[4]+oi[7]*oj[7];
        float R12 = oi[1]*oj[2]+oi[4]*oj[5]+oi[7]*oj[8];
        float R20 = oi[2]*oj[0]+oi[5]*oj[3]+oi[8]*oj[6];
        float R21 = oi[2]*oj[1]+oi[5]*oj[4]+oi[8]*oj[7];
        float R22 = oi[2]*oj[2]+oi[5]*oj[5]+oi[8]*oj[8];
        float mx = 0.5f*sqrtf(fabsf(1.f + R00 - R11 - R22));
        float my = 0.5f*sqrtf(fabsf(1.f - R00 + R11 - R22));
        float mz = 0.5f*sqrtf(fabsf(1.f - R00 - R11 + R22));
        float qx = sgnf(R21 - R12)*mx;
        float qy = sgnf(R02 - R20)*my;
        float qz = sgnf(R10 - R01)*mz;
        float qw = 0.5f*sqrtf(fmaxf(0.f, 1.f + R00 + R11 + R22));
        float qn = sqrtf(qx*qx + qy*qy + qz*qz + qw*qw);
        float qi = 1.f/(qn + 1e-8f);
        ef[35] = f2bf(qx*qi); ef[36] = f2bf(qy*qi);
        ef[37] = f2bf(qz*qi); ef[38] = f2bf(qw*qi);
    } else if (wave == 1) {
        int ge = E0 + lane;
        float dnb = wsDnb[ge];
        short* ef = &Ef[lane*72 + 16];
        #pragma unroll
        for (int m = 0; m < 16; ++m) {
            float mu = 2.f + (20.f/15.f)*(float)m;
            float z = (dnb - mu) * 0.8f;
            ef[m] = f2bf(expf(-z*z));
        }
    } else if (wave == 2) {
        int ge = E0 + lane;
        int row = ge / KK;
        int b = row >> 11;
        int j = wsEidx[ge];
        int ri = ridx[row], rj = ridx[b*NN + j];
        int ch = (chain[row] == chain[b*NN + j]) ? 1 : 0;
        int dd = min(max(ri - rj + MAXREL, 0), 2*MAXREL);
        dd = ch ? dd : (2*MAXREL + 1);
        short* ef = &Ef[lane*72];
        #pragma unroll
        for (int m = 0; m < 16; ++m) ef[m] = f2bf(pe_w[dd*16 + m] + pe_b[m]);
    }
    __syncthreads();

    const bf16x8* W1f = (const bf16x8*)wsW1;
    const bf16x8* W2f = (const bf16x8*)wsW2;

    f32x4 acc[2][4];
    #pragma unroll
    for (int mf = 0; mf < 2; ++mf)
        #pragma unroll
        for (int nf = 0; nf < 4; ++nf)
            acc[mf][nf] = (f32x4){0.f, 0.f, 0.f, 0.f};
    #pragma unroll
    for (int ks = 0; ks < 2; ++ks) {
        bf16x8 a0 = *(const bf16x8*)&Ef[(wm*32      + lr)*72 + ks*32 + lk*8];
        bf16x8 a1 = *(const bf16x8*)&Ef[(wm*32 + 16 + lr)*72 + ks*32 + lk*8];
        #pragma unroll
        for (int nf = 0; nf < 4; ++nf) {
            bf16x8 Bf = W1f[((wn*4 + nf)*2 + ks)*64 + lane];
            acc[0][nf] = MFMA16(a0, Bf, acc[0][nf]);
            acc[1][nf] = MFMA16(a1, Bf, acc[1][nf]);
        }
    }
    #pragma unroll
    for (int mf = 0; mf < 2; ++mf)
        #pragma unroll
        for (int nf = 0; nf < 4; ++nf)
            #pragma unroll
            for (int r = 0; r < 4; ++r) {
                int row = wm*32 + mf*16 + lk*4 + r;
                int col = wn*64 + nf*16 + lr;
                h1t[row*136 + col] = f2bf(acc[mf][nf][r] + b1v[nf]);
            }
    __syncthreads();

    f32x4 acc2[2][4];
    #pragma unroll
    for (int mf = 0; mf < 2; ++mf)
        #pragma unroll
        for (int nf = 0; nf < 4; ++nf)
            acc2[mf][nf] = (f32x4){0.f, 0.f, 0.f, 0.f};
    #pragma unroll
    for (int ks = 0; ks < 4; ++ks) {
        bf16x8 a0 = *(const bf16x8*)&h1t[(wm*32      + lr)*136 + ks*32 + lk*8];
        bf16x8 a1 = *(const bf16x8*)&h1t[(wm*32 + 16 + lr)*136 + ks*32 + lk*8];
        #pragma unroll
        for (int nf = 0; nf < 4; ++nf) {
            bf16x8 Bf = W2f[((wn*4 + nf)*4 + ks)*64 + lane];
            acc2[0][nf] = MFMA16(a0, Bf, acc2[0][nf]);
            acc2[1][nf] = MFMA16(a1, Bf, acc2[1][nf]);
        }
    }
    #pragma unroll
    for (int mf = 0; mf < 2; ++mf)
        #pragma unroll
        for (int nf = 0; nf < 4; ++nf)
            #pragma unroll
            for (int r = 0; r < 4; ++r)
                acc2[mf][nf][r] += b2v[nf];

    #pragma unroll
    for (int mf = 0; mf < 2; ++mf) {
        #pragma unroll
        for (int r = 0; r < 4; ++r) {
            float v0 = acc2[mf][0][r], v1 = acc2[mf][1][r];
            float v2 = acc2[mf][2][r], v3 = acc2[mf][3][r];
            float s = v0 + v1 + v2 + v3;
            float q = v0*v0 + v1*v1 + v2*v2 + v3*v3;
            #pragma unroll
            for (int off = 1; off < 16; off <<= 1) {
                s += __shfl_xor(s, off, 64);
                q += __shfl_xor(q, off, 64);
            }
            if (lr == 0) {
                int row = wm*32 + mf*16 + lk*4 + r;
                redS[row*2 + wn] = s; redSS[row*2 + wn] = q;
            }
        }
    }
    __syncthreads();

    const size_t obase = (size_t)E0 * 128;
    #pragma unroll
    for (int mf = 0; mf < 2; ++mf) {
        #pragma unroll
        for (int r = 0; r < 4; ++r) {
            int row = wm*32 + mf*16 + lk*4 + r;
            float S = redS[row*2 + 0] + redS[row*2 + 1];
            float Q = redSS[row*2 + 0] + redSS[row*2 + 1];
            float mu = S * (1.f/128.f);
            float var = Q * (1.f/128.f) - mu*mu;
            float inv = rsqrtf(var + 1e-5f);
            #pragma unroll
            for (int nf = 0; nf < 4; ++nf) {
                int col = wn*64 + nf*16 + lr;
                outE[obase + (size_t)row*128 + col] =
                    (acc2[mf][nf][r] - mu)*inv*gv[nf] + bv[nf];
            }
        }
    }
}

// ---------------------------------------------------------------------------
extern "C" void kernel_launch(void* const* d_in, const int* in_sizes, int n_in,
                              void* d_out, int out_size, void* d_ws, size_t ws_size,
                              hipStream_t stream)
{
    const float* X     = (const float*)d_in[0];
    const float* mask  = (const float*)d_in[1];
    const int*   ridx  = (const int*)  d_in[2];
    const int*   chain = (const int*)  d_in[3];
    const float* pe_w  = (const float*)d_in[4];
    const float* pe_b  = (const float*)d_in[5];
    const float* nlw   = (const float*)d_in[6];
    const float* nlb   = (const float*)d_in[7];
    const float* new_  = (const float*)d_in[8];
    const float* neb   = (const float*)d_in[9];
    const float* elw   = (const float*)d_in[10];
    const float* elb   = (const float*)d_in[11];
    const float* eew   = (const float*)d_in[12];
    const float* eeb   = (const float*)d_in[13];
    const float* nng   = (const float*)d_in[14];
    const float* nnb   = (const float*)d_in[15];
    const float* neg_  = (const float*)d_in[16];
    const float* neb_  = (const float*)d_in[17];

    float* out = (float*)d_out;
    char*  ws  = (char*)d_ws;
    int*    wsEidx = (int*)   (ws + WS_EIDX_OFF);
    float*  wsDnb  = (float*) (ws + WS_DNB_OFF);
    float*  wsO    = (float*) (ws + WS_O_OFF);
    float*  wsV6   = (float*) (ws + WS_V6_OFF);
    float4* wsCa4  = (float4*)(ws + WS_CA4_OFF);
    __hip_bfloat16* wsW1 = (__hip_bfloat16*)(ws + WS_W1_OFF);
    __hip_bfloat16* wsW2 = (__hip_bfloat16*)(ws + WS_W2_OFF);

    prep_kernel<<<96, 256, 0, stream>>>(elw, eew, wsW1, wsW2);
    geom_kernel<<<(BB*NN + 255)/256, 256, 0, stream>>>(X, mask, wsO, wsV6, wsCa4);
    topk_kernel<<<BB*NN/4, 256, 0, stream>>>(wsCa4, wsEidx, wsDnb, out + EIDX_OUT_OFF);
    node_kernel<<<BB*NN/8, 128, 0, stream>>>(wsV6, nlw, nlb, new_, neb, nng, nnb, out);
    edge_mfma_kernel<<<BB*NN*KK/64, 256, 0, stream>>>(wsCa4, ridx, chain, wsEidx, wsDnb, wsO,
                                                      pe_w, pe_b, wsW1, wsW2,
                                                      elb, eeb, neg_, neb_, out + E_OUT_OFF);
}